// Round 7
// baseline (379.498 us; speedup 1.0000x reference)
//
#include <hip/hip_runtime.h>
#include <hip/hip_bf16.h>

#define NN 10000
#define EE 160000
#define FF 128
#define UU 128
#define HH 8
#define BN_EPS 1e-3f

typedef __attribute__((ext_vector_type(8))) short bf16x8;
typedef __attribute__((ext_vector_type(8))) unsigned short u16x8;
typedef __attribute__((ext_vector_type(4))) float f32x4;

static __device__ __forceinline__ unsigned short f2bf(float f) {
    unsigned u = __float_as_uint(f);
    u += 0x7fffu + ((u >> 16) & 1u);
    return (unsigned short)(u >> 16);
}
static __device__ __forceinline__ float bf2f(unsigned short b) {
    return __uint_as_float((unsigned)b << 16);
}

// ---------------- f32 -> bf16 bulk convert (count divisible by 4) ----------------
__global__ void k_f2bf(const float* __restrict__ in, unsigned short* __restrict__ out, long n4) {
    long i = (long)blockIdx.x * 256 + threadIdx.x;
    long stride = (long)gridDim.x * 256;
    for (; i < n4; i += stride) {
        float4 v = reinterpret_cast<const float4*>(in)[i];
        ushort4 o;
        o.x = f2bf(v.x); o.y = f2bf(v.y); o.z = f2bf(v.z); o.w = f2bf(v.w);
        reinterpret_cast<ushort4*>(out)[i] = o;
    }
}

// ---------------- generic W [K][U] f32 -> W^T [U][K] bf16 ----------------
__global__ void k_wtg(const float* __restrict__ W, unsigned short* __restrict__ Wt, int K, int U) {
    int i = blockIdx.x * 256 + threadIdx.x;
    if (i < K * U) {
        int k = i / U, u = i - k * U;
        Wt[u * K + k] = f2bf(W[i]);
    }
}

// ---------------- W_att [8][128][128] f32 -> per-head W^T [8][128][128] bf16 ----------------
__global__ void k_wt_att(const float* __restrict__ W, unsigned short* __restrict__ Wt) {
    int i = blockIdx.x * 256 + threadIdx.x;   // over 8*128*128
    if (i < 8 * 128 * 128) {
        int h = i >> 14, rem = i & 16383, f = rem >> 7, u = rem & 127;
        Wt[h * 16384 + u * 128 + f] = f2bf(W[i]);
    }
}

// ---------------- GRU combined weight: WcT [512][256] bf16 ----------------
__global__ void k_wt_gru(const float* __restrict__ Wk, const float* __restrict__ Wr,
                         unsigned short* __restrict__ WcT) {
    int i = blockIdx.x * 256 + threadIdx.x;   // over 512*256
    if (i >= 512 * 256) return;
    int c = i >> 8, k = i & 255;
    float v;
    if (c < 256)       v = (k < 128) ? Wk[k * 384 + c] : Wr[(k - 128) * 384 + c];
    else if (c < 384)  v = (k < 128) ? Wk[k * 384 + c] : 0.f;
    else               v = (k < 128) ? 0.f : Wr[(k - 128) * 384 + (c - 128)];
    WcT[c * 256 + k] = f2bf(v);
}

// ---------------- CSR construction ----------------
__global__ void k_hist(const int* __restrict__ eidx, int* __restrict__ cnt, int E) {
    int e = blockIdx.x * 256 + threadIdx.x;
    if (e < E) atomicAdd(&cnt[eidx[2 * e]], 1);   // dst = eidx[e][0]
}

__global__ void k_scan(const int* __restrict__ cnt, int* __restrict__ off,
                       int* __restrict__ cursor, int N) {
    __shared__ int s[1024];
    int t = threadIdx.x;
    int run = 0;
    if (t == 0) off[0] = 0;
    for (int base = 0; base < N; base += 1024) {
        int x = (base + t < N) ? cnt[base + t] : 0;
        s[t] = x;
        __syncthreads();
        for (int o = 1; o < 1024; o <<= 1) {
            int v = (t >= o) ? s[t - o] : 0;
            __syncthreads();
            s[t] += v;
            __syncthreads();
        }
        if (base + t < N) {
            off[base + t + 1] = run + s[t];
            cursor[base + t] = run + s[t] - x;
        }
        run += s[1023];
        __syncthreads();
    }
}

__global__ void k_scatter(const int* __restrict__ eidx, int* __restrict__ cursor,
                          int* __restrict__ elist, int E) {
    int e = blockIdx.x * 256 + threadIdx.x;
    if (e < E) {
        int d = eidx[2 * e];
        int p = atomicAdd(&cursor[d], 1);
        elist[p] = e;
    }
}

// ---------------- z (bf16) = node @ W_att[h] + b_att[h], MFMA, LDS-coalesced store ----------------
__global__ void __launch_bounds__(256) k_z_mfma(
        const unsigned short* __restrict__ node_bf, const unsigned short* __restrict__ WtA,
        const float* __restrict__ batt, unsigned short* __restrict__ zbf, int N) {
    __shared__ unsigned short ash[64][136];     // 128 + 8 pad
    int n0 = blockIdx.x * 64;
    int h = blockIdx.y;
    int t = threadIdx.x;
    for (int q = t; q < 64 * 16; q += 256) {
        int r = q >> 4, c = q & 15;
        int n = n0 + r; if (n >= N) n = N - 1;
        *reinterpret_cast<uint4*>(&ash[r][c * 8]) =
            *reinterpret_cast<const uint4*>(node_bf + (size_t)n * 128 + c * 8);
    }
    __syncthreads();

    int wid = t >> 6, lane = t & 63;
    int wm = wid >> 1, wn = wid & 1;
    int lr = lane & 15, lg = lane >> 4;

    f32x4 acc[2][4];
#pragma unroll
    for (int m = 0; m < 2; ++m)
#pragma unroll
        for (int n = 0; n < 4; ++n) acc[m][n] = (f32x4){0.f, 0.f, 0.f, 0.f};

    const unsigned short* Wh = WtA + (size_t)h * 16384;
#pragma unroll
    for (int ks = 0; ks < 4; ++ks) {
        int kb = ks * 32 + lg * 8;
        bf16x8 a0 = *reinterpret_cast<const bf16x8*>(&ash[wm * 32 + lr][kb]);
        bf16x8 a1 = *reinterpret_cast<const bf16x8*>(&ash[wm * 32 + 16 + lr][kb]);
        bf16x8 b[4];
#pragma unroll
        for (int n = 0; n < 4; ++n)
            b[n] = *reinterpret_cast<const bf16x8*>(Wh + (size_t)(wn * 64 + n * 16 + lr) * 128 + kb);
#pragma unroll
        for (int n = 0; n < 4; ++n) {
            acc[0][n] = __builtin_amdgcn_mfma_f32_16x16x32_bf16(a0, b[n], acc[0][n], 0, 0, 0);
            acc[1][n] = __builtin_amdgcn_mfma_f32_16x16x32_bf16(a1, b[n], acc[1][n], 0, 0, 0);
        }
    }

    __syncthreads();                      // A-tile reads done; reuse ash as C-tile
    unsigned short* ot = &ash[0][0];      // [64][136]
#pragma unroll
    for (int n = 0; n < 4; ++n) {
        int col = wn * 64 + n * 16 + lr;
        float bias = batt[h * 128 + col];
#pragma unroll
        for (int m = 0; m < 2; ++m) {
            int rowb = wm * 32 + m * 16 + lg * 4;
#pragma unroll
            for (int r = 0; r < 4; ++r)
                ot[(rowb + r) * 136 + col] = f2bf(acc[m][n][r] + bias);
        }
    }
    __syncthreads();
    for (int q = t; q < 64 * 16; q += 256) {
        int r = q >> 4, c = q & 15;
        int row = n0 + r;
        if (row < N)
            *reinterpret_cast<uint4*>(&zbf[(size_t)row * 1024 + h * 128 + c * 8]) =
                *reinterpret_cast<const uint4*>(&ot[r * 136 + c * 8]);
    }
}

// ---------------- s_src[n,h], s_dst[n,h]: wave=node, lane=(head, 16-col slice) ----------------
__global__ void __launch_bounds__(256) k_snodes(
        const unsigned short* __restrict__ zbf, const float* __restrict__ aatt,
        float* __restrict__ s_src, float* __restrict__ s_dst, int N) {
    int t = threadIdx.x;
    int w = t >> 6, lane = t & 63;
    int n = blockIdx.x * 4 + w;
    if (n >= N) return;
    int h = lane >> 3, p = lane & 7;
    const unsigned short* zp = zbf + (size_t)n * 1024 + h * 128 + p * 16;
    const float* as = aatt + h * 384 + p * 16;
    u16x8 z0 = *reinterpret_cast<const u16x8*>(zp);
    u16x8 z1 = *reinterpret_cast<const u16x8*>(zp + 8);
    float vs = 0.f, vd = 0.f;
#pragma unroll
    for (int j = 0; j < 8; ++j) {
        float zv = bf2f(z0[j]);
        vs = fmaf(zv, as[j], vs);
        vd = fmaf(zv, as[128 + j], vd);
    }
#pragma unroll
    for (int j = 0; j < 8; ++j) {
        float zv = bf2f(z1[j]);
        vs = fmaf(zv, as[8 + j], vs);
        vd = fmaf(zv, as[136 + j], vd);
    }
#pragma unroll
    for (int o = 1; o < 8; o <<= 1) {
        vs += __shfl_xor(vs, o, 64);
        vd += __shfl_xor(vd, o, 64);
    }
    if (p == 0) {
        s_src[n * 8 + h] = vs;
        s_dst[n * 8 + h] = vd;
    }
}

// ---------------- edge MLP via MFMA bf16: 32-edge tile (high occupancy) ----------------
__global__ void __launch_bounds__(256) k_edge_mlp_mfma(
        const unsigned short* __restrict__ node_bf, const unsigned short* __restrict__ eattr_bf,
        const int* __restrict__ eidx, const unsigned short* __restrict__ Wt,
        const float* __restrict__ be, unsigned short* __restrict__ ebuf, float* __restrict__ part) {
    __shared__ unsigned short ash[32][392];     // 384 + 8 pad (25 KB)
    __shared__ int sd[64];
    __shared__ float sbuf[4][64], qbuf[4][64];
    int e0 = blockIdx.x * 32;
    int t = threadIdx.x;
    if (t < 64) sd[t] = eidx[e0 * 2 + t];       // [e][0]=dst, [e][1]=src
    __syncthreads();
    for (int q = t; q < 32 * 48; q += 256) {    // 6 chunks/thread
        int r = q / 48, c = q - r * 48;
        const unsigned short* sp;
        if (c < 16)      sp = node_bf + (size_t)sd[r * 2 + 1] * 128 + c * 8;
        else if (c < 32) sp = node_bf + (size_t)sd[r * 2] * 128 + (c - 16) * 8;
        else             sp = eattr_bf + (size_t)(e0 + r) * 128 + (c - 32) * 8;
        *reinterpret_cast<uint4*>(&ash[r][c * 8]) = *reinterpret_cast<const uint4*>(sp);
    }
    __syncthreads();

    int wid = t >> 6, lane = t & 63;
    int wm = wid >> 1, wn = wid & 1;            // wave tile: rows wm*16.., cols wn*64..
    int lr = lane & 15, lg = lane >> 4;

    f32x4 acc[4];
#pragma unroll
    for (int n = 0; n < 4; ++n) acc[n] = (f32x4){0.f, 0.f, 0.f, 0.f};

#pragma unroll
    for (int ks = 0; ks < 12; ++ks) {
        int kb = ks * 32 + lg * 8;
        bf16x8 a0 = *reinterpret_cast<const bf16x8*>(&ash[wm * 16 + lr][kb]);
        bf16x8 b[4];
#pragma unroll
        for (int n = 0; n < 4; ++n)
            b[n] = *reinterpret_cast<const bf16x8*>(Wt + (size_t)(wn * 64 + n * 16 + lr) * 384 + kb);
#pragma unroll
        for (int n = 0; n < 4; ++n)
            acc[n] = __builtin_amdgcn_mfma_f32_16x16x32_bf16(a0, b[n], acc[n], 0, 0, 0);
    }

    __syncthreads();                      // A-tile reads done; reuse ash as C-tile [32][136]
    unsigned short* ot = &ash[0][0];
    float s[4] = {0.f, 0.f, 0.f, 0.f}, q[4] = {0.f, 0.f, 0.f, 0.f};
#pragma unroll
    for (int n = 0; n < 4; ++n) {
        int col = wn * 64 + n * 16 + lr;
        float bias = be[col];
        int rowb = wm * 16 + lg * 4;
#pragma unroll
        for (int r = 0; r < 4; ++r) {
            float v = acc[n][r] + bias;
            v = v > 0.f ? v : 0.f;
            ot[(rowb + r) * 136 + col] = f2bf(v);
            s[n] += v;
            q[n] += v * v;
        }
    }
#pragma unroll
    for (int n = 0; n < 4; ++n) {
        s[n] += __shfl_xor(s[n], 16, 64);
        s[n] += __shfl_xor(s[n], 32, 64);
        q[n] += __shfl_xor(q[n], 16, 64);
        q[n] += __shfl_xor(q[n], 32, 64);
    }
    if (lane < 16) {
#pragma unroll
        for (int n = 0; n < 4; ++n) {
            sbuf[wid][n * 16 + lane] = s[n];
            qbuf[wid][n * 16 + lane] = q[n];
        }
    }
    __syncthreads();
    for (int q2 = t; q2 < 32 * 16; q2 += 256) {
        int r = q2 >> 4, c = q2 & 15;
        *reinterpret_cast<uint4*>(&ebuf[(size_t)(e0 + r) * 128 + c * 8]) =
            *reinterpret_cast<const uint4*>(&ot[r * 136 + c * 8]);
    }
    if (t < 128) {
        int half = t >> 6, c = t & 63;
        part[(size_t)blockIdx.x * 256 + t] = sbuf[half][c] + sbuf[2 + half][c];
        part[(size_t)blockIdx.x * 256 + 128 + t] = qbuf[half][c] + qbuf[2 + half][c];
    }
}

// ---------------- node MLP via MFMA: relu(node @ W_node + b) -> bf16, BN partials ----------------
__global__ void __launch_bounds__(256) k_node_mlp_mfma(
        const unsigned short* __restrict__ node_bf, const unsigned short* __restrict__ WnT,
        const float* __restrict__ bn, unsigned short* __restrict__ nupd_bf,
        float* __restrict__ part, int N) {
    __shared__ unsigned short ash[64][136];
    __shared__ float sbuf[4][64], qbuf[4][64];
    int n0 = blockIdx.x * 64;
    int t = threadIdx.x;
    for (int q = t; q < 64 * 16; q += 256) {
        int r = q >> 4, c = q & 15;
        int n = n0 + r; if (n >= N) n = N - 1;
        *reinterpret_cast<uint4*>(&ash[r][c * 8]) =
            *reinterpret_cast<const uint4*>(node_bf + (size_t)n * 128 + c * 8);
    }
    __syncthreads();

    int wid = t >> 6, lane = t & 63;
    int wm = wid >> 1, wn = wid & 1;
    int lr = lane & 15, lg = lane >> 4;

    f32x4 acc[2][4];
#pragma unroll
    for (int m = 0; m < 2; ++m)
#pragma unroll
        for (int n = 0; n < 4; ++n) acc[m][n] = (f32x4){0.f, 0.f, 0.f, 0.f};

#pragma unroll
    for (int ks = 0; ks < 4; ++ks) {
        int kb = ks * 32 + lg * 8;
        bf16x8 a0 = *reinterpret_cast<const bf16x8*>(&ash[wm * 32 + lr][kb]);
        bf16x8 a1 = *reinterpret_cast<const bf16x8*>(&ash[wm * 32 + 16 + lr][kb]);
        bf16x8 b[4];
#pragma unroll
        for (int n = 0; n < 4; ++n)
            b[n] = *reinterpret_cast<const bf16x8*>(WnT + (size_t)(wn * 64 + n * 16 + lr) * 128 + kb);
#pragma unroll
        for (int n = 0; n < 4; ++n) {
            acc[0][n] = __builtin_amdgcn_mfma_f32_16x16x32_bf16(a0, b[n], acc[0][n], 0, 0, 0);
            acc[1][n] = __builtin_amdgcn_mfma_f32_16x16x32_bf16(a1, b[n], acc[1][n], 0, 0, 0);
        }
    }

    __syncthreads();
    unsigned short* ot = &ash[0][0];
    float s[4] = {0.f, 0.f, 0.f, 0.f}, q[4] = {0.f, 0.f, 0.f, 0.f};
#pragma unroll
    for (int n = 0; n < 4; ++n) {
        int col = wn * 64 + n * 16 + lr;
        float bias = bn[col];
#pragma unroll
        for (int m = 0; m < 2; ++m) {
            int rowb = wm * 32 + m * 16 + lg * 4;
#pragma unroll
            for (int r = 0; r < 4; ++r) {
                int row = n0 + rowb + r;
                float v = acc[m][n][r] + bias;
                v = v > 0.f ? v : 0.f;
                ot[(rowb + r) * 136 + col] = f2bf(v);
                if (row < N) { s[n] += v; q[n] += v * v; }
            }
        }
    }
#pragma unroll
    for (int n = 0; n < 4; ++n) {
        s[n] += __shfl_xor(s[n], 16, 64);
        s[n] += __shfl_xor(s[n], 32, 64);
        q[n] += __shfl_xor(q[n], 16, 64);
        q[n] += __shfl_xor(q[n], 32, 64);
    }
    if (lane < 16) {
#pragma unroll
        for (int n = 0; n < 4; ++n) {
            sbuf[wid][n * 16 + lane] = s[n];
            qbuf[wid][n * 16 + lane] = q[n];
        }
    }
    __syncthreads();
    for (int q2 = t; q2 < 64 * 16; q2 += 256) {
        int r = q2 >> 4, c = q2 & 15;
        int row = n0 + r;
        if (row < N)
            *reinterpret_cast<uint4*>(&nupd_bf[(size_t)row * 128 + c * 8]) =
                *reinterpret_cast<const uint4*>(&ot[r * 136 + c * 8]);
    }
    if (t < 128) {
        int half = t >> 6, c = t & 63;
        part[(size_t)blockIdx.x * 256 + t] = sbuf[half][c] + sbuf[2 + half][c];
        part[(size_t)blockIdx.x * 256 + 128 + t] = qbuf[half][c] + qbuf[2 + half][c];
    }
}

// ---------------- BN finalize: scale/shift per column ----------------
__global__ void k_bn_fin(const float* __restrict__ part, int nblk, float invcnt,
                         const float* __restrict__ g, const float* __restrict__ b,
                         float* __restrict__ scale, float* __restrict__ shift) {
    int u = blockIdx.x;               // 128 blocks
    int t = threadIdx.x;              // 256
    float s = 0.f, q = 0.f;
    for (int i = t; i < nblk; i += 256) {
        s += part[(size_t)i * 256 + u];
        q += part[(size_t)i * 256 + 128 + u];
    }
    __shared__ float ls[4], lq[4];
    for (int o = 32; o > 0; o >>= 1) {
        s += __shfl_down(s, o, 64);
        q += __shfl_down(q, o, 64);
    }
    int lane = t & 63, w = t >> 6;
    if (lane == 0) { ls[w] = s; lq[w] = q; }
    __syncthreads();
    if (t == 0) {
        float S = ls[0] + ls[1] + ls[2] + ls[3];
        float Q = lq[0] + lq[1] + lq[2] + lq[3];
        float mean = S * invcnt;
        float var = Q * invcnt - mean * mean;
        float inv = rsqrtf(var + BN_EPS);
        float sc = g[u] * inv;
        scale[u] = sc;
        shift[u] = b[u] - mean * sc;
    }
}

// ---------------- edge finalize: wave=2 edges, lane=4 cols; BN apply + s_edge ----------------
__global__ void __launch_bounds__(256) k_edge_final(
        const unsigned short* __restrict__ ebuf, const float* __restrict__ scale,
        const float* __restrict__ shift, const float* __restrict__ aatt,
        float* __restrict__ eout, float* __restrict__ s_edge) {
    int t = threadIdx.x;
    int w = t >> 6, lane = t & 63;
    int q = lane & 31, half = lane >> 5;
    int e = blockIdx.x * 8 + w * 2 + half;

    float4 sc = *reinterpret_cast<const float4*>(scale + q * 4);
    float4 sh = *reinterpret_cast<const float4*>(shift + q * 4);
    float4 a4[8];
#pragma unroll
    for (int h = 0; h < 8; ++h)
        a4[h] = *reinterpret_cast<const float4*>(aatt + h * 384 + 256 + q * 4);

    ushort4 xb = *reinterpret_cast<const ushort4*>(ebuf + (size_t)e * 128 + q * 4);
    float4 x;
    x.x = bf2f(xb.x) * sc.x + sh.x;
    x.y = bf2f(xb.y) * sc.y + sh.y;
    x.z = bf2f(xb.z) * sc.z + sh.z;
    x.w = bf2f(xb.w) * sc.w + sh.w;
    *reinterpret_cast<float4*>(eout + (size_t)e * 128 + q * 4) = x;

    float v[8];
#pragma unroll
    for (int h = 0; h < 8; ++h)
        v[h] = x.x * a4[h].x + x.y * a4[h].y + x.z * a4[h].z + x.w * a4[h].w;
#pragma unroll
    for (int o = 1; o < 32; o <<= 1) {
#pragma unroll
        for (int h = 0; h < 8; ++h) v[h] += __shfl_xor(v[h], o, 64);
    }
    if (q == 0) {
#pragma unroll
        for (int h = 0; h < 8; ++h) s_edge[e * 8 + h] = v[h];
    }
}

// ---------------- attention softmax + aggregation; writes bf16 into cat[:,0:128] ----------------
__global__ void k_agg(const unsigned short* __restrict__ zbf, const float* __restrict__ s_src,
                      const float* __restrict__ s_dst, const float* __restrict__ s_edge,
                      const int* __restrict__ off, const int* __restrict__ elist,
                      const int* __restrict__ eidx, unsigned short* __restrict__ cat) {
    int n = blockIdx.x;
    int t = threadIdx.x;              // 128
    int beg = off[n], end = off[n + 1];
    int deg = end - beg;
    if (deg == 0) { cat[(size_t)n * 256 + t] = 0; return; }

    float sdh[8];
#pragma unroll
    for (int h = 0; h < 8; ++h) sdh[h] = s_dst[n * 8 + h];

    __shared__ float lred[16];
    __shared__ float wbuf[128][8];
    __shared__ int snbuf[128];

    float mx[8], den[8];
#pragma unroll
    for (int h = 0; h < 8; ++h) { mx[h] = -1e30f; den[h] = 0.f; }

    int lane = t & 63, w = t >> 6;

    // pass 1: running max / denominator (online across chunks of 128)
    for (int c0 = 0; c0 < deg; c0 += 128) {
        int cn = min(128, deg - c0);
        bool act = t < cn;
        int e = 0, sn = 0;
        if (act) { e = elist[beg + c0 + t]; sn = eidx[2 * e + 1]; }
        float lg[8];
#pragma unroll
        for (int h = 0; h < 8; ++h) {
            float x = act ? (s_src[sn * 8 + h] + sdh[h] + s_edge[e * 8 + h]) : -1e30f;
            lg[h] = x >= 0.f ? x : 0.2f * x;
        }
        float cm[8];
#pragma unroll
        for (int h = 0; h < 8; ++h) cm[h] = lg[h];
        for (int o = 32; o > 0; o >>= 1) {
#pragma unroll
            for (int h = 0; h < 8; ++h) cm[h] = fmaxf(cm[h], __shfl_down(cm[h], o, 64));
        }
        if (lane == 0) {
#pragma unroll
            for (int h = 0; h < 8; ++h) lred[w * 8 + h] = cm[h];
        }
        __syncthreads();
#pragma unroll
        for (int h = 0; h < 8; ++h) cm[h] = fmaxf(lred[h], lred[8 + h]);
        __syncthreads();
        float cs[8];
#pragma unroll
        for (int h = 0; h < 8; ++h) cs[h] = act ? __expf(lg[h] - cm[h]) : 0.f;
        for (int o = 32; o > 0; o >>= 1) {
#pragma unroll
            for (int h = 0; h < 8; ++h) cs[h] += __shfl_down(cs[h], o, 64);
        }
        if (lane == 0) {
#pragma unroll
            for (int h = 0; h < 8; ++h) lred[w * 8 + h] = cs[h];
        }
        __syncthreads();
#pragma unroll
        for (int h = 0; h < 8; ++h) {
            float csum = lred[h] + lred[8 + h];
            float nm = fmaxf(mx[h], cm[h]);
            den[h] = den[h] * __expf(mx[h] - nm) + csum * __expf(cm[h] - nm);
            mx[h] = nm;
        }
        __syncthreads();
    }
    float inv[8];
#pragma unroll
    for (int h = 0; h < 8; ++h) inv[h] = 1.f / den[h];

    // pass 2: weights into LDS, then accumulate sum over heads of alpha*z[src]
    float acc = 0.f;
    for (int c0 = 0; c0 < deg; c0 += 128) {
        int cn = min(128, deg - c0);
        if (t < cn) {
            int e = elist[beg + c0 + t];
            int sn = eidx[2 * e + 1];
            snbuf[t] = sn;
#pragma unroll
            for (int h = 0; h < 8; ++h) {
                float x = s_src[sn * 8 + h] + sdh[h] + s_edge[e * 8 + h];
                x = x >= 0.f ? x : 0.2f * x;
                wbuf[t][h] = __expf(x - mx[h]) * inv[h];
            }
        }
        __syncthreads();
        for (int i = 0; i < cn; ++i) {
            int sn = snbuf[i];
            const unsigned short* zr = zbf + (size_t)sn * 1024 + t;
#pragma unroll
            for (int h = 0; h < 8; ++h)
                acc = fmaf(wbuf[i][h], bf2f(zr[h * 128]), acc);
        }
        __syncthreads();
    }
    cat[(size_t)n * 256 + t] = f2bf(fmaxf(acc * 0.125f, 0.f));
}

// ---------------- GRU pre: ush = BN(nupd_bf); cat[:,128:256] = bf16(ush) ----------------
__global__ void k_gru_pre(const unsigned short* __restrict__ nupd_bf, const float* __restrict__ scale,
                          const float* __restrict__ shift, unsigned short* __restrict__ cat,
                          float* __restrict__ ush) {
    int i = blockIdx.x * 256 + threadIdx.x;   // over NN*32
    if (i >= NN * 32) return;
    int n = i >> 5, j4 = (i & 31) * 4;
    ushort4 ub_in = *reinterpret_cast<const ushort4*>(nupd_bf + (size_t)n * 128 + j4);
    float4 sc = *reinterpret_cast<const float4*>(scale + j4);
    float4 sh = *reinterpret_cast<const float4*>(shift + j4);
    float4 uv;
    uv.x = bf2f(ub_in.x) * sc.x + sh.x;
    uv.y = bf2f(ub_in.y) * sc.y + sh.y;
    uv.z = bf2f(ub_in.z) * sc.z + sh.z;
    uv.w = bf2f(ub_in.w) * sc.w + sh.w;
    ushort4 ub;
    ub.x = f2bf(uv.x); ub.y = f2bf(uv.y); ub.z = f2bf(uv.z); ub.w = f2bf(uv.w);
    *reinterpret_cast<ushort4*>(cat + (size_t)n * 256 + 128 + j4) = ub;
    *reinterpret_cast<float4*>(ush + (size_t)n * 128 + j4) = uv;
}

// ---------------- GRU GEMM: S = cat @ Wc  (M x 256 x 512), MFMA, LDS-coalesced store ----------------
__global__ void __launch_bounds__(256) k_gru_mm(
        const unsigned short* __restrict__ cat, const unsigned short* __restrict__ WcT,
        float* __restrict__ S, int N) {
    __shared__ unsigned short ash[64][264];     // 256 + 8 pad (33792 B)
    int n0 = blockIdx.x * 64;
    int g = blockIdx.y;                          // col group 0..3
    int t = threadIdx.x;
    for (int q = t; q < 64 * 32; q += 256) {
        int r = q >> 5, c = q & 31;
        int n = n0 + r; if (n >= N) n = N - 1;
        *reinterpret_cast<uint4*>(&ash[r][c * 8]) =
            *reinterpret_cast<const uint4*>(cat + (size_t)n * 256 + c * 8);
    }
    __syncthreads();

    int wid = t >> 6, lane = t & 63;
    int wm = wid >> 1, wn = wid & 1;
    int lr = lane & 15, lg = lane >> 4;

    f32x4 acc[2][4];
#pragma unroll
    for (int m = 0; m < 2; ++m)
#pragma unroll
        for (int n = 0; n < 4; ++n) acc[m][n] = (f32x4){0.f, 0.f, 0.f, 0.f};

    const unsigned short* Wg = WcT + (size_t)g * 128 * 256;
#pragma unroll
    for (int ks = 0; ks < 8; ++ks) {
        int kb = ks * 32 + lg * 8;
        bf16x8 a0 = *reinterpret_cast<const bf16x8*>(&ash[wm * 32 + lr][kb]);
        bf16x8 a1 = *reinterpret_cast<const bf16x8*>(&ash[wm * 32 + 16 + lr][kb]);
        bf16x8 b[4];
#pragma unroll
        for (int n = 0; n < 4; ++n)
            b[n] = *reinterpret_cast<const bf16x8*>(Wg + (size_t)(wn * 64 + n * 16 + lr) * 256 + kb);
#pragma unroll
        for (int n = 0; n < 4; ++n) {
            acc[0][n] = __builtin_amdgcn_mfma_f32_16x16x32_bf16(a0, b[n], acc[0][n], 0, 0, 0);
            acc[1][n] = __builtin_amdgcn_mfma_f32_16x16x32_bf16(a1, b[n], acc[1][n], 0, 0, 0);
        }
    }

    __syncthreads();
    float* otf = reinterpret_cast<float*>(&ash[0][0]);   // [64][132] f32 (33792 B)
#pragma unroll
    for (int n = 0; n < 4; ++n) {
        int col = wn * 64 + n * 16 + lr;
#pragma unroll
        for (int m = 0; m < 2; ++m) {
            int rowb = wm * 32 + m * 16 + lg * 4;
#pragma unroll
            for (int r = 0; r < 4; ++r)
                otf[(rowb + r) * 132 + col] = acc[m][n][r];
        }
    }
    __syncthreads();
    for (int q = t; q < 64 * 32; q += 256) {
        int r = q >> 5, c = q & 31;
        int row = n0 + r;
        if (row < N)
            *reinterpret_cast<float4*>(&S[(size_t)row * 512 + g * 128 + c * 4]) =
                *reinterpret_cast<const float4*>(&otf[r * 132 + c * 4]);
    }
}

// ---------------- GRU gates: sigmoid/tanh + combine ----------------
__global__ void __launch_bounds__(256) k_gru_gates(
        const float* __restrict__ S, const float* __restrict__ ush,
        const float* __restrict__ gbias, float* __restrict__ outp) {
    int t = threadIdx.x;
    int n = blockIdx.x * 2 + (t >> 7);
    int u = t & 127;
    const float* b0 = gbias;
    const float* b1 = gbias + 384;
    float s0 = S[(size_t)n * 512 + u];
    float s1 = S[(size_t)n * 512 + 128 + u];
    float xh = S[(size_t)n * 512 + 256 + u];
    float rh = S[(size_t)n * 512 + 384 + u];
    float zg = 1.f / (1.f + __expf(-(s0 + b0[u] + b1[u])));
    float rg = 1.f / (1.f + __expf(-(s1 + b0[128 + u] + b1[128 + u])));
    float hh = tanhf(xh + b0[256 + u] + rg * (rh + b1[256 + u]));
    float uv = ush[(size_t)n * 128 + u];
    outp[(size_t)n * 128 + u] = zg * uv + (1.f - zg) * hh;
}

// ---------------- launch ----------------
extern "C" void kernel_launch(void* const* d_in, const int* in_sizes, int n_in,
                              void* d_out, int out_size, void* d_ws, size_t ws_size,
                              hipStream_t stream) {
    const float* node    = (const float*)d_in[0];
    const float* eattr   = (const float*)d_in[1];
    const int*   eidx    = (const int*)d_in[2];
    const float* We      = (const float*)d_in[3];
    const float* be      = (const float*)d_in[4];
    const float* gamma_e = (const float*)d_in[5];
    const float* beta_e  = (const float*)d_in[6];
    const float* Wn      = (const float*)d_in[7];
    const float* bnb     = (const float*)d_in[8];
    const float* gamma_n = (const float*)d_in[9];
    const float* beta_n  = (const float*)d_in[10];
    const float* Watt    = (const float*)d_in[11];
    const float* batt    = (const float*)d_in[12];
    const float* aatt    = (const float*)d_in[13];
    const float* Wk      = (const float*)d_in[14];
    const float* Wr      = (const float*)d_in[15];
    const float* gbias   = (const float*)d_in[16];

    float* out_node = (float*)d_out;
    float* out_edge = out_node + (size_t)NN * UU;

    char* wp = (char*)d_ws;
    auto alloc = [&](size_t bytes) {
        void* p = (void*)wp;
        wp += (bytes + 255) / 256 * 256;
        return p;
    };
    // zbf (bf16, 20.5MB) shares a region with eattr_bf (bf16, 41MB); eattr_bf dead before k_z_mfma
    unsigned short* zregion = (unsigned short*)alloc((size_t)EE * 128 * 2);
    unsigned short* zbf      = zregion;
    unsigned short* eattr_bf = zregion;
    unsigned short* ebuf = (unsigned short*)alloc((size_t)EE * 128 * 2);
    float* s_src   = (float*)alloc((size_t)NN * 8 * 4);
    float* s_dst   = (float*)alloc((size_t)NN * 8 * 4);
    float* s_edge  = (float*)alloc((size_t)EE * 8 * 4);
    float* part_e  = (float*)alloc((size_t)5000 * 256 * 4);
    float* part_n  = (float*)alloc((size_t)157 * 256 * 4);
    float* scale_e = (float*)alloc(512);
    float* shift_e = (float*)alloc(512);
    float* scale_n = (float*)alloc(512);
    float* shift_n = (float*)alloc(512);
    unsigned short* nupd_bf = (unsigned short*)alloc((size_t)NN * 128 * 2);
    float* ush     = (float*)alloc((size_t)NN * 128 * 4);
    float* Sbuf    = (float*)alloc((size_t)NN * 512 * 4);
    int*   cnt     = (int*)alloc((size_t)NN * 4);
    int*   offs    = (int*)alloc((size_t)(NN + 1) * 4);
    int*   cursor  = (int*)alloc((size_t)NN * 4);
    int*   elist   = (int*)alloc((size_t)EE * 4);
    unsigned short* node_bf = (unsigned short*)alloc((size_t)NN * 128 * 2);
    unsigned short* Wt      = (unsigned short*)alloc((size_t)128 * 384 * 2);
    unsigned short* WtA     = (unsigned short*)alloc((size_t)8 * 128 * 128 * 2);
    unsigned short* WnT     = (unsigned short*)alloc((size_t)128 * 128 * 2);
    unsigned short* WcT     = (unsigned short*)alloc((size_t)512 * 256 * 2);
    unsigned short* cat     = (unsigned short*)alloc((size_t)NN * 256 * 2);

    hipMemsetAsync(cnt, 0, (size_t)NN * 4, stream);
    k_hist<<<(EE + 255) / 256, 256, 0, stream>>>(eidx, cnt, EE);
    k_scan<<<1, 1024, 0, stream>>>(cnt, offs, cursor, NN);
    k_scatter<<<(EE + 255) / 256, 256, 0, stream>>>(eidx, cursor, elist, EE);

    // bf16 conversions
    k_f2bf<<<1280, 256, 0, stream>>>(node, node_bf, (long)NN * 128 / 4);
    k_f2bf<<<2048, 256, 0, stream>>>(eattr, eattr_bf, (long)EE * 128 / 4);
    k_wtg<<<(384 * 128 + 255) / 256, 256, 0, stream>>>(We, Wt, 384, 128);
    k_wtg<<<(128 * 128 + 255) / 256, 256, 0, stream>>>(Wn, WnT, 128, 128);
    k_wt_att<<<(8 * 128 * 128 + 255) / 256, 256, 0, stream>>>(Watt, WtA);
    k_wt_gru<<<(512 * 256 + 255) / 256, 256, 0, stream>>>(Wk, Wr, WcT);

    // edge pipeline (uses eattr_bf which aliases zbf; must precede k_z_mfma)
    k_edge_mlp_mfma<<<EE / 32, 256, 0, stream>>>(node_bf, eattr_bf, eidx, Wt, be, ebuf, part_e);
    k_bn_fin<<<128, 256, 0, stream>>>(part_e, EE / 32, 1.f / (float)EE,
                                      gamma_e, beta_e, scale_e, shift_e);
    k_edge_final<<<EE / 8, 256, 0, stream>>>(ebuf, scale_e, shift_e, aatt, out_edge, s_edge);

    // node/attention pipeline
    k_z_mfma<<<dim3((NN + 63) / 64, 8), 256, 0, stream>>>(node_bf, WtA, batt, zbf, NN);
    k_snodes<<<NN / 4, 256, 0, stream>>>(zbf, aatt, s_src, s_dst, NN);
    k_agg<<<NN, 128, 0, stream>>>(zbf, s_src, s_dst, s_edge, offs, elist, eidx, cat);

    // node MLP + BN
    k_node_mlp_mfma<<<(NN + 63) / 64, 256, 0, stream>>>(node_bf, WnT, bnb, nupd_bf, part_n, NN);
    k_bn_fin<<<128, 256, 0, stream>>>(part_n, (NN + 63) / 64, 1.f / (float)NN,
                                      gamma_n, beta_n, scale_n, shift_n);

    // GRU
    k_gru_pre<<<(NN * 32 + 255) / 256, 256, 0, stream>>>(nupd_bf, scale_n, shift_n, cat, ush);
    k_gru_mm<<<dim3((NN + 63) / 64, 4), 256, 0, stream>>>(cat, WcT, Sbuf, NN);
    k_gru_gates<<<NN / 2, 256, 0, stream>>>(Sbuf, ush, gbias, out_node);
}

// Round 8
// 338.161 us; speedup vs baseline: 1.1222x; 1.1222x over previous
//
#include <hip/hip_runtime.h>
#include <hip/hip_bf16.h>

#define NN 10000
#define EE 160000
#define FF 128
#define UU 128
#define HH 8
#define BN_EPS 1e-3f

typedef __attribute__((ext_vector_type(8))) short bf16x8;
typedef __attribute__((ext_vector_type(8))) unsigned short u16x8;
typedef __attribute__((ext_vector_type(4))) float f32x4;

static __device__ __forceinline__ unsigned short f2bf(float f) {
    unsigned u = __float_as_uint(f);
    u += 0x7fffu + ((u >> 16) & 1u);
    return (unsigned short)(u >> 16);
}
static __device__ __forceinline__ float bf2f(unsigned short b) {
    return __uint_as_float((unsigned)b << 16);
}

// ---------------- f32 -> bf16 bulk convert (count divisible by 4) ----------------
__global__ void k_f2bf(const float* __restrict__ in, unsigned short* __restrict__ out, long n4) {
    long i = (long)blockIdx.x * 256 + threadIdx.x;
    long stride = (long)gridDim.x * 256;
    for (; i < n4; i += stride) {
        float4 v = reinterpret_cast<const float4*>(in)[i];
        ushort4 o;
        o.x = f2bf(v.x); o.y = f2bf(v.y); o.z = f2bf(v.z); o.w = f2bf(v.w);
        reinterpret_cast<ushort4*>(out)[i] = o;
    }
}

// ---------------- generic W [K][U] f32 -> W^T [U][K] bf16 ----------------
__global__ void k_wtg(const float* __restrict__ W, unsigned short* __restrict__ Wt, int K, int U) {
    int i = blockIdx.x * 256 + threadIdx.x;
    if (i < K * U) {
        int k = i / U, u = i - k * U;
        Wt[u * K + k] = f2bf(W[i]);
    }
}

// ---------------- W_att [8][128][128] f32 -> per-head W^T [8][128][128] bf16 ----------------
__global__ void k_wt_att(const float* __restrict__ W, unsigned short* __restrict__ Wt) {
    int i = blockIdx.x * 256 + threadIdx.x;   // over 8*128*128
    if (i < 8 * 128 * 128) {
        int h = i >> 14, rem = i & 16383, f = rem >> 7, u = rem & 127;
        Wt[h * 16384 + u * 128 + f] = f2bf(W[i]);
    }
}

// ---------------- GRU combined weight: WcT [512][256] bf16 ----------------
__global__ void k_wt_gru(const float* __restrict__ Wk, const float* __restrict__ Wr,
                         unsigned short* __restrict__ WcT) {
    int i = blockIdx.x * 256 + threadIdx.x;   // over 512*256
    if (i >= 512 * 256) return;
    int c = i >> 8, k = i & 255;
    float v;
    if (c < 256)       v = (k < 128) ? Wk[k * 384 + c] : Wr[(k - 128) * 384 + c];
    else if (c < 384)  v = (k < 128) ? Wk[k * 384 + c] : 0.f;
    else               v = (k < 128) ? 0.f : Wr[(k - 128) * 384 + (c - 128)];
    WcT[c * 256 + k] = f2bf(v);
}

// ---------------- CSR construction ----------------
__global__ void k_hist(const int* __restrict__ eidx, int* __restrict__ cnt, int E) {
    int e = blockIdx.x * 256 + threadIdx.x;
    if (e < E) atomicAdd(&cnt[eidx[2 * e]], 1);   // dst = eidx[e][0]
}

__global__ void k_scan(const int* __restrict__ cnt, int* __restrict__ off,
                       int* __restrict__ cursor, int N) {
    __shared__ int s[1024];
    int t = threadIdx.x;
    int run = 0;
    if (t == 0) off[0] = 0;
    for (int base = 0; base < N; base += 1024) {
        int x = (base + t < N) ? cnt[base + t] : 0;
        s[t] = x;
        __syncthreads();
        for (int o = 1; o < 1024; o <<= 1) {
            int v = (t >= o) ? s[t - o] : 0;
            __syncthreads();
            s[t] += v;
            __syncthreads();
        }
        if (base + t < N) {
            off[base + t + 1] = run + s[t];
            cursor[base + t] = run + s[t] - x;
        }
        run += s[1023];
        __syncthreads();
    }
}

__global__ void k_scatter(const int* __restrict__ eidx, int* __restrict__ cursor,
                          int* __restrict__ elist, int E) {
    int e = blockIdx.x * 256 + threadIdx.x;
    if (e < E) {
        int d = eidx[2 * e];
        int p = atomicAdd(&cursor[d], 1);
        elist[p] = e;
    }
}

// ---------------- z (bf16) = node @ W_att[h] + b_att[h], MFMA, LDS-coalesced store ----------------
__global__ void __launch_bounds__(256) k_z_mfma(
        const unsigned short* __restrict__ node_bf, const unsigned short* __restrict__ WtA,
        const float* __restrict__ batt, unsigned short* __restrict__ zbf, int N) {
    __shared__ unsigned short ash[64][136];     // 128 + 8 pad
    int n0 = blockIdx.x * 64;
    int h = blockIdx.y;
    int t = threadIdx.x;
    for (int q = t; q < 64 * 16; q += 256) {
        int r = q >> 4, c = q & 15;
        int n = n0 + r; if (n >= N) n = N - 1;
        *reinterpret_cast<uint4*>(&ash[r][c * 8]) =
            *reinterpret_cast<const uint4*>(node_bf + (size_t)n * 128 + c * 8);
    }
    __syncthreads();

    int wid = t >> 6, lane = t & 63;
    int wm = wid >> 1, wn = wid & 1;
    int lr = lane & 15, lg = lane >> 4;

    f32x4 acc[2][4];
#pragma unroll
    for (int m = 0; m < 2; ++m)
#pragma unroll
        for (int n = 0; n < 4; ++n) acc[m][n] = (f32x4){0.f, 0.f, 0.f, 0.f};

    const unsigned short* Wh = WtA + (size_t)h * 16384;
#pragma unroll
    for (int ks = 0; ks < 4; ++ks) {
        int kb = ks * 32 + lg * 8;
        bf16x8 a0 = *reinterpret_cast<const bf16x8*>(&ash[wm * 32 + lr][kb]);
        bf16x8 a1 = *reinterpret_cast<const bf16x8*>(&ash[wm * 32 + 16 + lr][kb]);
        bf16x8 b[4];
#pragma unroll
        for (int n = 0; n < 4; ++n)
            b[n] = *reinterpret_cast<const bf16x8*>(Wh + (size_t)(wn * 64 + n * 16 + lr) * 128 + kb);
#pragma unroll
        for (int n = 0; n < 4; ++n) {
            acc[0][n] = __builtin_amdgcn_mfma_f32_16x16x32_bf16(a0, b[n], acc[0][n], 0, 0, 0);
            acc[1][n] = __builtin_amdgcn_mfma_f32_16x16x32_bf16(a1, b[n], acc[1][n], 0, 0, 0);
        }
    }

    __syncthreads();                      // A-tile reads done; reuse ash as C-tile
    unsigned short* ot = &ash[0][0];      // [64][136]
#pragma unroll
    for (int n = 0; n < 4; ++n) {
        int col = wn * 64 + n * 16 + lr;
        float bias = batt[h * 128 + col];
#pragma unroll
        for (int m = 0; m < 2; ++m) {
            int rowb = wm * 32 + m * 16 + lg * 4;
#pragma unroll
            for (int r = 0; r < 4; ++r)
                ot[(rowb + r) * 136 + col] = f2bf(acc[m][n][r] + bias);
        }
    }
    __syncthreads();
    for (int q = t; q < 64 * 16; q += 256) {
        int r = q >> 4, c = q & 15;
        int row = n0 + r;
        if (row < N)
            *reinterpret_cast<uint4*>(&zbf[(size_t)row * 1024 + h * 128 + c * 8]) =
                *reinterpret_cast<const uint4*>(&ot[r * 136 + c * 8]);
    }
}

// ---------------- s_src[n,h], s_dst[n,h]: wave=node, lane=(head, 16-col slice) ----------------
__global__ void __launch_bounds__(256) k_snodes(
        const unsigned short* __restrict__ zbf, const float* __restrict__ aatt,
        float* __restrict__ s_src, float* __restrict__ s_dst, int N) {
    int t = threadIdx.x;
    int w = t >> 6, lane = t & 63;
    int n = blockIdx.x * 4 + w;
    if (n >= N) return;
    int h = lane >> 3, p = lane & 7;
    const unsigned short* zp = zbf + (size_t)n * 1024 + h * 128 + p * 16;
    const float* as = aatt + h * 384 + p * 16;
    u16x8 z0 = *reinterpret_cast<const u16x8*>(zp);
    u16x8 z1 = *reinterpret_cast<const u16x8*>(zp + 8);
    float vs = 0.f, vd = 0.f;
#pragma unroll
    for (int j = 0; j < 8; ++j) {
        float zv = bf2f(z0[j]);
        vs = fmaf(zv, as[j], vs);
        vd = fmaf(zv, as[128 + j], vd);
    }
#pragma unroll
    for (int j = 0; j < 8; ++j) {
        float zv = bf2f(z1[j]);
        vs = fmaf(zv, as[8 + j], vs);
        vd = fmaf(zv, as[136 + j], vd);
    }
#pragma unroll
    for (int o = 1; o < 8; o <<= 1) {
        vs += __shfl_xor(vs, o, 64);
        vd += __shfl_xor(vd, o, 64);
    }
    if (p == 0) {
        s_src[n * 8 + h] = vs;
        s_dst[n * 8 + h] = vd;
    }
}

// ---------------- edge MLP: 128-edge x 128-col tile, 8 waves, global_load_lds staging ----------------
__global__ void __launch_bounds__(512) k_edge_mlp_mfma(
        const unsigned short* __restrict__ node_bf, const unsigned short* __restrict__ eattr_bf,
        const int* __restrict__ eidx, const unsigned short* __restrict__ Wt,
        const float* __restrict__ be, unsigned short* __restrict__ ebuf, float* __restrict__ part) {
    __shared__ unsigned short ash[128][392];    // 384 + 8 pad (100352 B)
    __shared__ int sd[256];
    __shared__ float sbuf[8][64], qbuf[8][64];
    int e0 = blockIdx.x * 128;
    int t = threadIdx.x;
    if (t < 256) sd[t] = eidx[e0 * 2 + t];      // [e][0]=dst, [e][1]=src
    __syncthreads();

    int wid = t >> 6, lane = t & 63;

    // staging: wave wid stages rows wid*16 .. wid*16+15 via global_load_lds (48 lanes x 16B per row)
#pragma unroll
    for (int i = 0; i < 16; ++i) {
        int r = wid * 16 + i;
        const unsigned short* g;
        if (lane < 16)      g = node_bf + (size_t)sd[r * 2 + 1] * 128 + lane * 8;
        else if (lane < 32) g = node_bf + (size_t)sd[r * 2] * 128 + (lane - 16) * 8;
        else                g = eattr_bf + (size_t)(e0 + r) * 128 + (lane - 32) * 8;
        if (lane < 48)
            __builtin_amdgcn_global_load_lds(
                (const __attribute__((address_space(1))) unsigned int*)g,
                (__attribute__((address_space(3))) unsigned int*)&ash[r][0],
                16, 0, 0);
    }
    __syncthreads();

    int wm = wid >> 1, wn = wid & 1;            // wave tile: rows wm*32.., cols wn*64..
    int lr = lane & 15, lg = lane >> 4;

    f32x4 acc[2][4];
#pragma unroll
    for (int m = 0; m < 2; ++m)
#pragma unroll
        for (int n = 0; n < 4; ++n) acc[m][n] = (f32x4){0.f, 0.f, 0.f, 0.f};

#pragma unroll
    for (int ks = 0; ks < 12; ++ks) {
        int kb = ks * 32 + lg * 8;
        bf16x8 a0 = *reinterpret_cast<const bf16x8*>(&ash[wm * 32 + lr][kb]);
        bf16x8 a1 = *reinterpret_cast<const bf16x8*>(&ash[wm * 32 + 16 + lr][kb]);
        bf16x8 b[4];
#pragma unroll
        for (int n = 0; n < 4; ++n)
            b[n] = *reinterpret_cast<const bf16x8*>(Wt + (size_t)(wn * 64 + n * 16 + lr) * 384 + kb);
#pragma unroll
        for (int n = 0; n < 4; ++n) {
            acc[0][n] = __builtin_amdgcn_mfma_f32_16x16x32_bf16(a0, b[n], acc[0][n], 0, 0, 0);
            acc[1][n] = __builtin_amdgcn_mfma_f32_16x16x32_bf16(a1, b[n], acc[1][n], 0, 0, 0);
        }
    }

    __syncthreads();                      // A-tile reads done; reuse ash as C-tile [128][136]
    unsigned short* ot = &ash[0][0];
    float s[4] = {0.f, 0.f, 0.f, 0.f}, q[4] = {0.f, 0.f, 0.f, 0.f};
#pragma unroll
    for (int n = 0; n < 4; ++n) {
        int col = wn * 64 + n * 16 + lr;
        float bias = be[col];
#pragma unroll
        for (int m = 0; m < 2; ++m) {
            int rowb = wm * 32 + m * 16 + lg * 4;
#pragma unroll
            for (int r = 0; r < 4; ++r) {
                float v = acc[m][n][r] + bias;
                v = v > 0.f ? v : 0.f;
                ot[(rowb + r) * 136 + col] = f2bf(v);
                s[n] += v;
                q[n] += v * v;
            }
        }
    }
#pragma unroll
    for (int n = 0; n < 4; ++n) {
        s[n] += __shfl_xor(s[n], 16, 64);
        s[n] += __shfl_xor(s[n], 32, 64);
        q[n] += __shfl_xor(q[n], 16, 64);
        q[n] += __shfl_xor(q[n], 32, 64);
    }
    if (lane < 16) {
#pragma unroll
        for (int n = 0; n < 4; ++n) {
            sbuf[wid][n * 16 + lane] = s[n];
            qbuf[wid][n * 16 + lane] = q[n];
        }
    }
    __syncthreads();
    for (int q2 = t; q2 < 128 * 16; q2 += 512) {
        int r = q2 >> 4, c = q2 & 15;
        *reinterpret_cast<uint4*>(&ebuf[(size_t)(e0 + r) * 128 + c * 8]) =
            *reinterpret_cast<const uint4*>(&ot[r * 136 + c * 8]);
    }
    if (t < 128) {
        int c = t & 63, half = t >> 6;   // half = wn of col t
        float ssum = 0.f, qsum = 0.f;
#pragma unroll
        for (int k = 0; k < 4; ++k) {
            ssum += sbuf[half + 2 * k][c];
            qsum += qbuf[half + 2 * k][c];
        }
        part[(size_t)blockIdx.x * 256 + t] = ssum;
        part[(size_t)blockIdx.x * 256 + 128 + t] = qsum;
    }
}

// ---------------- node MLP via MFMA: relu(node @ W_node + b) -> bf16, BN partials ----------------
__global__ void __launch_bounds__(256) k_node_mlp_mfma(
        const unsigned short* __restrict__ node_bf, const unsigned short* __restrict__ WnT,
        const float* __restrict__ bn, unsigned short* __restrict__ nupd_bf,
        float* __restrict__ part, int N) {
    __shared__ unsigned short ash[64][136];
    __shared__ float sbuf[4][64], qbuf[4][64];
    int n0 = blockIdx.x * 64;
    int t = threadIdx.x;
    for (int q = t; q < 64 * 16; q += 256) {
        int r = q >> 4, c = q & 15;
        int n = n0 + r; if (n >= N) n = N - 1;
        *reinterpret_cast<uint4*>(&ash[r][c * 8]) =
            *reinterpret_cast<const uint4*>(node_bf + (size_t)n * 128 + c * 8);
    }
    __syncthreads();

    int wid = t >> 6, lane = t & 63;
    int wm = wid >> 1, wn = wid & 1;
    int lr = lane & 15, lg = lane >> 4;

    f32x4 acc[2][4];
#pragma unroll
    for (int m = 0; m < 2; ++m)
#pragma unroll
        for (int n = 0; n < 4; ++n) acc[m][n] = (f32x4){0.f, 0.f, 0.f, 0.f};

#pragma unroll
    for (int ks = 0; ks < 4; ++ks) {
        int kb = ks * 32 + lg * 8;
        bf16x8 a0 = *reinterpret_cast<const bf16x8*>(&ash[wm * 32 + lr][kb]);
        bf16x8 a1 = *reinterpret_cast<const bf16x8*>(&ash[wm * 32 + 16 + lr][kb]);
        bf16x8 b[4];
#pragma unroll
        for (int n = 0; n < 4; ++n)
            b[n] = *reinterpret_cast<const bf16x8*>(WnT + (size_t)(wn * 64 + n * 16 + lr) * 128 + kb);
#pragma unroll
        for (int n = 0; n < 4; ++n) {
            acc[0][n] = __builtin_amdgcn_mfma_f32_16x16x32_bf16(a0, b[n], acc[0][n], 0, 0, 0);
            acc[1][n] = __builtin_amdgcn_mfma_f32_16x16x32_bf16(a1, b[n], acc[1][n], 0, 0, 0);
        }
    }

    __syncthreads();
    unsigned short* ot = &ash[0][0];
    float s[4] = {0.f, 0.f, 0.f, 0.f}, q[4] = {0.f, 0.f, 0.f, 0.f};
#pragma unroll
    for (int n = 0; n < 4; ++n) {
        int col = wn * 64 + n * 16 + lr;
        float bias = bn[col];
#pragma unroll
        for (int m = 0; m < 2; ++m) {
            int rowb = wm * 32 + m * 16 + lg * 4;
#pragma unroll
            for (int r = 0; r < 4; ++r) {
                int row = n0 + rowb + r;
                float v = acc[m][n][r] + bias;
                v = v > 0.f ? v : 0.f;
                ot[(rowb + r) * 136 + col] = f2bf(v);
                if (row < N) { s[n] += v; q[n] += v * v; }
            }
        }
    }
#pragma unroll
    for (int n = 0; n < 4; ++n) {
        s[n] += __shfl_xor(s[n], 16, 64);
        s[n] += __shfl_xor(s[n], 32, 64);
        q[n] += __shfl_xor(q[n], 16, 64);
        q[n] += __shfl_xor(q[n], 32, 64);
    }
    if (lane < 16) {
#pragma unroll
        for (int n = 0; n < 4; ++n) {
            sbuf[wid][n * 16 + lane] = s[n];
            qbuf[wid][n * 16 + lane] = q[n];
        }
    }
    __syncthreads();
    for (int q2 = t; q2 < 64 * 16; q2 += 256) {
        int r = q2 >> 4, c = q2 & 15;
        int row = n0 + r;
        if (row < N)
            *reinterpret_cast<uint4*>(&nupd_bf[(size_t)row * 128 + c * 8]) =
                *reinterpret_cast<const uint4*>(&ot[r * 136 + c * 8]);
    }
    if (t < 128) {
        int half = t >> 6, c = t & 63;
        part[(size_t)blockIdx.x * 256 + t] = sbuf[half][c] + sbuf[2 + half][c];
        part[(size_t)blockIdx.x * 256 + 128 + t] = qbuf[half][c] + qbuf[2 + half][c];
    }
}

// ---------------- BN finalize: scale/shift per column ----------------
__global__ void k_bn_fin(const float* __restrict__ part, int nblk, float invcnt,
                         const float* __restrict__ g, const float* __restrict__ b,
                         float* __restrict__ scale, float* __restrict__ shift) {
    int u = blockIdx.x;               // 128 blocks
    int t = threadIdx.x;              // 256
    float s = 0.f, q = 0.f;
    for (int i = t; i < nblk; i += 256) {
        s += part[(size_t)i * 256 + u];
        q += part[(size_t)i * 256 + 128 + u];
    }
    __shared__ float ls[4], lq[4];
    for (int o = 32; o > 0; o >>= 1) {
        s += __shfl_down(s, o, 64);
        q += __shfl_down(q, o, 64);
    }
    int lane = t & 63, w = t >> 6;
    if (lane == 0) { ls[w] = s; lq[w] = q; }
    __syncthreads();
    if (t == 0) {
        float S = ls[0] + ls[1] + ls[2] + ls[3];
        float Q = lq[0] + lq[1] + lq[2] + lq[3];
        float mean = S * invcnt;
        float var = Q * invcnt - mean * mean;
        float inv = rsqrtf(var + BN_EPS);
        float sc = g[u] * inv;
        scale[u] = sc;
        shift[u] = b[u] - mean * sc;
    }
}

// ---------------- edge finalize: wave=2 edges, lane=4 cols; BN apply + s_edge ----------------
__global__ void __launch_bounds__(256) k_edge_final(
        const unsigned short* __restrict__ ebuf, const float* __restrict__ scale,
        const float* __restrict__ shift, const float* __restrict__ aatt,
        float* __restrict__ eout, float* __restrict__ s_edge) {
    int t = threadIdx.x;
    int w = t >> 6, lane = t & 63;
    int q = lane & 31, half = lane >> 5;
    int e = blockIdx.x * 8 + w * 2 + half;

    float4 sc = *reinterpret_cast<const float4*>(scale + q * 4);
    float4 sh = *reinterpret_cast<const float4*>(shift + q * 4);
    float4 a4[8];
#pragma unroll
    for (int h = 0; h < 8; ++h)
        a4[h] = *reinterpret_cast<const float4*>(aatt + h * 384 + 256 + q * 4);

    ushort4 xb = *reinterpret_cast<const ushort4*>(ebuf + (size_t)e * 128 + q * 4);
    float4 x;
    x.x = bf2f(xb.x) * sc.x + sh.x;
    x.y = bf2f(xb.y) * sc.y + sh.y;
    x.z = bf2f(xb.z) * sc.z + sh.z;
    x.w = bf2f(xb.w) * sc.w + sh.w;
    *reinterpret_cast<float4*>(eout + (size_t)e * 128 + q * 4) = x;

    float v[8];
#pragma unroll
    for (int h = 0; h < 8; ++h)
        v[h] = x.x * a4[h].x + x.y * a4[h].y + x.z * a4[h].z + x.w * a4[h].w;
#pragma unroll
    for (int o = 1; o < 32; o <<= 1) {
#pragma unroll
        for (int h = 0; h < 8; ++h) v[h] += __shfl_xor(v[h], o, 64);
    }
    if (q == 0) {
#pragma unroll
        for (int h = 0; h < 8; ++h) s_edge[e * 8 + h] = v[h];
    }
}

// ---------------- attention softmax + aggregation; writes bf16 into cat[:,0:128] ----------------
__global__ void k_agg(const unsigned short* __restrict__ zbf, const float* __restrict__ s_src,
                      const float* __restrict__ s_dst, const float* __restrict__ s_edge,
                      const int* __restrict__ off, const int* __restrict__ elist,
                      const int* __restrict__ eidx, unsigned short* __restrict__ cat) {
    int n = blockIdx.x;
    int t = threadIdx.x;              // 128
    int beg = off[n], end = off[n + 1];
    int deg = end - beg;
    if (deg == 0) { cat[(size_t)n * 256 + t] = 0; return; }

    float sdh[8];
#pragma unroll
    for (int h = 0; h < 8; ++h) sdh[h] = s_dst[n * 8 + h];

    __shared__ float lred[16];
    __shared__ float wbuf[128][8];
    __shared__ int snbuf[128];

    float mx[8], den[8];
#pragma unroll
    for (int h = 0; h < 8; ++h) { mx[h] = -1e30f; den[h] = 0.f; }

    int lane = t & 63, w = t >> 6;

    // pass 1: running max / denominator (online across chunks of 128)
    for (int c0 = 0; c0 < deg; c0 += 128) {
        int cn = min(128, deg - c0);
        bool act = t < cn;
        int e = 0, sn = 0;
        if (act) { e = elist[beg + c0 + t]; sn = eidx[2 * e + 1]; }
        float lg[8];
#pragma unroll
        for (int h = 0; h < 8; ++h) {
            float x = act ? (s_src[sn * 8 + h] + sdh[h] + s_edge[e * 8 + h]) : -1e30f;
            lg[h] = x >= 0.f ? x : 0.2f * x;
        }
        float cm[8];
#pragma unroll
        for (int h = 0; h < 8; ++h) cm[h] = lg[h];
        for (int o = 32; o > 0; o >>= 1) {
#pragma unroll
            for (int h = 0; h < 8; ++h) cm[h] = fmaxf(cm[h], __shfl_down(cm[h], o, 64));
        }
        if (lane == 0) {
#pragma unroll
            for (int h = 0; h < 8; ++h) lred[w * 8 + h] = cm[h];
        }
        __syncthreads();
#pragma unroll
        for (int h = 0; h < 8; ++h) cm[h] = fmaxf(lred[h], lred[8 + h]);
        __syncthreads();
        float cs[8];
#pragma unroll
        for (int h = 0; h < 8; ++h) cs[h] = act ? __expf(lg[h] - cm[h]) : 0.f;
        for (int o = 32; o > 0; o >>= 1) {
#pragma unroll
            for (int h = 0; h < 8; ++h) cs[h] += __shfl_down(cs[h], o, 64);
        }
        if (lane == 0) {
#pragma unroll
            for (int h = 0; h < 8; ++h) lred[w * 8 + h] = cs[h];
        }
        __syncthreads();
#pragma unroll
        for (int h = 0; h < 8; ++h) {
            float csum = lred[h] + lred[8 + h];
            float nm = fmaxf(mx[h], cm[h]);
            den[h] = den[h] * __expf(mx[h] - nm) + csum * __expf(cm[h] - nm);
            mx[h] = nm;
        }
        __syncthreads();
    }
    float inv[8];
#pragma unroll
    for (int h = 0; h < 8; ++h) inv[h] = 1.f / den[h];

    // pass 2: weights into LDS, then accumulate sum over heads of alpha*z[src]
    float acc = 0.f;
    for (int c0 = 0; c0 < deg; c0 += 128) {
        int cn = min(128, deg - c0);
        if (t < cn) {
            int e = elist[beg + c0 + t];
            int sn = eidx[2 * e + 1];
            snbuf[t] = sn;
#pragma unroll
            for (int h = 0; h < 8; ++h) {
                float x = s_src[sn * 8 + h] + sdh[h] + s_edge[e * 8 + h];
                x = x >= 0.f ? x : 0.2f * x;
                wbuf[t][h] = __expf(x - mx[h]) * inv[h];
            }
        }
        __syncthreads();
        for (int i = 0; i < cn; ++i) {
            int sn = snbuf[i];
            const unsigned short* zr = zbf + (size_t)sn * 1024 + t;
#pragma unroll
            for (int h = 0; h < 8; ++h)
                acc = fmaf(wbuf[i][h], bf2f(zr[h * 128]), acc);
        }
        __syncthreads();
    }
    cat[(size_t)n * 256 + t] = f2bf(fmaxf(acc * 0.125f, 0.f));
}

// ---------------- GRU pre: ush = BN(nupd_bf); cat[:,128:256] = bf16(ush) ----------------
__global__ void k_gru_pre(const unsigned short* __restrict__ nupd_bf, const float* __restrict__ scale,
                          const float* __restrict__ shift, unsigned short* __restrict__ cat,
                          float* __restrict__ ush) {
    int i = blockIdx.x * 256 + threadIdx.x;   // over NN*32
    if (i >= NN * 32) return;
    int n = i >> 5, j4 = (i & 31) * 4;
    ushort4 ub_in = *reinterpret_cast<const ushort4*>(nupd_bf + (size_t)n * 128 + j4);
    float4 sc = *reinterpret_cast<const float4*>(scale + j4);
    float4 sh = *reinterpret_cast<const float4*>(shift + j4);
    float4 uv;
    uv.x = bf2f(ub_in.x) * sc.x + sh.x;
    uv.y = bf2f(ub_in.y) * sc.y + sh.y;
    uv.z = bf2f(ub_in.z) * sc.z + sh.z;
    uv.w = bf2f(ub_in.w) * sc.w + sh.w;
    ushort4 ub;
    ub.x = f2bf(uv.x); ub.y = f2bf(uv.y); ub.z = f2bf(uv.z); ub.w = f2bf(uv.w);
    *reinterpret_cast<ushort4*>(cat + (size_t)n * 256 + 128 + j4) = ub;
    *reinterpret_cast<float4*>(ush + (size_t)n * 128 + j4) = uv;
}

// ---------------- GRU GEMM: S = cat @ Wc  (M x 256 x 512), MFMA, LDS-coalesced store ----------------
__global__ void __launch_bounds__(256) k_gru_mm(
        const unsigned short* __restrict__ cat, const unsigned short* __restrict__ WcT,
        float* __restrict__ S, int N) {
    __shared__ unsigned short ash[64][264];     // 256 + 8 pad (33792 B)
    int n0 = blockIdx.x * 64;
    int g = blockIdx.y;                          // col group 0..3
    int t = threadIdx.x;
    for (int q = t; q < 64 * 32; q += 256) {
        int r = q >> 5, c = q & 31;
        int n = n0 + r; if (n >= N) n = N - 1;
        *reinterpret_cast<uint4*>(&ash[r][c * 8]) =
            *reinterpret_cast<const uint4*>(cat + (size_t)n * 256 + c * 8);
    }
    __syncthreads();

    int wid = t >> 6, lane = t & 63;
    int wm = wid >> 1, wn = wid & 1;
    int lr = lane & 15, lg = lane >> 4;

    f32x4 acc[2][4];
#pragma unroll
    for (int m = 0; m < 2; ++m)
#pragma unroll
        for (int n = 0; n < 4; ++n) acc[m][n] = (f32x4){0.f, 0.f, 0.f, 0.f};

    const unsigned short* Wg = WcT + (size_t)g * 128 * 256;
#pragma unroll
    for (int ks = 0; ks < 8; ++ks) {
        int kb = ks * 32 + lg * 8;
        bf16x8 a0 = *reinterpret_cast<const bf16x8*>(&ash[wm * 32 + lr][kb]);
        bf16x8 a1 = *reinterpret_cast<const bf16x8*>(&ash[wm * 32 + 16 + lr][kb]);
        bf16x8 b[4];
#pragma unroll
        for (int n = 0; n < 4; ++n)
            b[n] = *reinterpret_cast<const bf16x8*>(Wg + (size_t)(wn * 64 + n * 16 + lr) * 256 + kb);
#pragma unroll
        for (int n = 0; n < 4; ++n) {
            acc[0][n] = __builtin_amdgcn_mfma_f32_16x16x32_bf16(a0, b[n], acc[0][n], 0, 0, 0);
            acc[1][n] = __builtin_amdgcn_mfma_f32_16x16x32_bf16(a1, b[n], acc[1][n], 0, 0, 0);
        }
    }

    __syncthreads();
    float* otf = reinterpret_cast<float*>(&ash[0][0]);   // [64][132] f32 (33792 B)
#pragma unroll
    for (int n = 0; n < 4; ++n) {
        int col = wn * 64 + n * 16 + lr;
#pragma unroll
        for (int m = 0; m < 2; ++m) {
            int rowb = wm * 32 + m * 16 + lg * 4;
#pragma unroll
            for (int r = 0; r < 4; ++r)
                otf[(rowb + r) * 132 + col] = acc[m][n][r];
        }
    }
    __syncthreads();
    for (int q = t; q < 64 * 32; q += 256) {
        int r = q >> 5, c = q & 31;
        int row = n0 + r;
        if (row < N)
            *reinterpret_cast<float4*>(&S[(size_t)row * 512 + g * 128 + c * 4]) =
                *reinterpret_cast<const float4*>(&otf[r * 132 + c * 4]);
    }
}

// ---------------- GRU gates: sigmoid/tanh + combine ----------------
__global__ void __launch_bounds__(256) k_gru_gates(
        const float* __restrict__ S, const float* __restrict__ ush,
        const float* __restrict__ gbias, float* __restrict__ outp) {
    int t = threadIdx.x;
    int n = blockIdx.x * 2 + (t >> 7);
    int u = t & 127;
    const float* b0 = gbias;
    const float* b1 = gbias + 384;
    float s0 = S[(size_t)n * 512 + u];
    float s1 = S[(size_t)n * 512 + 128 + u];
    float xh = S[(size_t)n * 512 + 256 + u];
    float rh = S[(size_t)n * 512 + 384 + u];
    float zg = 1.f / (1.f + __expf(-(s0 + b0[u] + b1[u])));
    float rg = 1.f / (1.f + __expf(-(s1 + b0[128 + u] + b1[128 + u])));
    float hh = tanhf(xh + b0[256 + u] + rg * (rh + b1[256 + u]));
    float uv = ush[(size_t)n * 128 + u];
    outp[(size_t)n * 128 + u] = zg * uv + (1.f - zg) * hh;
}

// ---------------- launch ----------------
extern "C" void kernel_launch(void* const* d_in, const int* in_sizes, int n_in,
                              void* d_out, int out_size, void* d_ws, size_t ws_size,
                              hipStream_t stream) {
    const float* node    = (const float*)d_in[0];
    const float* eattr   = (const float*)d_in[1];
    const int*   eidx    = (const int*)d_in[2];
    const float* We      = (const float*)d_in[3];
    const float* be      = (const float*)d_in[4];
    const float* gamma_e = (const float*)d_in[5];
    const float* beta_e  = (const float*)d_in[6];
    const float* Wn      = (const float*)d_in[7];
    const float* bnb     = (const float*)d_in[8];
    const float* gamma_n = (const float*)d_in[9];
    const float* beta_n  = (const float*)d_in[10];
    const float* Watt    = (const float*)d_in[11];
    const float* batt    = (const float*)d_in[12];
    const float* aatt    = (const float*)d_in[13];
    const float* Wk      = (const float*)d_in[14];
    const float* Wr      = (const float*)d_in[15];
    const float* gbias   = (const float*)d_in[16];

    float* out_node = (float*)d_out;
    float* out_edge = out_node + (size_t)NN * UU;

    char* wp = (char*)d_ws;
    auto alloc = [&](size_t bytes) {
        void* p = (void*)wp;
        wp += (bytes + 255) / 256 * 256;
        return p;
    };
    // zbf (bf16, 20.5MB) shares a region with eattr_bf (bf16, 41MB); eattr_bf dead before k_z_mfma
    unsigned short* zregion = (unsigned short*)alloc((size_t)EE * 128 * 2);
    unsigned short* zbf      = zregion;
    unsigned short* eattr_bf = zregion;
    unsigned short* ebuf = (unsigned short*)alloc((size_t)EE * 128 * 2);
    float* s_src   = (float*)alloc((size_t)NN * 8 * 4);
    float* s_dst   = (float*)alloc((size_t)NN * 8 * 4);
    float* s_edge  = (float*)alloc((size_t)EE * 8 * 4);
    float* part_e  = (float*)alloc((size_t)1250 * 256 * 4);
    float* part_n  = (float*)alloc((size_t)157 * 256 * 4);
    float* scale_e = (float*)alloc(512);
    float* shift_e = (float*)alloc(512);
    float* scale_n = (float*)alloc(512);
    float* shift_n = (float*)alloc(512);
    unsigned short* nupd_bf = (unsigned short*)alloc((size_t)NN * 128 * 2);
    float* ush     = (float*)alloc((size_t)NN * 128 * 4);
    float* Sbuf    = (float*)alloc((size_t)NN * 512 * 4);
    int*   cnt     = (int*)alloc((size_t)NN * 4);
    int*   offs    = (int*)alloc((size_t)(NN + 1) * 4);
    int*   cursor  = (int*)alloc((size_t)NN * 4);
    int*   elist   = (int*)alloc((size_t)EE * 4);
    unsigned short* node_bf = (unsigned short*)alloc((size_t)NN * 128 * 2);
    unsigned short* Wt      = (unsigned short*)alloc((size_t)128 * 384 * 2);
    unsigned short* WtA     = (unsigned short*)alloc((size_t)8 * 128 * 128 * 2);
    unsigned short* WnT     = (unsigned short*)alloc((size_t)128 * 128 * 2);
    unsigned short* WcT     = (unsigned short*)alloc((size_t)512 * 256 * 2);
    unsigned short* cat     = (unsigned short*)alloc((size_t)NN * 256 * 2);

    hipMemsetAsync(cnt, 0, (size_t)NN * 4, stream);
    k_hist<<<(EE + 255) / 256, 256, 0, stream>>>(eidx, cnt, EE);
    k_scan<<<1, 1024, 0, stream>>>(cnt, offs, cursor, NN);
    k_scatter<<<(EE + 255) / 256, 256, 0, stream>>>(eidx, cursor, elist, EE);

    // bf16 conversions
    k_f2bf<<<1280, 256, 0, stream>>>(node, node_bf, (long)NN * 128 / 4);
    k_f2bf<<<2048, 256, 0, stream>>>(eattr, eattr_bf, (long)EE * 128 / 4);
    k_wtg<<<(384 * 128 + 255) / 256, 256, 0, stream>>>(We, Wt, 384, 128);
    k_wtg<<<(128 * 128 + 255) / 256, 256, 0, stream>>>(Wn, WnT, 128, 128);
    k_wt_att<<<(8 * 128 * 128 + 255) / 256, 256, 0, stream>>>(Watt, WtA);
    k_wt_gru<<<(512 * 256 + 255) / 256, 256, 0, stream>>>(Wk, Wr, WcT);

    // edge pipeline (uses eattr_bf which aliases zbf; must precede k_z_mfma)
    k_edge_mlp_mfma<<<EE / 128, 512, 0, stream>>>(node_bf, eattr_bf, eidx, Wt, be, ebuf, part_e);
    k_bn_fin<<<128, 256, 0, stream>>>(part_e, EE / 128, 1.f / (float)EE,
                                      gamma_e, beta_e, scale_e, shift_e);
    k_edge_final<<<EE / 8, 256, 0, stream>>>(ebuf, scale_e, shift_e, aatt, out_edge, s_edge);

    // node/attention pipeline
    k_z_mfma<<<dim3((NN + 63) / 64, 8), 256, 0, stream>>>(node_bf, WtA, batt, zbf, NN);
    k_snodes<<<NN / 4, 256, 0, stream>>>(zbf, aatt, s_src, s_dst, NN);
    k_agg<<<NN, 128, 0, stream>>>(zbf, s_src, s_dst, s_edge, offs, elist, eidx, cat);

    // node MLP + BN
    k_node_mlp_mfma<<<(NN + 63) / 64, 256, 0, stream>>>(node_bf, WnT, bnb, nupd_bf, part_n, NN);
    k_bn_fin<<<128, 256, 0, stream>>>(part_n, (NN + 63) / 64, 1.f / (float)NN,
                                      gamma_n, beta_n, scale_n, shift_n);

    // GRU
    k_gru_pre<<<(NN * 32 + 255) / 256, 256, 0, stream>>>(nupd_bf, scale_n, shift_n, cat, ush);
    k_gru_mm<<<dim3((NN + 63) / 64, 4), 256, 0, stream>>>(cat, WcT, Sbuf, NN);
    k_gru_gates<<<NN / 2, 256, 0, stream>>>(Sbuf, ush, gbias, out_node);
}

// Round 9
// 318.537 us; speedup vs baseline: 1.1914x; 1.0616x over previous
//
#include <hip/hip_runtime.h>
#include <hip/hip_bf16.h>

#define NN 10000
#define EE 160000
#define FF 128
#define UU 128
#define HH 8
#define BN_EPS 1e-3f

typedef __attribute__((ext_vector_type(8))) short bf16x8;
typedef __attribute__((ext_vector_type(8))) unsigned short u16x8;
typedef __attribute__((ext_vector_type(4))) float f32x4;

static __device__ __forceinline__ unsigned short f2bf(float f) {
    unsigned u = __float_as_uint(f);
    u += 0x7fffu + ((u >> 16) & 1u);
    return (unsigned short)(u >> 16);
}
static __device__ __forceinline__ float bf2f(unsigned short b) {
    return __uint_as_float((unsigned)b << 16);
}

// ---------------- f32 -> bf16 bulk convert (count divisible by 4) ----------------
__global__ void k_f2bf(const float* __restrict__ in, unsigned short* __restrict__ out, long n4) {
    long i = (long)blockIdx.x * 256 + threadIdx.x;
    long stride = (long)gridDim.x * 256;
    for (; i < n4; i += stride) {
        float4 v = reinterpret_cast<const float4*>(in)[i];
        ushort4 o;
        o.x = f2bf(v.x); o.y = f2bf(v.y); o.z = f2bf(v.z); o.w = f2bf(v.w);
        reinterpret_cast<ushort4*>(out)[i] = o;
    }
}

// ---------------- generic W [K][U] f32 -> W^T [U][K] bf16 ----------------
__global__ void k_wtg(const float* __restrict__ W, unsigned short* __restrict__ Wt, int K, int U) {
    int i = blockIdx.x * 256 + threadIdx.x;
    if (i < K * U) {
        int k = i / U, u = i - k * U;
        Wt[u * K + k] = f2bf(W[i]);
    }
}

// ---------------- W_edge [384][128] -> WtE [3][128 u][128 k] bf16 ----------------
__global__ void k_wt_edge(const float* __restrict__ We, unsigned short* __restrict__ WtE) {
    int i = blockIdx.x * 256 + threadIdx.x;   // over 3*128*128
    if (i < 3 * 128 * 128) {
        int s = i >> 14, rem = i & 16383, u = rem >> 7, k = rem & 127;
        WtE[i] = f2bf(We[(s * 128 + k) * 128 + u]);
    }
}

// ---------------- W_att [8][128][128] f32 -> per-head W^T [8][128][128] bf16 ----------------
__global__ void k_wt_att(const float* __restrict__ W, unsigned short* __restrict__ Wt) {
    int i = blockIdx.x * 256 + threadIdx.x;   // over 8*128*128
    if (i < 8 * 128 * 128) {
        int h = i >> 14, rem = i & 16383, f = rem >> 7, u = rem & 127;
        Wt[h * 16384 + u * 128 + f] = f2bf(W[i]);
    }
}

// ---------------- GRU combined weight: WcT [512][256] bf16 ----------------
__global__ void k_wt_gru(const float* __restrict__ Wk, const float* __restrict__ Wr,
                         unsigned short* __restrict__ WcT) {
    int i = blockIdx.x * 256 + threadIdx.x;   // over 512*256
    if (i >= 512 * 256) return;
    int c = i >> 8, k = i & 255;
    float v;
    if (c < 256)       v = (k < 128) ? Wk[k * 384 + c] : Wr[(k - 128) * 384 + c];
    else if (c < 384)  v = (k < 128) ? Wk[k * 384 + c] : 0.f;
    else               v = (k < 128) ? 0.f : Wr[(k - 128) * 384 + (c - 128)];
    WcT[c * 256 + k] = f2bf(v);
}

// ---------------- CSR construction ----------------
__global__ void k_hist(const int* __restrict__ eidx, int* __restrict__ cnt, int E) {
    int e = blockIdx.x * 256 + threadIdx.x;
    if (e < E) atomicAdd(&cnt[eidx[2 * e]], 1);   // dst = eidx[e][0]
}

__global__ void k_scan(const int* __restrict__ cnt, int* __restrict__ off,
                       int* __restrict__ cursor, int N) {
    __shared__ int s[1024];
    int t = threadIdx.x;
    int run = 0;
    if (t == 0) off[0] = 0;
    for (int base = 0; base < N; base += 1024) {
        int x = (base + t < N) ? cnt[base + t] : 0;
        s[t] = x;
        __syncthreads();
        for (int o = 1; o < 1024; o <<= 1) {
            int v = (t >= o) ? s[t - o] : 0;
            __syncthreads();
            s[t] += v;
            __syncthreads();
        }
        if (base + t < N) {
            off[base + t + 1] = run + s[t];
            cursor[base + t] = run + s[t] - x;
        }
        run += s[1023];
        __syncthreads();
    }
}

__global__ void k_scatter(const int* __restrict__ eidx, int* __restrict__ cursor,
                          int* __restrict__ elist, int E) {
    int e = blockIdx.x * 256 + threadIdx.x;
    if (e < E) {
        int d = eidx[2 * e];
        int p = atomicAdd(&cursor[d], 1);
        elist[p] = e;
    }
}

// ---------------- z (bf16) = node @ W_att[h] + b_att[h], MFMA, LDS-coalesced store ----------------
__global__ void __launch_bounds__(256) k_z_mfma(
        const unsigned short* __restrict__ node_bf, const unsigned short* __restrict__ WtA,
        const float* __restrict__ batt, unsigned short* __restrict__ zbf, int N) {
    __shared__ unsigned short ash[64][136];     // 128 + 8 pad
    int n0 = blockIdx.x * 64;
    int h = blockIdx.y;
    int t = threadIdx.x;
    for (int q = t; q < 64 * 16; q += 256) {
        int r = q >> 4, c = q & 15;
        int n = n0 + r; if (n >= N) n = N - 1;
        *reinterpret_cast<uint4*>(&ash[r][c * 8]) =
            *reinterpret_cast<const uint4*>(node_bf + (size_t)n * 128 + c * 8);
    }
    __syncthreads();

    int wid = t >> 6, lane = t & 63;
    int wm = wid >> 1, wn = wid & 1;
    int lr = lane & 15, lg = lane >> 4;

    f32x4 acc[2][4];
#pragma unroll
    for (int m = 0; m < 2; ++m)
#pragma unroll
        for (int n = 0; n < 4; ++n) acc[m][n] = (f32x4){0.f, 0.f, 0.f, 0.f};

    const unsigned short* Wh = WtA + (size_t)h * 16384;
#pragma unroll
    for (int ks = 0; ks < 4; ++ks) {
        int kb = ks * 32 + lg * 8;
        bf16x8 a0 = *reinterpret_cast<const bf16x8*>(&ash[wm * 32 + lr][kb]);
        bf16x8 a1 = *reinterpret_cast<const bf16x8*>(&ash[wm * 32 + 16 + lr][kb]);
        bf16x8 b[4];
#pragma unroll
        for (int n = 0; n < 4; ++n)
            b[n] = *reinterpret_cast<const bf16x8*>(Wh + (size_t)(wn * 64 + n * 16 + lr) * 128 + kb);
#pragma unroll
        for (int n = 0; n < 4; ++n) {
            acc[0][n] = __builtin_amdgcn_mfma_f32_16x16x32_bf16(a0, b[n], acc[0][n], 0, 0, 0);
            acc[1][n] = __builtin_amdgcn_mfma_f32_16x16x32_bf16(a1, b[n], acc[1][n], 0, 0, 0);
        }
    }

    __syncthreads();                      // A-tile reads done; reuse ash as C-tile
    unsigned short* ot = &ash[0][0];      // [64][136]
#pragma unroll
    for (int n = 0; n < 4; ++n) {
        int col = wn * 64 + n * 16 + lr;
        float bias = batt[h * 128 + col];
#pragma unroll
        for (int m = 0; m < 2; ++m) {
            int rowb = wm * 32 + m * 16 + lg * 4;
#pragma unroll
            for (int r = 0; r < 4; ++r)
                ot[(rowb + r) * 136 + col] = f2bf(acc[m][n][r] + bias);
        }
    }
    __syncthreads();
    for (int q = t; q < 64 * 16; q += 256) {
        int r = q >> 4, c = q & 15;
        int row = n0 + r;
        if (row < N)
            *reinterpret_cast<uint4*>(&zbf[(size_t)row * 1024 + h * 128 + c * 8]) =
                *reinterpret_cast<const uint4*>(&ot[r * 136 + c * 8]);
    }
}

// ---------------- P12 (bf16) = node @ [W1|W2], MFMA, out N x 256 ----------------
__global__ void __launch_bounds__(256) k_p12_mfma(
        const unsigned short* __restrict__ node_bf, const unsigned short* __restrict__ WtE,
        unsigned short* __restrict__ p12, int N) {
    __shared__ unsigned short ash[64][136];
    int n0 = blockIdx.x * 64;
    int s = blockIdx.y;                    // 0: W1 (src part), 1: W2 (dst part)
    int t = threadIdx.x;
    for (int q = t; q < 64 * 16; q += 256) {
        int r = q >> 4, c = q & 15;
        int n = n0 + r; if (n >= N) n = N - 1;
        *reinterpret_cast<uint4*>(&ash[r][c * 8]) =
            *reinterpret_cast<const uint4*>(node_bf + (size_t)n * 128 + c * 8);
    }
    __syncthreads();

    int wid = t >> 6, lane = t & 63;
    int wm = wid >> 1, wn = wid & 1;
    int lr = lane & 15, lg = lane >> 4;

    f32x4 acc[2][4];
#pragma unroll
    for (int m = 0; m < 2; ++m)
#pragma unroll
        for (int n = 0; n < 4; ++n) acc[m][n] = (f32x4){0.f, 0.f, 0.f, 0.f};

    const unsigned short* Wh = WtE + (size_t)s * 16384;
#pragma unroll
    for (int ks = 0; ks < 4; ++ks) {
        int kb = ks * 32 + lg * 8;
        bf16x8 a0 = *reinterpret_cast<const bf16x8*>(&ash[wm * 32 + lr][kb]);
        bf16x8 a1 = *reinterpret_cast<const bf16x8*>(&ash[wm * 32 + 16 + lr][kb]);
        bf16x8 b[4];
#pragma unroll
        for (int n = 0; n < 4; ++n)
            b[n] = *reinterpret_cast<const bf16x8*>(Wh + (size_t)(wn * 64 + n * 16 + lr) * 128 + kb);
#pragma unroll
        for (int n = 0; n < 4; ++n) {
            acc[0][n] = __builtin_amdgcn_mfma_f32_16x16x32_bf16(a0, b[n], acc[0][n], 0, 0, 0);
            acc[1][n] = __builtin_amdgcn_mfma_f32_16x16x32_bf16(a1, b[n], acc[1][n], 0, 0, 0);
        }
    }

    __syncthreads();
    unsigned short* ot = &ash[0][0];
#pragma unroll
    for (int n = 0; n < 4; ++n) {
        int col = wn * 64 + n * 16 + lr;
#pragma unroll
        for (int m = 0; m < 2; ++m) {
            int rowb = wm * 32 + m * 16 + lg * 4;
#pragma unroll
            for (int r = 0; r < 4; ++r)
                ot[(rowb + r) * 136 + col] = f2bf(acc[m][n][r]);
        }
    }
    __syncthreads();
    for (int q = t; q < 64 * 16; q += 256) {
        int r = q >> 4, c = q & 15;
        int row = n0 + r;
        if (row < N)
            *reinterpret_cast<uint4*>(&p12[(size_t)row * 256 + s * 128 + c * 8]) =
                *reinterpret_cast<const uint4*>(&ot[r * 136 + c * 8]);
    }
}

// ---------------- PE (bf16) = eattr @ W3 + be, MFMA (dense, contiguous rows) ----------------
__global__ void __launch_bounds__(256) k_pe_mfma(
        const unsigned short* __restrict__ eattr_bf, const unsigned short* __restrict__ WtE,
        const float* __restrict__ be, unsigned short* __restrict__ pe) {
    __shared__ unsigned short ash[64][136];
    int e0 = blockIdx.x * 64;
    int t = threadIdx.x;
    for (int q = t; q < 64 * 16; q += 256) {
        int r = q >> 4, c = q & 15;
        *reinterpret_cast<uint4*>(&ash[r][c * 8]) =
            *reinterpret_cast<const uint4*>(eattr_bf + (size_t)(e0 + r) * 128 + c * 8);
    }
    __syncthreads();

    int wid = t >> 6, lane = t & 63;
    int wm = wid >> 1, wn = wid & 1;
    int lr = lane & 15, lg = lane >> 4;

    f32x4 acc[2][4];
#pragma unroll
    for (int m = 0; m < 2; ++m)
#pragma unroll
        for (int n = 0; n < 4; ++n) acc[m][n] = (f32x4){0.f, 0.f, 0.f, 0.f};

    const unsigned short* Wh = WtE + (size_t)2 * 16384;
#pragma unroll
    for (int ks = 0; ks < 4; ++ks) {
        int kb = ks * 32 + lg * 8;
        bf16x8 a0 = *reinterpret_cast<const bf16x8*>(&ash[wm * 32 + lr][kb]);
        bf16x8 a1 = *reinterpret_cast<const bf16x8*>(&ash[wm * 32 + 16 + lr][kb]);
        bf16x8 b[4];
#pragma unroll
        for (int n = 0; n < 4; ++n)
            b[n] = *reinterpret_cast<const bf16x8*>(Wh + (size_t)(wn * 64 + n * 16 + lr) * 128 + kb);
#pragma unroll
        for (int n = 0; n < 4; ++n) {
            acc[0][n] = __builtin_amdgcn_mfma_f32_16x16x32_bf16(a0, b[n], acc[0][n], 0, 0, 0);
            acc[1][n] = __builtin_amdgcn_mfma_f32_16x16x32_bf16(a1, b[n], acc[1][n], 0, 0, 0);
        }
    }

    __syncthreads();
    unsigned short* ot = &ash[0][0];
#pragma unroll
    for (int n = 0; n < 4; ++n) {
        int col = wn * 64 + n * 16 + lr;
        float bias = be[col];
#pragma unroll
        for (int m = 0; m < 2; ++m) {
            int rowb = wm * 32 + m * 16 + lg * 4;
#pragma unroll
            for (int r = 0; r < 4; ++r)
                ot[(rowb + r) * 136 + col] = f2bf(acc[m][n][r] + bias);
        }
    }
    __syncthreads();
    for (int q = t; q < 64 * 16; q += 256) {
        int r = q >> 4, c = q & 15;
        *reinterpret_cast<uint4*>(&pe[(size_t)(e0 + r) * 128 + c * 8]) =
            *reinterpret_cast<const uint4*>(&ot[r * 136 + c * 8]);
    }
}

// ---------------- edge combine: ebuf[e] = relu(PE[e] + P1[src] + P2[dst]), BN partials ----------------
__global__ void __launch_bounds__(256) k_edge_combine(
        const unsigned short* __restrict__ p12, const int* __restrict__ eidx,
        unsigned short* __restrict__ ebuf, float* __restrict__ part) {
    __shared__ int sd[128];
    __shared__ float sbuf[4][128], qbuf[4][128];
    int e0 = blockIdx.x * 64;
    int t = threadIdx.x;
    if (t < 128) sd[t] = eidx[e0 * 2 + t];      // [e][0]=dst, [e][1]=src
    __syncthreads();
    int slot = t >> 5;            // 0..7
    int c = t & 31;               // cols c*4 .. c*4+3
    float s[4] = {0.f, 0.f, 0.f, 0.f}, q[4] = {0.f, 0.f, 0.f, 0.f};
#pragma unroll
    for (int i = 0; i < 8; ++i) {
        int el = i * 8 + slot;
        int e = e0 + el;
        int dst = sd[el * 2], src = sd[el * 2 + 1];
        ushort4 pe = *reinterpret_cast<const ushort4*>(ebuf + (size_t)e * 128 + c * 4);
        ushort4 p1 = *reinterpret_cast<const ushort4*>(p12 + (size_t)src * 256 + c * 4);
        ushort4 p2 = *reinterpret_cast<const ushort4*>(p12 + (size_t)dst * 256 + 128 + c * 4);
        float v0 = bf2f(pe.x) + bf2f(p1.x) + bf2f(p2.x); v0 = v0 > 0.f ? v0 : 0.f;
        float v1 = bf2f(pe.y) + bf2f(p1.y) + bf2f(p2.y); v1 = v1 > 0.f ? v1 : 0.f;
        float v2 = bf2f(pe.z) + bf2f(p1.z) + bf2f(p2.z); v2 = v2 > 0.f ? v2 : 0.f;
        float v3 = bf2f(pe.w) + bf2f(p1.w) + bf2f(p2.w); v3 = v3 > 0.f ? v3 : 0.f;
        ushort4 o;
        o.x = f2bf(v0); o.y = f2bf(v1); o.z = f2bf(v2); o.w = f2bf(v3);
        *reinterpret_cast<ushort4*>(ebuf + (size_t)e * 128 + c * 4) = o;
        s[0] += v0; q[0] += v0 * v0;
        s[1] += v1; q[1] += v1 * v1;
        s[2] += v2; q[2] += v2 * v2;
        s[3] += v3; q[3] += v3 * v3;
    }
#pragma unroll
    for (int j = 0; j < 4; ++j) {
        s[j] += __shfl_xor(s[j], 32, 64);
        q[j] += __shfl_xor(q[j], 32, 64);
    }
    int w = t >> 6, lane = t & 63;
    if (lane < 32) {
#pragma unroll
        for (int j = 0; j < 4; ++j) {
            sbuf[w][c * 4 + j] = s[j];
            qbuf[w][c * 4 + j] = q[j];
        }
    }
    __syncthreads();
    if (t < 128) {
        part[(size_t)blockIdx.x * 256 + t] =
            sbuf[0][t] + sbuf[1][t] + sbuf[2][t] + sbuf[3][t];
        part[(size_t)blockIdx.x * 256 + 128 + t] =
            qbuf[0][t] + qbuf[1][t] + qbuf[2][t] + qbuf[3][t];
    }
}

// ---------------- s_src[n,h], s_dst[n,h]: wave=node, lane=(head, 16-col slice) ----------------
__global__ void __launch_bounds__(256) k_snodes(
        const unsigned short* __restrict__ zbf, const float* __restrict__ aatt,
        float* __restrict__ s_src, float* __restrict__ s_dst, int N) {
    int t = threadIdx.x;
    int w = t >> 6, lane = t & 63;
    int n = blockIdx.x * 4 + w;
    if (n >= N) return;
    int h = lane >> 3, p = lane & 7;
    const unsigned short* zp = zbf + (size_t)n * 1024 + h * 128 + p * 16;
    const float* as = aatt + h * 384 + p * 16;
    u16x8 z0 = *reinterpret_cast<const u16x8*>(zp);
    u16x8 z1 = *reinterpret_cast<const u16x8*>(zp + 8);
    float vs = 0.f, vd = 0.f;
#pragma unroll
    for (int j = 0; j < 8; ++j) {
        float zv = bf2f(z0[j]);
        vs = fmaf(zv, as[j], vs);
        vd = fmaf(zv, as[128 + j], vd);
    }
#pragma unroll
    for (int j = 0; j < 8; ++j) {
        float zv = bf2f(z1[j]);
        vs = fmaf(zv, as[8 + j], vs);
        vd = fmaf(zv, as[136 + j], vd);
    }
#pragma unroll
    for (int o = 1; o < 8; o <<= 1) {
        vs += __shfl_xor(vs, o, 64);
        vd += __shfl_xor(vd, o, 64);
    }
    if (p == 0) {
        s_src[n * 8 + h] = vs;
        s_dst[n * 8 + h] = vd;
    }
}

// ---------------- node MLP via MFMA: relu(node @ W_node + b) -> bf16, BN partials ----------------
__global__ void __launch_bounds__(256) k_node_mlp_mfma(
        const unsigned short* __restrict__ node_bf, const unsigned short* __restrict__ WnT,
        const float* __restrict__ bn, unsigned short* __restrict__ nupd_bf,
        float* __restrict__ part, int N) {
    __shared__ unsigned short ash[64][136];
    __shared__ float sbuf[4][64], qbuf[4][64];
    int n0 = blockIdx.x * 64;
    int t = threadIdx.x;
    for (int q = t; q < 64 * 16; q += 256) {
        int r = q >> 4, c = q & 15;
        int n = n0 + r; if (n >= N) n = N - 1;
        *reinterpret_cast<uint4*>(&ash[r][c * 8]) =
            *reinterpret_cast<const uint4*>(node_bf + (size_t)n * 128 + c * 8);
    }
    __syncthreads();

    int wid = t >> 6, lane = t & 63;
    int wm = wid >> 1, wn = wid & 1;
    int lr = lane & 15, lg = lane >> 4;

    f32x4 acc[2][4];
#pragma unroll
    for (int m = 0; m < 2; ++m)
#pragma unroll
        for (int n = 0; n < 4; ++n) acc[m][n] = (f32x4){0.f, 0.f, 0.f, 0.f};

#pragma unroll
    for (int ks = 0; ks < 4; ++ks) {
        int kb = ks * 32 + lg * 8;
        bf16x8 a0 = *reinterpret_cast<const bf16x8*>(&ash[wm * 32 + lr][kb]);
        bf16x8 a1 = *reinterpret_cast<const bf16x8*>(&ash[wm * 32 + 16 + lr][kb]);
        bf16x8 b[4];
#pragma unroll
        for (int n = 0; n < 4; ++n)
            b[n] = *reinterpret_cast<const bf16x8*>(WnT + (size_t)(wn * 64 + n * 16 + lr) * 128 + kb);
#pragma unroll
        for (int n = 0; n < 4; ++n) {
            acc[0][n] = __builtin_amdgcn_mfma_f32_16x16x32_bf16(a0, b[n], acc[0][n], 0, 0, 0);
            acc[1][n] = __builtin_amdgcn_mfma_f32_16x16x32_bf16(a1, b[n], acc[1][n], 0, 0, 0);
        }
    }

    __syncthreads();
    unsigned short* ot = &ash[0][0];
    float s[4] = {0.f, 0.f, 0.f, 0.f}, q[4] = {0.f, 0.f, 0.f, 0.f};
#pragma unroll
    for (int n = 0; n < 4; ++n) {
        int col = wn * 64 + n * 16 + lr;
        float bias = bn[col];
#pragma unroll
        for (int m = 0; m < 2; ++m) {
            int rowb = wm * 32 + m * 16 + lg * 4;
#pragma unroll
            for (int r = 0; r < 4; ++r) {
                int row = n0 + rowb + r;
                float v = acc[m][n][r] + bias;
                v = v > 0.f ? v : 0.f;
                ot[(rowb + r) * 136 + col] = f2bf(v);
                if (row < N) { s[n] += v; q[n] += v * v; }
            }
        }
    }
#pragma unroll
    for (int n = 0; n < 4; ++n) {
        s[n] += __shfl_xor(s[n], 16, 64);
        s[n] += __shfl_xor(s[n], 32, 64);
        q[n] += __shfl_xor(q[n], 16, 64);
        q[n] += __shfl_xor(q[n], 32, 64);
    }
    if (lane < 16) {
#pragma unroll
        for (int n = 0; n < 4; ++n) {
            sbuf[wid][n * 16 + lane] = s[n];
            qbuf[wid][n * 16 + lane] = q[n];
        }
    }
    __syncthreads();
    for (int q2 = t; q2 < 64 * 16; q2 += 256) {
        int r = q2 >> 4, c = q2 & 15;
        int row = n0 + r;
        if (row < N)
            *reinterpret_cast<uint4*>(&nupd_bf[(size_t)row * 128 + c * 8]) =
                *reinterpret_cast<const uint4*>(&ot[r * 136 + c * 8]);
    }
    if (t < 128) {
        int half = t >> 6, c = t & 63;
        part[(size_t)blockIdx.x * 256 + t] = sbuf[half][c] + sbuf[2 + half][c];
        part[(size_t)blockIdx.x * 256 + 128 + t] = qbuf[half][c] + qbuf[2 + half][c];
    }
}

// ---------------- BN finalize: scale/shift per column ----------------
__global__ void k_bn_fin(const float* __restrict__ part, int nblk, float invcnt,
                         const float* __restrict__ g, const float* __restrict__ b,
                         float* __restrict__ scale, float* __restrict__ shift) {
    int u = blockIdx.x;               // 128 blocks
    int t = threadIdx.x;              // 256
    float s = 0.f, q = 0.f;
    for (int i = t; i < nblk; i += 256) {
        s += part[(size_t)i * 256 + u];
        q += part[(size_t)i * 256 + 128 + u];
    }
    __shared__ float ls[4], lq[4];
    for (int o = 32; o > 0; o >>= 1) {
        s += __shfl_down(s, o, 64);
        q += __shfl_down(q, o, 64);
    }
    int lane = t & 63, w = t >> 6;
    if (lane == 0) { ls[w] = s; lq[w] = q; }
    __syncthreads();
    if (t == 0) {
        float S = ls[0] + ls[1] + ls[2] + ls[3];
        float Q = lq[0] + lq[1] + lq[2] + lq[3];
        float mean = S * invcnt;
        float var = Q * invcnt - mean * mean;
        float inv = rsqrtf(var + BN_EPS);
        float sc = g[u] * inv;
        scale[u] = sc;
        shift[u] = b[u] - mean * sc;
    }
}

// ---------------- edge finalize: wave=2 edges, lane=4 cols; BN apply + s_edge ----------------
__global__ void __launch_bounds__(256) k_edge_final(
        const unsigned short* __restrict__ ebuf, const float* __restrict__ scale,
        const float* __restrict__ shift, const float* __restrict__ aatt,
        float* __restrict__ eout, float* __restrict__ s_edge) {
    int t = threadIdx.x;
    int w = t >> 6, lane = t & 63;
    int q = lane & 31, half = lane >> 5;
    int e = blockIdx.x * 8 + w * 2 + half;

    float4 sc = *reinterpret_cast<const float4*>(scale + q * 4);
    float4 sh = *reinterpret_cast<const float4*>(shift + q * 4);
    float4 a4[8];
#pragma unroll
    for (int h = 0; h < 8; ++h)
        a4[h] = *reinterpret_cast<const float4*>(aatt + h * 384 + 256 + q * 4);

    ushort4 xb = *reinterpret_cast<const ushort4*>(ebuf + (size_t)e * 128 + q * 4);
    float4 x;
    x.x = bf2f(xb.x) * sc.x + sh.x;
    x.y = bf2f(xb.y) * sc.y + sh.y;
    x.z = bf2f(xb.z) * sc.z + sh.z;
    x.w = bf2f(xb.w) * sc.w + sh.w;
    *reinterpret_cast<float4*>(eout + (size_t)e * 128 + q * 4) = x;

    float v[8];
#pragma unroll
    for (int h = 0; h < 8; ++h)
        v[h] = x.x * a4[h].x + x.y * a4[h].y + x.z * a4[h].z + x.w * a4[h].w;
#pragma unroll
    for (int o = 1; o < 32; o <<= 1) {
#pragma unroll
        for (int h = 0; h < 8; ++h) v[h] += __shfl_xor(v[h], o, 64);
    }
    if (q == 0) {
#pragma unroll
        for (int h = 0; h < 8; ++h) s_edge[e * 8 + h] = v[h];
    }
}

// ---------------- attention softmax + aggregation; writes bf16 into cat[:,0:128] ----------------
__global__ void k_agg(const unsigned short* __restrict__ zbf, const float* __restrict__ s_src,
                      const float* __restrict__ s_dst, const float* __restrict__ s_edge,
                      const int* __restrict__ off, const int* __restrict__ elist,
                      const int* __restrict__ eidx, unsigned short* __restrict__ cat) {
    int n = blockIdx.x;
    int t = threadIdx.x;              // 128
    int beg = off[n], end = off[n + 1];
    int deg = end - beg;
    if (deg == 0) { cat[(size_t)n * 256 + t] = 0; return; }

    float sdh[8];
#pragma unroll
    for (int h = 0; h < 8; ++h) sdh[h] = s_dst[n * 8 + h];

    __shared__ float lred[16];
    __shared__ float wbuf[128][8];
    __shared__ int snbuf[128];

    float mx[8], den[8];
#pragma unroll
    for (int h = 0; h < 8; ++h) { mx[h] = -1e30f; den[h] = 0.f; }

    int lane = t & 63, w = t >> 6;

    // pass 1: running max / denominator (online across chunks of 128)
    for (int c0 = 0; c0 < deg; c0 += 128) {
        int cn = min(128, deg - c0);
        bool act = t < cn;
        int e = 0, sn = 0;
        if (act) { e = elist[beg + c0 + t]; sn = eidx[2 * e + 1]; }
        float lg[8];
#pragma unroll
        for (int h = 0; h < 8; ++h) {
            float x = act ? (s_src[sn * 8 + h] + sdh[h] + s_edge[e * 8 + h]) : -1e30f;
            lg[h] = x >= 0.f ? x : 0.2f * x;
        }
        float cm[8];
#pragma unroll
        for (int h = 0; h < 8; ++h) cm[h] = lg[h];
        for (int o = 32; o > 0; o >>= 1) {
#pragma unroll
            for (int h = 0; h < 8; ++h) cm[h] = fmaxf(cm[h], __shfl_down(cm[h], o, 64));
        }
        if (lane == 0) {
#pragma unroll
            for (int h = 0; h < 8; ++h) lred[w * 8 + h] = cm[h];
        }
        __syncthreads();
#pragma unroll
        for (int h = 0; h < 8; ++h) cm[h] = fmaxf(lred[h], lred[8 + h]);
        __syncthreads();
        float cs[8];
#pragma unroll
        for (int h = 0; h < 8; ++h) cs[h] = act ? __expf(lg[h] - cm[h]) : 0.f;
        for (int o = 32; o > 0; o >>= 1) {
#pragma unroll
            for (int h = 0; h < 8; ++h) cs[h] += __shfl_down(cs[h], o, 64);
        }
        if (lane == 0) {
#pragma unroll
            for (int h = 0; h < 8; ++h) lred[w * 8 + h] = cs[h];
        }
        __syncthreads();
#pragma unroll
        for (int h = 0; h < 8; ++h) {
            float csum = lred[h] + lred[8 + h];
            float nm = fmaxf(mx[h], cm[h]);
            den[h] = den[h] * __expf(mx[h] - nm) + csum * __expf(cm[h] - nm);
            mx[h] = nm;
        }
        __syncthreads();
    }
    float inv[8];
#pragma unroll
    for (int h = 0; h < 8; ++h) inv[h] = 1.f / den[h];

    // pass 2: weights into LDS, then accumulate sum over heads of alpha*z[src]
    float acc = 0.f;
    for (int c0 = 0; c0 < deg; c0 += 128) {
        int cn = min(128, deg - c0);
        if (t < cn) {
            int e = elist[beg + c0 + t];
            int sn = eidx[2 * e + 1];
            snbuf[t] = sn;
#pragma unroll
            for (int h = 0; h < 8; ++h) {
                float x = s_src[sn * 8 + h] + sdh[h] + s_edge[e * 8 + h];
                x = x >= 0.f ? x : 0.2f * x;
                wbuf[t][h] = __expf(x - mx[h]) * inv[h];
            }
        }
        __syncthreads();
        for (int i = 0; i < cn; ++i) {
            int sn = snbuf[i];
            const unsigned short* zr = zbf + (size_t)sn * 1024 + t;
#pragma unroll
            for (int h = 0; h < 8; ++h)
                acc = fmaf(wbuf[i][h], bf2f(zr[h * 128]), acc);
        }
        __syncthreads();
    }
    cat[(size_t)n * 256 + t] = f2bf(fmaxf(acc * 0.125f, 0.f));
}

// ---------------- GRU pre: ush = BN(nupd_bf); cat[:,128:256] = bf16(ush) ----------------
__global__ void k_gru_pre(const unsigned short* __restrict__ nupd_bf, const float* __restrict__ scale,
                          const float* __restrict__ shift, unsigned short* __restrict__ cat,
                          float* __restrict__ ush) {
    int i = blockIdx.x * 256 + threadIdx.x;   // over NN*32
    if (i >= NN * 32) return;
    int n = i >> 5, j4 = (i & 31) * 4;
    ushort4 ub_in = *reinterpret_cast<const ushort4*>(nupd_bf + (size_t)n * 128 + j4);
    float4 sc = *reinterpret_cast<const float4*>(scale + j4);
    float4 sh = *reinterpret_cast<const float4*>(shift + j4);
    float4 uv;
    uv.x = bf2f(ub_in.x) * sc.x + sh.x;
    uv.y = bf2f(ub_in.y) * sc.y + sh.y;
    uv.z = bf2f(ub_in.z) * sc.z + sh.z;
    uv.w = bf2f(ub_in.w) * sc.w + sh.w;
    ushort4 ub;
    ub.x = f2bf(uv.x); ub.y = f2bf(uv.y); ub.z = f2bf(uv.z); ub.w = f2bf(uv.w);
    *reinterpret_cast<ushort4*>(cat + (size_t)n * 256 + 128 + j4) = ub;
    *reinterpret_cast<float4*>(ush + (size_t)n * 128 + j4) = uv;
}

// ---------------- GRU GEMM: S = cat @ Wc  (M x 256 x 512), MFMA, LDS-coalesced store ----------------
__global__ void __launch_bounds__(256) k_gru_mm(
        const unsigned short* __restrict__ cat, const unsigned short* __restrict__ WcT,
        float* __restrict__ S, int N) {
    __shared__ unsigned short ash[64][264];     // 256 + 8 pad (33792 B)
    int n0 = blockIdx.x * 64;
    int g = blockIdx.y;                          // col group 0..3
    int t = threadIdx.x;
    for (int q = t; q < 64 * 32; q += 256) {
        int r = q >> 5, c = q & 31;
        int n = n0 + r; if (n >= N) n = N - 1;
        *reinterpret_cast<uint4*>(&ash[r][c * 8]) =
            *reinterpret_cast<const uint4*>(cat + (size_t)n * 256 + c * 8);
    }
    __syncthreads();

    int wid = t >> 6, lane = t & 63;
    int wm = wid >> 1, wn = wid & 1;
    int lr = lane & 15, lg = lane >> 4;

    f32x4 acc[2][4];
#pragma unroll
    for (int m = 0; m < 2; ++m)
#pragma unroll
        for (int n = 0; n < 4; ++n) acc[m][n] = (f32x4){0.f, 0.f, 0.f, 0.f};

    const unsigned short* Wg = WcT + (size_t)g * 128 * 256;
#pragma unroll
    for (int ks = 0; ks < 8; ++ks) {
        int kb = ks * 32 + lg * 8;
        bf16x8 a0 = *reinterpret_cast<const bf16x8*>(&ash[wm * 32 + lr][kb]);
        bf16x8 a1 = *reinterpret_cast<const bf16x8*>(&ash[wm * 32 + 16 + lr][kb]);
        bf16x8 b[4];
#pragma unroll
        for (int n = 0; n < 4; ++n)
            b[n] = *reinterpret_cast<const bf16x8*>(Wg + (size_t)(wn * 64 + n * 16 + lr) * 256 + kb);
#pragma unroll
        for (int n = 0; n < 4; ++n) {
            acc[0][n] = __builtin_amdgcn_mfma_f32_16x16x32_bf16(a0, b[n], acc[0][n], 0, 0, 0);
            acc[1][n] = __builtin_amdgcn_mfma_f32_16x16x32_bf16(a1, b[n], acc[1][n], 0, 0, 0);
        }
    }

    __syncthreads();
    float* otf = reinterpret_cast<float*>(&ash[0][0]);   // [64][132] f32 (33792 B)
#pragma unroll
    for (int n = 0; n < 4; ++n) {
        int col = wn * 64 + n * 16 + lr;
#pragma unroll
        for (int m = 0; m < 2; ++m) {
            int rowb = wm * 32 + m * 16 + lg * 4;
#pragma unroll
            for (int r = 0; r < 4; ++r)
                otf[(rowb + r) * 132 + col] = acc[m][n][r];
        }
    }
    __syncthreads();
    for (int q = t; q < 64 * 32; q += 256) {
        int r = q >> 5, c = q & 31;
        int row = n0 + r;
        if (row < N)
            *reinterpret_cast<float4*>(&S[(size_t)row * 512 + g * 128 + c * 4]) =
                *reinterpret_cast<const float4*>(&otf[r * 132 + c * 4]);
    }
}

// ---------------- GRU gates: sigmoid/tanh + combine ----------------
__global__ void __launch_bounds__(256) k_gru_gates(
        const float* __restrict__ S, const float* __restrict__ ush,
        const float* __restrict__ gbias, float* __restrict__ outp) {
    int t = threadIdx.x;
    int n = blockIdx.x * 2 + (t >> 7);
    int u = t & 127;
    const float* b0 = gbias;
    const float* b1 = gbias + 384;
    float s0 = S[(size_t)n * 512 + u];
    float s1 = S[(size_t)n * 512 + 128 + u];
    float xh = S[(size_t)n * 512 + 256 + u];
    float rh = S[(size_t)n * 512 + 384 + u];
    float zg = 1.f / (1.f + __expf(-(s0 + b0[u] + b1[u])));
    float rg = 1.f / (1.f + __expf(-(s1 + b0[128 + u] + b1[128 + u])));
    float hh = tanhf(xh + b0[256 + u] + rg * (rh + b1[256 + u]));
    float uv = ush[(size_t)n * 128 + u];
    outp[(size_t)n * 128 + u] = zg * uv + (1.f - zg) * hh;
}

// ---------------- launch ----------------
extern "C" void kernel_launch(void* const* d_in, const int* in_sizes, int n_in,
                              void* d_out, int out_size, void* d_ws, size_t ws_size,
                              hipStream_t stream) {
    const float* node    = (const float*)d_in[0];
    const float* eattr   = (const float*)d_in[1];
    const int*   eidx    = (const int*)d_in[2];
    const float* We      = (const float*)d_in[3];
    const float* be      = (const float*)d_in[4];
    const float* gamma_e = (const float*)d_in[5];
    const float* beta_e  = (const float*)d_in[6];
    const float* Wn      = (const float*)d_in[7];
    const float* bnb     = (const float*)d_in[8];
    const float* gamma_n = (const float*)d_in[9];
    const float* beta_n  = (const float*)d_in[10];
    const float* Watt    = (const float*)d_in[11];
    const float* batt    = (const float*)d_in[12];
    const float* aatt    = (const float*)d_in[13];
    const float* Wk      = (const float*)d_in[14];
    const float* Wr      = (const float*)d_in[15];
    const float* gbias   = (const float*)d_in[16];

    float* out_node = (float*)d_out;
    float* out_edge = out_node + (size_t)NN * UU;

    char* wp = (char*)d_ws;
    auto alloc = [&](size_t bytes) {
        void* p = (void*)wp;
        wp += (bytes + 255) / 256 * 256;
        return p;
    };
    // zbf (bf16, 20.5MB) shares a region with eattr_bf (bf16, 41MB); eattr_bf dead before k_z_mfma
    unsigned short* zregion = (unsigned short*)alloc((size_t)EE * 128 * 2);
    unsigned short* zbf      = zregion;
    unsigned short* eattr_bf = zregion;
    unsigned short* ebuf = (unsigned short*)alloc((size_t)EE * 128 * 2);   // PE, then combined in-place
    float* s_src   = (float*)alloc((size_t)NN * 8 * 4);
    float* s_dst   = (float*)alloc((size_t)NN * 8 * 4);
    float* s_edge  = (float*)alloc((size_t)EE * 8 * 4);
    float* part_e  = (float*)alloc((size_t)2500 * 256 * 4);
    float* part_n  = (float*)alloc((size_t)157 * 256 * 4);
    float* scale_e = (float*)alloc(512);
    float* shift_e = (float*)alloc(512);
    float* scale_n = (float*)alloc(512);
    float* shift_n = (float*)alloc(512);
    unsigned short* nupd_bf = (unsigned short*)alloc((size_t)NN * 128 * 2);
    float* ush     = (float*)alloc((size_t)NN * 128 * 4);
    float* Sbuf    = (float*)alloc((size_t)NN * 512 * 4);
    int*   cnt     = (int*)alloc((size_t)NN * 4);
    int*   offs    = (int*)alloc((size_t)(NN + 1) * 4);
    int*   cursor  = (int*)alloc((size_t)NN * 4);
    int*   elist   = (int*)alloc((size_t)EE * 4);
    unsigned short* node_bf = (unsigned short*)alloc((size_t)NN * 128 * 2);
    unsigned short* WtE     = (unsigned short*)alloc((size_t)3 * 128 * 128 * 2);
    unsigned short* WtA     = (unsigned short*)alloc((size_t)8 * 128 * 128 * 2);
    unsigned short* WnT     = (unsigned short*)alloc((size_t)128 * 128 * 2);
    unsigned short* WcT     = (unsigned short*)alloc((size_t)512 * 256 * 2);
    unsigned short* cat     = (unsigned short*)alloc((size_t)NN * 256 * 2);
    unsigned short* p12     = (unsigned short*)alloc((size_t)NN * 256 * 2);

    hipMemsetAsync(cnt, 0, (size_t)NN * 4, stream);
    k_hist<<<(EE + 255) / 256, 256, 0, stream>>>(eidx, cnt, EE);
    k_scan<<<1, 1024, 0, stream>>>(cnt, offs, cursor, NN);
    k_scatter<<<(EE + 255) / 256, 256, 0, stream>>>(eidx, cursor, elist, EE);

    // bf16 conversions
    k_f2bf<<<1280, 256, 0, stream>>>(node, node_bf, (long)NN * 128 / 4);
    k_f2bf<<<2048, 256, 0, stream>>>(eattr, eattr_bf, (long)EE * 128 / 4);
    k_wt_edge<<<(3 * 128 * 128 + 255) / 256, 256, 0, stream>>>(We, WtE);
    k_wtg<<<(128 * 128 + 255) / 256, 256, 0, stream>>>(Wn, WnT, 128, 128);
    k_wt_att<<<(8 * 128 * 128 + 255) / 256, 256, 0, stream>>>(Watt, WtA);
    k_wt_gru<<<(512 * 256 + 255) / 256, 256, 0, stream>>>(Wk, Wr, WcT);

    // edge pipeline: PE GEMM (dense) + P12 GEMM + gather-combine (in-place on ebuf)
    k_p12_mfma<<<dim3((NN + 63) / 64, 2), 256, 0, stream>>>(node_bf, WtE, p12, NN);
    k_pe_mfma<<<EE / 64, 256, 0, stream>>>(eattr_bf, WtE, be, ebuf);
    k_edge_combine<<<EE / 64, 256, 0, stream>>>(p12, eidx, ebuf, part_e);
    k_bn_fin<<<128, 256, 0, stream>>>(part_e, EE / 64, 1.f / (float)EE,
                                      gamma_e, beta_e, scale_e, shift_e);
    k_edge_final<<<EE / 8, 256, 0, stream>>>(ebuf, scale_e, shift_e, aatt, out_edge, s_edge);

    // node/attention pipeline (k_z overwrites zregion only after k_pe consumed eattr_bf)
    k_z_mfma<<<dim3((NN + 63) / 64, 8), 256, 0, stream>>>(node_bf, WtA, batt, zbf, NN);
    k_snodes<<<NN / 4, 256, 0, stream>>>(zbf, aatt, s_src, s_dst, NN);
    k_agg<<<NN, 128, 0, stream>>>(zbf, s_src, s_dst, s_edge, offs, elist, eidx, cat);

    // node MLP + BN
    k_node_mlp_mfma<<<(NN + 63) / 64, 256, 0, stream>>>(node_bf, WnT, bnb, nupd_bf, part_n, NN);
    k_bn_fin<<<128, 256, 0, stream>>>(part_n, (NN + 63) / 64, 1.f / (float)NN,
                                      gamma_n, beta_n, scale_n, shift_n);

    // GRU
    k_gru_pre<<<(NN * 32 + 255) / 256, 256, 0, stream>>>(nupd_bf, scale_n, shift_n, cat, ush);
    k_gru_mm<<<dim3((NN + 63) / 64, 4), 256, 0, stream>>>(cat, WcT, Sbuf, NN);
    k_gru_gates<<<NN / 2, 256, 0, stream>>>(Sbuf, ush, gbias, out_node);
}

// Round 10
// 307.010 us; speedup vs baseline: 1.2361x; 1.0375x over previous
//
#include <hip/hip_runtime.h>
#include <hip/hip_bf16.h>

#define NN 10000
#define EE 160000
#define FF 128
#define UU 128
#define HH 8
#define BN_EPS 1e-3f

typedef __attribute__((ext_vector_type(8))) short bf16x8;
typedef __attribute__((ext_vector_type(8))) unsigned short u16x8;
typedef __attribute__((ext_vector_type(4))) float f32x4;

static __device__ __forceinline__ unsigned short f2bf(float f) {
    unsigned u = __float_as_uint(f);
    u += 0x7fffu + ((u >> 16) & 1u);
    return (unsigned short)(u >> 16);
}
static __device__ __forceinline__ float bf2f(unsigned short b) {
    return __uint_as_float((unsigned)b << 16);
}

// ---------------- f32 -> bf16 bulk convert (count divisible by 4) ----------------
__global__ void k_f2bf(const float* __restrict__ in, unsigned short* __restrict__ out, long n4) {
    long i = (long)blockIdx.x * 256 + threadIdx.x;
    long stride = (long)gridDim.x * 256;
    for (; i < n4; i += stride) {
        float4 v = reinterpret_cast<const float4*>(in)[i];
        ushort4 o;
        o.x = f2bf(v.x); o.y = f2bf(v.y); o.z = f2bf(v.z); o.w = f2bf(v.w);
        reinterpret_cast<ushort4*>(out)[i] = o;
    }
}

// ---------------- generic W [K][U] f32 -> W^T [U][K] bf16 ----------------
__global__ void k_wtg(const float* __restrict__ W, unsigned short* __restrict__ Wt, int K, int U) {
    int i = blockIdx.x * 256 + threadIdx.x;
    if (i < K * U) {
        int k = i / U, u = i - k * U;
        Wt[u * K + k] = f2bf(W[i]);
    }
}

// ---------------- W_edge [384][128] -> WtE [3][128 u][128 k] bf16 ----------------
__global__ void k_wt_edge(const float* __restrict__ We, unsigned short* __restrict__ WtE) {
    int i = blockIdx.x * 256 + threadIdx.x;   // over 3*128*128
    if (i < 3 * 128 * 128) {
        int s = i >> 14, rem = i & 16383, u = rem >> 7, k = rem & 127;
        WtE[i] = f2bf(We[(s * 128 + k) * 128 + u]);
    }
}

// ---------------- W_att [8][128][128] f32 -> per-head W^T [8][128][128] bf16 ----------------
__global__ void k_wt_att(const float* __restrict__ W, unsigned short* __restrict__ Wt) {
    int i = blockIdx.x * 256 + threadIdx.x;   // over 8*128*128
    if (i < 8 * 128 * 128) {
        int h = i >> 14, rem = i & 16383, f = rem >> 7, u = rem & 127;
        Wt[h * 16384 + u * 128 + f] = f2bf(W[i]);
    }
}

// ---------------- a_att transpose: aT[u][0..7]=a_src[h][u], aT[u][8..15]=a_dst[h][u] ----------------
__global__ void k_at(const float* __restrict__ aatt, float* __restrict__ aT) {
    int i = blockIdx.x * 256 + threadIdx.x;   // over 128*16
    if (i < 128 * 16) {
        int u = i >> 4, j = i & 15;
        int h = j & 7, part = j >> 3;         // part 0: src, 1: dst
        aT[u * 16 + j] = aatt[h * 384 + part * 128 + u];
    }
}

// ---------------- GRU combined weight: WcT [512][256] bf16 ----------------
__global__ void k_wt_gru(const float* __restrict__ Wk, const float* __restrict__ Wr,
                         unsigned short* __restrict__ WcT) {
    int i = blockIdx.x * 256 + threadIdx.x;   // over 512*256
    if (i >= 512 * 256) return;
    int c = i >> 8, k = i & 255;
    float v;
    if (c < 256)       v = (k < 128) ? Wk[k * 384 + c] : Wr[(k - 128) * 384 + c];
    else if (c < 384)  v = (k < 128) ? Wk[k * 384 + c] : 0.f;
    else               v = (k < 128) ? 0.f : Wr[(k - 128) * 384 + (c - 128)];
    WcT[c * 256 + k] = f2bf(v);
}

// ---------------- CSR construction ----------------
__global__ void k_hist(const int* __restrict__ eidx, int* __restrict__ cnt, int E) {
    int e = blockIdx.x * 256 + threadIdx.x;
    if (e < E) atomicAdd(&cnt[eidx[2 * e]], 1);   // dst = eidx[e][0]
}

__global__ void k_scan(const int* __restrict__ cnt, int* __restrict__ off,
                       int* __restrict__ cursor, int N) {
    __shared__ int s[1024];
    int t = threadIdx.x;
    int run = 0;
    if (t == 0) off[0] = 0;
    for (int base = 0; base < N; base += 1024) {
        int x = (base + t < N) ? cnt[base + t] : 0;
        s[t] = x;
        __syncthreads();
        for (int o = 1; o < 1024; o <<= 1) {
            int v = (t >= o) ? s[t - o] : 0;
            __syncthreads();
            s[t] += v;
            __syncthreads();
        }
        if (base + t < N) {
            off[base + t + 1] = run + s[t];
            cursor[base + t] = run + s[t] - x;
        }
        run += s[1023];
        __syncthreads();
    }
}

__global__ void k_scatter(const int* __restrict__ eidx, int* __restrict__ cursor,
                          int* __restrict__ elist, int E) {
    int e = blockIdx.x * 256 + threadIdx.x;
    if (e < E) {
        int d = eidx[2 * e];
        int p = atomicAdd(&cursor[d], 1);
        elist[p] = e;
    }
}

// ---------------- z (bf16, layout (N,U,H)) = node @ W_att[h] + b_att[h], all heads ----------------
// 16 rows/block, 4 waves x 2 heads each. C staged in LDS with row-XOR swizzle, 16B writeout.
__global__ void __launch_bounds__(256) k_z8(
        const unsigned short* __restrict__ node_bf, const unsigned short* __restrict__ WtA,
        const float* __restrict__ batt, unsigned short* __restrict__ zt) {
    __shared__ unsigned short lds[16 * 1032];    // C: row stride 1032 shorts; A aliased at front
    int n0 = blockIdx.x * 16;
    int t = threadIdx.x;
    // stage A: 16 rows x 128 cols bf16, row stride 136 shorts (within lds)
    {
        int r = t >> 4, c = t & 15;
        *reinterpret_cast<uint4*>(&lds[r * 136 + c * 8]) =
            *reinterpret_cast<const uint4*>(node_bf + (size_t)(n0 + r) * 128 + c * 8);
    }
    __syncthreads();

    int wid = t >> 6, lane = t & 63;
    int lr = lane & 15, lg = lane >> 4;

    f32x4 acc[2][8];
#pragma unroll
    for (int hh = 0; hh < 2; ++hh)
#pragma unroll
        for (int nt = 0; nt < 8; ++nt) acc[hh][nt] = (f32x4){0.f, 0.f, 0.f, 0.f};

#pragma unroll
    for (int ks = 0; ks < 4; ++ks) {
        int kb = ks * 32 + lg * 8;
        bf16x8 a = *reinterpret_cast<const bf16x8*>(&lds[lr * 136 + kb]);
#pragma unroll
        for (int hh = 0; hh < 2; ++hh) {
            const unsigned short* Wh = WtA + (size_t)(wid * 2 + hh) * 16384;
#pragma unroll
            for (int nt = 0; nt < 8; ++nt) {
                bf16x8 b = *reinterpret_cast<const bf16x8*>(Wh + (size_t)(nt * 16 + lr) * 128 + kb);
                acc[hh][nt] = __builtin_amdgcn_mfma_f32_16x16x32_bf16(a, b, acc[hh][nt], 0, 0, 0);
            }
        }
    }

    __syncthreads();                     // A reads done; reuse lds as (U,H)-interleaved C
#pragma unroll
    for (int hh = 0; hh < 2; ++hh) {
        int head = wid * 2 + hh;
#pragma unroll
        for (int nt = 0; nt < 8; ++nt) {
            int col = nt * 16 + lr;
            float bias = batt[head * 128 + col];
#pragma unroll
            for (int r = 0; r < 4; ++r) {
                int row = lg * 4 + r;
                lds[row * 1032 + ((col * 8) ^ ((row & 3) << 4)) + head] =
                    f2bf(acc[hh][nt][r] + bias);
            }
        }
    }
    __syncthreads();
    for (int q = t; q < 16 * 128; q += 256) {
        int row = q >> 7, c = q & 127;
        *reinterpret_cast<uint4*>(&zt[(size_t)(n0 + row) * 1024 + c * 8]) =
            *reinterpret_cast<const uint4*>(&lds[row * 1032 + ((c * 8) ^ ((row & 3) << 4))]);
    }
}

// ---------------- s_src[n,h], s_dst[n,h] from zt (N,U,H): wave = node ----------------
__global__ void __launch_bounds__(256) k_snodes(
        const unsigned short* __restrict__ zt, const float* __restrict__ aT,
        float* __restrict__ s_src, float* __restrict__ s_dst) {
    int t = threadIdx.x;
    int wid = t >> 6, lane = t & 63;
    int n = blockIdx.x * 4 + wid;
    float vs[8], vd[8];
#pragma unroll
    for (int h = 0; h < 8; ++h) { vs[h] = 0.f; vd[h] = 0.f; }
#pragma unroll
    for (int p = 0; p < 2; ++p) {
        int u = p * 64 + lane;
        u16x8 zv = *reinterpret_cast<const u16x8*>(zt + (size_t)n * 1024 + u * 8);
        const float* a = aT + u * 16;
#pragma unroll
        for (int h = 0; h < 8; ++h) {
            float z = bf2f(zv[h]);
            vs[h] = fmaf(z, a[h], vs[h]);
            vd[h] = fmaf(z, a[8 + h], vd[h]);
        }
    }
#pragma unroll
    for (int o = 1; o < 64; o <<= 1) {
#pragma unroll
        for (int h = 0; h < 8; ++h) {
            vs[h] += __shfl_xor(vs[h], o, 64);
            vd[h] += __shfl_xor(vd[h], o, 64);
        }
    }
    if (lane == 0) {
#pragma unroll
        for (int h = 0; h < 8; ++h) {
            s_src[n * 8 + h] = vs[h];
            s_dst[n * 8 + h] = vd[h];
        }
    }
}

// ---------------- P12 (bf16) = node @ [W1|W2], MFMA, out N x 256 ----------------
__global__ void __launch_bounds__(256) k_p12_mfma(
        const unsigned short* __restrict__ node_bf, const unsigned short* __restrict__ WtE,
        unsigned short* __restrict__ p12, int N) {
    __shared__ unsigned short ash[64][136];
    int n0 = blockIdx.x * 64;
    int s = blockIdx.y;                    // 0: W1 (src part), 1: W2 (dst part)
    int t = threadIdx.x;
    for (int q = t; q < 64 * 16; q += 256) {
        int r = q >> 4, c = q & 15;
        int n = n0 + r; if (n >= N) n = N - 1;
        *reinterpret_cast<uint4*>(&ash[r][c * 8]) =
            *reinterpret_cast<const uint4*>(node_bf + (size_t)n * 128 + c * 8);
    }
    __syncthreads();

    int wid = t >> 6, lane = t & 63;
    int wm = wid >> 1, wn = wid & 1;
    int lr = lane & 15, lg = lane >> 4;

    f32x4 acc[2][4];
#pragma unroll
    for (int m = 0; m < 2; ++m)
#pragma unroll
        for (int n = 0; n < 4; ++n) acc[m][n] = (f32x4){0.f, 0.f, 0.f, 0.f};

    const unsigned short* Wh = WtE + (size_t)s * 16384;
#pragma unroll
    for (int ks = 0; ks < 4; ++ks) {
        int kb = ks * 32 + lg * 8;
        bf16x8 a0 = *reinterpret_cast<const bf16x8*>(&ash[wm * 32 + lr][kb]);
        bf16x8 a1 = *reinterpret_cast<const bf16x8*>(&ash[wm * 32 + 16 + lr][kb]);
        bf16x8 b[4];
#pragma unroll
        for (int n = 0; n < 4; ++n)
            b[n] = *reinterpret_cast<const bf16x8*>(Wh + (size_t)(wn * 64 + n * 16 + lr) * 128 + kb);
#pragma unroll
        for (int n = 0; n < 4; ++n) {
            acc[0][n] = __builtin_amdgcn_mfma_f32_16x16x32_bf16(a0, b[n], acc[0][n], 0, 0, 0);
            acc[1][n] = __builtin_amdgcn_mfma_f32_16x16x32_bf16(a1, b[n], acc[1][n], 0, 0, 0);
        }
    }

    __syncthreads();
    unsigned short* ot = &ash[0][0];
#pragma unroll
    for (int n = 0; n < 4; ++n) {
        int col = wn * 64 + n * 16 + lr;
#pragma unroll
        for (int m = 0; m < 2; ++m) {
            int rowb = wm * 32 + m * 16 + lg * 4;
#pragma unroll
            for (int r = 0; r < 4; ++r)
                ot[(rowb + r) * 136 + col] = f2bf(acc[m][n][r]);
        }
    }
    __syncthreads();
    for (int q = t; q < 64 * 16; q += 256) {
        int r = q >> 4, c = q & 15;
        int row = n0 + r;
        if (row < N)
            *reinterpret_cast<uint4*>(&p12[(size_t)row * 256 + s * 128 + c * 8]) =
                *reinterpret_cast<const uint4*>(&ot[r * 136 + c * 8]);
    }
}

// ---------------- PE+combine fused: ebuf = relu(eattr@W3 + be + P1[src] + P2[dst]), BN partials ----------------
__global__ void __launch_bounds__(256) k_pe_comb(
        const float* __restrict__ eattr, const unsigned short* __restrict__ WtE,
        const float* __restrict__ be, const unsigned short* __restrict__ p12,
        const int* __restrict__ eidx, unsigned short* __restrict__ ebuf,
        float* __restrict__ part) {
    __shared__ unsigned short ash[64][136];     // A-tile (bf16 of eattr), then C-tile
    __shared__ unsigned short pcomb[64][136];   // p1[src]+p2[dst] per edge row
    __shared__ int sd[128];
    __shared__ float sbuf[4][64], qbuf[4][64];
    int e0 = blockIdx.x * 64;
    int t = threadIdx.x;
    if (t < 128) sd[t] = eidx[e0 * 2 + t];      // [e][0]=dst, [e][1]=src
    __syncthreads();
    // stage A: f32 -> bf16 (4 floats per chunk)
    for (int q = t; q < 64 * 32; q += 256) {
        int r = q >> 5, c = q & 31;
        float4 v = *reinterpret_cast<const float4*>(eattr + (size_t)(e0 + r) * 128 + c * 4);
        ushort4 o;
        o.x = f2bf(v.x); o.y = f2bf(v.y); o.z = f2bf(v.z); o.w = f2bf(v.w);
        *reinterpret_cast<ushort4*>(&ash[r][c * 4]) = o;
    }
    // stage pcomb: p1[src] + p2[dst] (f32 add, bf16 store)
    for (int q = t; q < 64 * 16; q += 256) {
        int r = q >> 4, c = q & 15;
        int dst = sd[r * 2], src = sd[r * 2 + 1];
        u16x8 a = *reinterpret_cast<const u16x8*>(p12 + (size_t)src * 256 + c * 8);
        u16x8 b = *reinterpret_cast<const u16x8*>(p12 + (size_t)dst * 256 + 128 + c * 8);
        u16x8 o;
#pragma unroll
        for (int j = 0; j < 8; ++j) o[j] = f2bf(bf2f(a[j]) + bf2f(b[j]));
        *reinterpret_cast<u16x8*>(&pcomb[r][c * 8]) = o;
    }
    __syncthreads();

    int wid = t >> 6, lane = t & 63;
    int wm = wid >> 1, wn = wid & 1;
    int lr = lane & 15, lg = lane >> 4;

    f32x4 acc[2][4];
#pragma unroll
    for (int m = 0; m < 2; ++m)
#pragma unroll
        for (int n = 0; n < 4; ++n) acc[m][n] = (f32x4){0.f, 0.f, 0.f, 0.f};

    const unsigned short* Wh = WtE + (size_t)2 * 16384;
#pragma unroll
    for (int ks = 0; ks < 4; ++ks) {
        int kb = ks * 32 + lg * 8;
        bf16x8 a0 = *reinterpret_cast<const bf16x8*>(&ash[wm * 32 + lr][kb]);
        bf16x8 a1 = *reinterpret_cast<const bf16x8*>(&ash[wm * 32 + 16 + lr][kb]);
        bf16x8 b[4];
#pragma unroll
        for (int n = 0; n < 4; ++n)
            b[n] = *reinterpret_cast<const bf16x8*>(Wh + (size_t)(wn * 64 + n * 16 + lr) * 128 + kb);
#pragma unroll
        for (int n = 0; n < 4; ++n) {
            acc[0][n] = __builtin_amdgcn_mfma_f32_16x16x32_bf16(a0, b[n], acc[0][n], 0, 0, 0);
            acc[1][n] = __builtin_amdgcn_mfma_f32_16x16x32_bf16(a1, b[n], acc[1][n], 0, 0, 0);
        }
    }

    __syncthreads();                      // A reads done; reuse ash as C-tile
    unsigned short* ot = &ash[0][0];
    float s[4] = {0.f, 0.f, 0.f, 0.f}, q[4] = {0.f, 0.f, 0.f, 0.f};
#pragma unroll
    for (int n = 0; n < 4; ++n) {
        int col = wn * 64 + n * 16 + lr;
        float bias = be[col];
#pragma unroll
        for (int m = 0; m < 2; ++m) {
            int rowb = wm * 32 + m * 16 + lg * 4;
#pragma unroll
            for (int r = 0; r < 4; ++r) {
                int row = rowb + r;
                float v = acc[m][n][r] + bias + bf2f(pcomb[row][col]);
                v = v > 0.f ? v : 0.f;
                ot[row * 136 + col] = f2bf(v);
                s[n] += v;
                q[n] += v * v;
            }
        }
    }
#pragma unroll
    for (int n = 0; n < 4; ++n) {
        s[n] += __shfl_xor(s[n], 16, 64);
        s[n] += __shfl_xor(s[n], 32, 64);
        q[n] += __shfl_xor(q[n], 16, 64);
        q[n] += __shfl_xor(q[n], 32, 64);
    }
    if (lane < 16) {
#pragma unroll
        for (int n = 0; n < 4; ++n) {
            sbuf[wid][n * 16 + lane] = s[n];
            qbuf[wid][n * 16 + lane] = q[n];
        }
    }
    __syncthreads();
    for (int q2 = t; q2 < 64 * 16; q2 += 256) {
        int r = q2 >> 4, c = q2 & 15;
        *reinterpret_cast<uint4*>(&ebuf[(size_t)(e0 + r) * 128 + c * 8]) =
            *reinterpret_cast<const uint4*>(&ot[r * 136 + c * 8]);
    }
    if (t < 128) {
        int half = t >> 6, c = t & 63;
        part[(size_t)blockIdx.x * 256 + t] = sbuf[half][c] + sbuf[2 + half][c];
        part[(size_t)blockIdx.x * 256 + 128 + t] = qbuf[half][c] + qbuf[2 + half][c];
    }
}

// ---------------- node MLP via MFMA: relu(node @ W_node + b) -> bf16, BN partials ----------------
__global__ void __launch_bounds__(256) k_node_mlp_mfma(
        const unsigned short* __restrict__ node_bf, const unsigned short* __restrict__ WnT,
        const float* __restrict__ bn, unsigned short* __restrict__ nupd_bf,
        float* __restrict__ part, int N) {
    __shared__ unsigned short ash[64][136];
    __shared__ float sbuf[4][64], qbuf[4][64];
    int n0 = blockIdx.x * 64;
    int t = threadIdx.x;
    for (int q = t; q < 64 * 16; q += 256) {
        int r = q >> 4, c = q & 15;
        int n = n0 + r; if (n >= N) n = N - 1;
        *reinterpret_cast<uint4*>(&ash[r][c * 8]) =
            *reinterpret_cast<const uint4*>(node_bf + (size_t)n * 128 + c * 8);
    }
    __syncthreads();

    int wid = t >> 6, lane = t & 63;
    int wm = wid >> 1, wn = wid & 1;
    int lr = lane & 15, lg = lane >> 4;

    f32x4 acc[2][4];
#pragma unroll
    for (int m = 0; m < 2; ++m)
#pragma unroll
        for (int n = 0; n < 4; ++n) acc[m][n] = (f32x4){0.f, 0.f, 0.f, 0.f};

#pragma unroll
    for (int ks = 0; ks < 4; ++ks) {
        int kb = ks * 32 + lg * 8;
        bf16x8 a0 = *reinterpret_cast<const bf16x8*>(&ash[wm * 32 + lr][kb]);
        bf16x8 a1 = *reinterpret_cast<const bf16x8*>(&ash[wm * 32 + 16 + lr][kb]);
        bf16x8 b[4];
#pragma unroll
        for (int n = 0; n < 4; ++n)
            b[n] = *reinterpret_cast<const bf16x8*>(WnT + (size_t)(wn * 64 + n * 16 + lr) * 128 + kb);
#pragma unroll
        for (int n = 0; n < 4; ++n) {
            acc[0][n] = __builtin_amdgcn_mfma_f32_16x16x32_bf16(a0, b[n], acc[0][n], 0, 0, 0);
            acc[1][n] = __builtin_amdgcn_mfma_f32_16x16x32_bf16(a1, b[n], acc[1][n], 0, 0, 0);
        }
    }

    __syncthreads();
    unsigned short* ot = &ash[0][0];
    float s[4] = {0.f, 0.f, 0.f, 0.f}, q[4] = {0.f, 0.f, 0.f, 0.f};
#pragma unroll
    for (int n = 0; n < 4; ++n) {
        int col = wn * 64 + n * 16 + lr;
        float bias = bn[col];
#pragma unroll
        for (int m = 0; m < 2; ++m) {
            int rowb = wm * 32 + m * 16 + lg * 4;
#pragma unroll
            for (int r = 0; r < 4; ++r) {
                int row = n0 + rowb + r;
                float v = acc[m][n][r] + bias;
                v = v > 0.f ? v : 0.f;
                ot[(rowb + r) * 136 + col] = f2bf(v);
                if (row < N) { s[n] += v; q[n] += v * v; }
            }
        }
    }
#pragma unroll
    for (int n = 0; n < 4; ++n) {
        s[n] += __shfl_xor(s[n], 16, 64);
        s[n] += __shfl_xor(s[n], 32, 64);
        q[n] += __shfl_xor(q[n], 16, 64);
        q[n] += __shfl_xor(q[n], 32, 64);
    }
    if (lane < 16) {
#pragma unroll
        for (int n = 0; n < 4; ++n) {
            sbuf[wid][n * 16 + lane] = s[n];
            qbuf[wid][n * 16 + lane] = q[n];
        }
    }
    __syncthreads();
    for (int q2 = t; q2 < 64 * 16; q2 += 256) {
        int r = q2 >> 4, c = q2 & 15;
        int row = n0 + r;
        if (row < N)
            *reinterpret_cast<uint4*>(&nupd_bf[(size_t)row * 128 + c * 8]) =
                *reinterpret_cast<const uint4*>(&ot[r * 136 + c * 8]);
    }
    if (t < 128) {
        int half = t >> 6, c = t & 63;
        part[(size_t)blockIdx.x * 256 + t] = sbuf[half][c] + sbuf[2 + half][c];
        part[(size_t)blockIdx.x * 256 + 128 + t] = qbuf[half][c] + qbuf[2 + half][c];
    }
}

// ---------------- BN finalize: scale/shift per column ----------------
__global__ void k_bn_fin(const float* __restrict__ part, int nblk, float invcnt,
                         const float* __restrict__ g, const float* __restrict__ b,
                         float* __restrict__ scale, float* __restrict__ shift) {
    int u = blockIdx.x;               // 128 blocks
    int t = threadIdx.x;              // 256
    float s = 0.f, q = 0.f;
    for (int i = t; i < nblk; i += 256) {
        s += part[(size_t)i * 256 + u];
        q += part[(size_t)i * 256 + 128 + u];
    }
    __shared__ float ls[4], lq[4];
    for (int o = 32; o > 0; o >>= 1) {
        s += __shfl_down(s, o, 64);
        q += __shfl_down(q, o, 64);
    }
    int lane = t & 63, w = t >> 6;
    if (lane == 0) { ls[w] = s; lq[w] = q; }
    __syncthreads();
    if (t == 0) {
        float S = ls[0] + ls[1] + ls[2] + ls[3];
        float Q = lq[0] + lq[1] + lq[2] + lq[3];
        float mean = S * invcnt;
        float var = Q * invcnt - mean * mean;
        float inv = rsqrtf(var + BN_EPS);
        float sc = g[u] * inv;
        scale[u] = sc;
        shift[u] = b[u] - mean * sc;
    }
}

// ---------------- edge finalize: wave=2 edges, lane=4 cols; BN apply + s_edge ----------------
__global__ void __launch_bounds__(256) k_edge_final(
        const unsigned short* __restrict__ ebuf, const float* __restrict__ scale,
        const float* __restrict__ shift, const float* __restrict__ aatt,
        float* __restrict__ eout, float* __restrict__ s_edge) {
    int t = threadIdx.x;
    int w = t >> 6, lane = t & 63;
    int q = lane & 31, half = lane >> 5;
    int e = blockIdx.x * 8 + w * 2 + half;

    float4 sc = *reinterpret_cast<const float4*>(scale + q * 4);
    float4 sh = *reinterpret_cast<const float4*>(shift + q * 4);
    float4 a4[8];
#pragma unroll
    for (int h = 0; h < 8; ++h)
        a4[h] = *reinterpret_cast<const float4*>(aatt + h * 384 + 256 + q * 4);

    ushort4 xb = *reinterpret_cast<const ushort4*>(ebuf + (size_t)e * 128 + q * 4);
    float4 x;
    x.x = bf2f(xb.x) * sc.x + sh.x;
    x.y = bf2f(xb.y) * sc.y + sh.y;
    x.z = bf2f(xb.z) * sc.z + sh.z;
    x.w = bf2f(xb.w) * sc.w + sh.w;
    *reinterpret_cast<float4*>(eout + (size_t)e * 128 + q * 4) = x;

    float v[8];
#pragma unroll
    for (int h = 0; h < 8; ++h)
        v[h] = x.x * a4[h].x + x.y * a4[h].y + x.z * a4[h].z + x.w * a4[h].w;
#pragma unroll
    for (int o = 1; o < 32; o <<= 1) {
#pragma unroll
        for (int h = 0; h < 8; ++h) v[h] += __shfl_xor(v[h], o, 64);
    }
    if (q == 0) {
#pragma unroll
        for (int h = 0; h < 8; ++h) s_edge[e * 8 + h] = v[h];
    }
}

// ---------------- attention softmax + aggregation; zt layout (N,U,H); bf16 out into cat ----------------
__global__ void k_agg(const unsigned short* __restrict__ zt, const float* __restrict__ s_src,
                      const float* __restrict__ s_dst, const float* __restrict__ s_edge,
                      const int* __restrict__ off, const int* __restrict__ elist,
                      const int* __restrict__ eidx, unsigned short* __restrict__ cat) {
    int n = blockIdx.x;
    int t = threadIdx.x;              // 128
    int beg = off[n], end = off[n + 1];
    int deg = end - beg;
    if (deg == 0) { cat[(size_t)n * 256 + t] = 0; return; }

    float sdh[8];
#pragma unroll
    for (int h = 0; h < 8; ++h) sdh[h] = s_dst[n * 8 + h];

    __shared__ float lred[16];
    __shared__ float wbuf[128][8];
    __shared__ int snbuf[128];

    float mx[8], den[8];
#pragma unroll
    for (int h = 0; h < 8; ++h) { mx[h] = -1e30f; den[h] = 0.f; }

    int lane = t & 63, w = t >> 6;

    // pass 1: running max / denominator (online across chunks of 128)
    for (int c0 = 0; c0 < deg; c0 += 128) {
        int cn = min(128, deg - c0);
        bool act = t < cn;
        int e = 0, sn = 0;
        if (act) { e = elist[beg + c0 + t]; sn = eidx[2 * e + 1]; }
        float lg[8];
#pragma unroll
        for (int h = 0; h < 8; ++h) {
            float x = act ? (s_src[sn * 8 + h] + sdh[h] + s_edge[e * 8 + h]) : -1e30f;
            lg[h] = x >= 0.f ? x : 0.2f * x;
        }
        float cm[8];
#pragma unroll
        for (int h = 0; h < 8; ++h) cm[h] = lg[h];
        for (int o = 32; o > 0; o >>= 1) {
#pragma unroll
            for (int h = 0; h < 8; ++h) cm[h] = fmaxf(cm[h], __shfl_down(cm[h], o, 64));
        }
        if (lane == 0) {
#pragma unroll
            for (int h = 0; h < 8; ++h) lred[w * 8 + h] = cm[h];
        }
        __syncthreads();
#pragma unroll
        for (int h = 0; h < 8; ++h) cm[h] = fmaxf(lred[h], lred[8 + h]);
        __syncthreads();
        float cs[8];
#pragma unroll
        for (int h = 0; h < 8; ++h) cs[h] = act ? __expf(lg[h] - cm[h]) : 0.f;
        for (int o = 32; o > 0; o >>= 1) {
#pragma unroll
            for (int h = 0; h < 8; ++h) cs[h] += __shfl_down(cs[h], o, 64);
        }
        if (lane == 0) {
#pragma unroll
            for (int h = 0; h < 8; ++h) lred[w * 8 + h] = cs[h];
        }
        __syncthreads();
#pragma unroll
        for (int h = 0; h < 8; ++h) {
            float csum = lred[h] + lred[8 + h];
            float nm = fmaxf(mx[h], cm[h]);
            den[h] = den[h] * __expf(mx[h] - nm) + csum * __expf(cm[h] - nm);
            mx[h] = nm;
        }
        __syncthreads();
    }
    float inv[8];
#pragma unroll
    for (int h = 0; h < 8; ++h) inv[h] = 1.f / den[h];

    // pass 2: weights into LDS, then accumulate Σ_h alpha_h * z[src, u=t, h] (16B vec load)
    float acc = 0.f;
    for (int c0 = 0; c0 < deg; c0 += 128) {
        int cn = min(128, deg - c0);
        if (t < cn) {
            int e = elist[beg + c0 + t];
            int sn = eidx[2 * e + 1];
            snbuf[t] = sn;
#pragma unroll
            for (int h = 0; h < 8; ++h) {
                float x = s_src[sn * 8 + h] + sdh[h] + s_edge[e * 8 + h];
                x = x >= 0.f ? x : 0.2f * x;
                wbuf[t][h] = __expf(x - mx[h]) * inv[h];
            }
        }
        __syncthreads();
        for (int i = 0; i < cn; ++i) {
            int sn = snbuf[i];
            u16x8 zv = *reinterpret_cast<const u16x8*>(zt + (size_t)sn * 1024 + t * 8);
            float4 w0 = *reinterpret_cast<const float4*>(&wbuf[i][0]);
            float4 w1 = *reinterpret_cast<const float4*>(&wbuf[i][4]);
            acc = fmaf(w0.x, bf2f(zv[0]), acc);
            acc = fmaf(w0.y, bf2f(zv[1]), acc);
            acc = fmaf(w0.z, bf2f(zv[2]), acc);
            acc = fmaf(w0.w, bf2f(zv[3]), acc);
            acc = fmaf(w1.x, bf2f(zv[4]), acc);
            acc = fmaf(w1.y, bf2f(zv[5]), acc);
            acc = fmaf(w1.z, bf2f(zv[6]), acc);
            acc = fmaf(w1.w, bf2f(zv[7]), acc);
        }
        __syncthreads();
    }
    cat[(size_t)n * 256 + t] = f2bf(fmaxf(acc * 0.125f, 0.f));
}

// ---------------- GRU pre: ush = BN(nupd_bf); cat[:,128:256] = bf16(ush) ----------------
__global__ void k_gru_pre(const unsigned short* __restrict__ nupd_bf, const float* __restrict__ scale,
                          const float* __restrict__ shift, unsigned short* __restrict__ cat,
                          float* __restrict__ ush) {
    int i = blockIdx.x * 256 + threadIdx.x;   // over NN*32
    if (i >= NN * 32) return;
    int n = i >> 5, j4 = (i & 31) * 4;
    ushort4 ub_in = *reinterpret_cast<const ushort4*>(nupd_bf + (size_t)n * 128 + j4);
    float4 sc = *reinterpret_cast<const float4*>(scale + j4);
    float4 sh = *reinterpret_cast<const float4*>(shift + j4);
    float4 uv;
    uv.x = bf2f(ub_in.x) * sc.x + sh.x;
    uv.y = bf2f(ub_in.y) * sc.y + sh.y;
    uv.z = bf2f(ub_in.z) * sc.z + sh.z;
    uv.w = bf2f(ub_in.w) * sc.w + sh.w;
    ushort4 ub;
    ub.x = f2bf(uv.x); ub.y = f2bf(uv.y); ub.z = f2bf(uv.z); ub.w = f2bf(uv.w);
    *reinterpret_cast<ushort4*>(cat + (size_t)n * 256 + 128 + j4) = ub;
    *reinterpret_cast<float4*>(ush + (size_t)n * 128 + j4) = uv;
}

// ---------------- GRU GEMM: S = cat @ Wc  (M x 256 x 512), MFMA, LDS-coalesced store ----------------
__global__ void __launch_bounds__(256) k_gru_mm(
        const unsigned short* __restrict__ cat, const unsigned short* __restrict__ WcT,
        float* __restrict__ S, int N) {
    __shared__ unsigned short ash[64][264];     // 256 + 8 pad (33792 B)
    int n0 = blockIdx.x * 64;
    int g = blockIdx.y;                          // col group 0..3
    int t = threadIdx.x;
    for (int q = t; q < 64 * 32; q += 256) {
        int r = q >> 5, c = q & 31;
        int n = n0 + r; if (n >= N) n = N - 1;
        *reinterpret_cast<uint4*>(&ash[r][c * 8]) =
            *reinterpret_cast<const uint4*>(cat + (size_t)n * 256 + c * 8);
    }
    __syncthreads();

    int wid = t >> 6, lane = t & 63;
    int wm = wid >> 1, wn = wid & 1;
    int lr = lane & 15, lg = lane >> 4;

    f32x4 acc[2][4];
#pragma unroll
    for (int m = 0; m < 2; ++m)
#pragma unroll
        for (int n = 0; n < 4; ++n) acc[m][n] = (f32x4){0.f, 0.f, 0.f, 0.f};

    const unsigned short* Wg = WcT + (size_t)g * 128 * 256;
#pragma unroll
    for (int ks = 0; ks < 8; ++ks) {
        int kb = ks * 32 + lg * 8;
        bf16x8 a0 = *reinterpret_cast<const bf16x8*>(&ash[wm * 32 + lr][kb]);
        bf16x8 a1 = *reinterpret_cast<const bf16x8*>(&ash[wm * 32 + 16 + lr][kb]);
        bf16x8 b[4];
#pragma unroll
        for (int n = 0; n < 4; ++n)
            b[n] = *reinterpret_cast<const bf16x8*>(Wg + (size_t)(wn * 64 + n * 16 + lr) * 256 + kb);
#pragma unroll
        for (int n = 0; n < 4; ++n) {
            acc[0][n] = __builtin_amdgcn_mfma_f32_16x16x32_bf16(a0, b[n], acc[0][n], 0, 0, 0);
            acc[1][n] = __builtin_amdgcn_mfma_f32_16x16x32_bf16(a1, b[n], acc[1][n], 0, 0, 0);
        }
    }

    __syncthreads();
    float* otf = reinterpret_cast<float*>(&ash[0][0]);   // [64][132] f32 (33792 B)
#pragma unroll
    for (int n = 0; n < 4; ++n) {
        int col = wn * 64 + n * 16 + lr;
#pragma unroll
        for (int m = 0; m < 2; ++m) {
            int rowb = wm * 32 + m * 16 + lg * 4;
#pragma unroll
            for (int r = 0; r < 4; ++r)
                otf[(rowb + r) * 132 + col] = acc[m][n][r];
        }
    }
    __syncthreads();
    for (int q = t; q < 64 * 32; q += 256) {
        int r = q >> 5, c = q & 31;
        int row = n0 + r;
        if (row < N)
            *reinterpret_cast<float4*>(&S[(size_t)row * 512 + g * 128 + c * 4]) =
                *reinterpret_cast<const float4*>(&otf[r * 132 + c * 4]);
    }
}

// ---------------- GRU gates: sigmoid/tanh + combine ----------------
__global__ void __launch_bounds__(256) k_gru_gates(
        const float* __restrict__ S, const float* __restrict__ ush,
        const float* __restrict__ gbias, float* __restrict__ outp) {
    int t = threadIdx.x;
    int n = blockIdx.x * 2 + (t >> 7);
    int u = t & 127;
    const float* b0 = gbias;
    const float* b1 = gbias + 384;
    float s0 = S[(size_t)n * 512 + u];
    float s1 = S[(size_t)n * 512 + 128 + u];
    float xh = S[(size_t)n * 512 + 256 + u];
    float rh = S[(size_t)n * 512 + 384 + u];
    float zg = 1.f / (1.f + __expf(-(s0 + b0[u] + b1[u])));
    float rg = 1.f / (1.f + __expf(-(s1 + b0[128 + u] + b1[128 + u])));
    float hh = tanhf(xh + b0[256 + u] + rg * (rh + b1[256 + u]));
    float uv = ush[(size_t)n * 128 + u];
    outp[(size_t)n * 128 + u] = zg * uv + (1.f - zg) * hh;
}

// ---------------- launch ----------------
extern "C" void kernel_launch(void* const* d_in, const int* in_sizes, int n_in,
                              void* d_out, int out_size, void* d_ws, size_t ws_size,
                              hipStream_t stream) {
    const float* node    = (const float*)d_in[0];
    const float* eattr   = (const float*)d_in[1];
    const int*   eidx    = (const int*)d_in[2];
    const float* We      = (const float*)d_in[3];
    const float* be      = (const float*)d_in[4];
    const float* gamma_e = (const float*)d_in[5];
    const float* beta_e  = (const float*)d_in[6];
    const float* Wn      = (const float*)d_in[7];
    const float* bnb     = (const float*)d_in[8];
    const float* gamma_n = (const float*)d_in[9];
    const float* beta_n  = (const float*)d_in[10];
    const float* Watt    = (const float*)d_in[11];
    const float* batt    = (const float*)d_in[12];
    const float* aatt    = (const float*)d_in[13];
    const float* Wk      = (const float*)d_in[14];
    const float* Wr      = (const float*)d_in[15];
    const float* gbias   = (const float*)d_in[16];

    float* out_node = (float*)d_out;
    float* out_edge = out_node + (size_t)NN * UU;

    char* wp = (char*)d_ws;
    auto alloc = [&](size_t bytes) {
        void* p = (void*)wp;
        wp += (bytes + 255) / 256 * 256;
        return p;
    };
    unsigned short* zt   = (unsigned short*)alloc((size_t)NN * 1024 * 2);   // z in (N,U,H)
    unsigned short* ebuf = (unsigned short*)alloc((size_t)EE * 128 * 2);
    float* s_src   = (float*)alloc((size_t)NN * 8 * 4);
    float* s_dst   = (float*)alloc((size_t)NN * 8 * 4);
    float* s_edge  = (float*)alloc((size_t)EE * 8 * 4);
    float* part_e  = (float*)alloc((size_t)2500 * 256 * 4);
    float* part_n  = (float*)alloc((size_t)157 * 256 * 4);
    float* scale_e = (float*)alloc(512);
    float* shift_e = (float*)alloc(512);
    float* scale_n = (float*)alloc(512);
    float* shift_n = (float*)alloc(512);
    unsigned short* nupd_bf = (unsigned short*)alloc((size_t)NN * 128 * 2);
    float* ush     = (float*)alloc((size_t)NN * 128 * 4);
    float* Sbuf    = (float*)alloc((size_t)NN * 512 * 4);
    int*   cnt     = (int*)alloc((size_t)NN * 4);
    int*   offs    = (int*)alloc((size_t)(NN + 1) * 4);
    int*   cursor  = (int*)alloc((size_t)NN * 4);
    int*   elist   = (int*)alloc((size_t)EE * 4);
    unsigned short* node_bf = (unsigned short*)alloc((size_t)NN * 128 * 2);
    unsigned short* WtE     = (unsigned short*)alloc((size_t)3 * 128 * 128 * 2);
    unsigned short* WtA     = (unsigned short*)alloc((size_t)8 * 128 * 128 * 2);
    unsigned short* WnT     = (unsigned short*)alloc((size_t)128 * 128 * 2);
    unsigned short* WcT     = (unsigned short*)alloc((size_t)512 * 256 * 2);
    unsigned short* cat     = (unsigned short*)alloc((size_t)NN * 256 * 2);
    unsigned short* p12     = (unsigned short*)alloc((size_t)NN * 256 * 2);
    float*          aT      = (float*)alloc((size_t)128 * 16 * 4);

    hipMemsetAsync(cnt, 0, (size_t)NN * 4, stream);
    k_hist<<<(EE + 255) / 256, 256, 0, stream>>>(eidx, cnt, EE);
    k_scan<<<1, 1024, 0, stream>>>(cnt, offs, cursor, NN);
    k_scatter<<<(EE + 255) / 256, 256, 0, stream>>>(eidx, cursor, elist, EE);

    // bf16 conversions / weight preps
    k_f2bf<<<1280, 256, 0, stream>>>(node, node_bf, (long)NN * 128 / 4);
    k_wt_edge<<<(3 * 128 * 128 + 255) / 256, 256, 0, stream>>>(We, WtE);
    k_wtg<<<(128 * 128 + 255) / 256, 256, 0, stream>>>(Wn, WnT, 128, 128);
    k_wt_att<<<(8 * 128 * 128 + 255) / 256, 256, 0, stream>>>(Watt, WtA);
    k_wt_gru<<<(512 * 256 + 255) / 256, 256, 0, stream>>>(Wk, Wr, WcT);
    k_at<<<(128 * 16 + 255) / 256, 256, 0, stream>>>(aatt, aT);

    // edge pipeline: P12 GEMM, fused PE+combine, BN, finalize
    k_p12_mfma<<<dim3((NN + 63) / 64, 2), 256, 0, stream>>>(node_bf, WtE, p12, NN);
    k_pe_comb<<<EE / 64, 256, 0, stream>>>(eattr, WtE, be, p12, eidx, ebuf, part_e);
    k_bn_fin<<<128, 256, 0, stream>>>(part_e, EE / 64, 1.f / (float)EE,
                                      gamma_e, beta_e, scale_e, shift_e);
    k_edge_final<<<EE / 8, 256, 0, stream>>>(ebuf, scale_e, shift_e, aatt, out_edge, s_edge);

    // node/attention pipeline
    k_z8<<<NN / 16, 256, 0, stream>>>(node_bf, WtA, batt, zt);
    k_snodes<<<NN / 4, 256, 0, stream>>>(zt, aT, s_src, s_dst);
    k_agg<<<NN, 128, 0, stream>>>(zt, s_src, s_dst, s_edge, offs, elist, eidx, cat);

    // node MLP + BN
    k_node_mlp_mfma<<<(NN + 63) / 64, 256, 0, stream>>>(node_bf, WnT, bnb, nupd_bf, part_n, NN);
    k_bn_fin<<<128, 256, 0, stream>>>(part_n, (NN + 63) / 64, 1.f / (float)NN,
                                      gamma_n, beta_n, scale_n, shift_n);

    // GRU
    k_gru_pre<<<(NN * 32 + 255) / 256, 256, 0, stream>>>(nupd_bf, scale_n, shift_n, cat, ush);
    k_gru_mm<<<dim3((NN + 63) / 64, 4), 256, 0, stream>>>(cat, WcT, Sbuf, NN);
    k_gru_gates<<<NN / 2, 256, 0, stream>>>(Sbuf, ush, gbias, out_node);
}

// Round 11
// 279.700 us; speedup vs baseline: 1.3568x; 1.0976x over previous
//
#include <hip/hip_runtime.h>
#include <hip/hip_bf16.h>

#define NN 10000
#define EE 160000
#define FF 128
#define UU 128
#define HH 8
#define BN_EPS 1e-3f

typedef __attribute__((ext_vector_type(8))) short bf16x8;
typedef __attribute__((ext_vector_type(8))) unsigned short u16x8;
typedef __attribute__((ext_vector_type(4))) float f32x4;

static __device__ __forceinline__ unsigned short f2bf(float f) {
    unsigned u = __float_as_uint(f);
    u += 0x7fffu + ((u >> 16) & 1u);
    return (unsigned short)(u >> 16);
}
static __device__ __forceinline__ float bf2f(unsigned short b) {
    return __uint_as_float((unsigned)b << 16);
}

// ---------------- fused prep: node f2bf + all weight transposes (one launch) ----------------
// blocks: [0,1250) node f2bf | [1250,1442) WtE | [1442,1506) WnT | [1506,2018) WtA | [2018,2530) WcT
__global__ void k_prep(const float* __restrict__ node, unsigned short* __restrict__ node_bf,
                       const float* __restrict__ We, unsigned short* __restrict__ WtE,
                       const float* __restrict__ Wn, unsigned short* __restrict__ WnT,
                       const float* __restrict__ Watt, unsigned short* __restrict__ WtA,
                       const float* __restrict__ Wk, const float* __restrict__ Wr,
                       unsigned short* __restrict__ WcT) {
    int b = blockIdx.x, t = threadIdx.x;
    if (b < 1250) {
        int i = b * 256 + t;                         // chunks of 4 floats, 320000 total
        float4 v = reinterpret_cast<const float4*>(node)[i];
        ushort4 o;
        o.x = f2bf(v.x); o.y = f2bf(v.y); o.z = f2bf(v.z); o.w = f2bf(v.w);
        reinterpret_cast<ushort4*>(node_bf)[i] = o;
    } else if (b < 1442) {
        int i = (b - 1250) * 256 + t;                // 3*128*128
        int s = i >> 14, rem = i & 16383, u = rem >> 7, k = rem & 127;
        WtE[i] = f2bf(We[(s * 128 + k) * 128 + u]);
    } else if (b < 1506) {
        int i = (b - 1442) * 256 + t;                // 128*128
        int k = i >> 7, u = i & 127;
        WnT[u * 128 + k] = f2bf(Wn[i]);
    } else if (b < 2018) {
        int i = (b - 1506) * 256 + t;                // 8*128*128
        int h = i >> 14, rem = i & 16383, f = rem >> 7, u = rem & 127;
        WtA[h * 16384 + u * 128 + f] = f2bf(Watt[i]);
    } else {
        int i = (b - 2018) * 256 + t;                // 512*256
        int c = i >> 8, k = i & 255;
        float v;
        if (c < 256)       v = (k < 128) ? Wk[k * 384 + c] : Wr[(k - 128) * 384 + c];
        else if (c < 384)  v = (k < 128) ? Wk[k * 384 + c] : 0.f;
        else               v = (k < 128) ? 0.f : Wr[(k - 128) * 384 + (c - 128)];
        WcT[c * 256 + k] = f2bf(v);
    }
}

// ---------------- CSR construction ----------------
__global__ void k_hist(const int* __restrict__ eidx, int* __restrict__ cnt, int E) {
    int e = blockIdx.x * 256 + threadIdx.x;
    if (e < E) atomicAdd(&cnt[eidx[2 * e]], 1);   // dst = eidx[e][0]
}

// single block, 1024 threads; wave-shuffle scan (2 barriers per 1024-chunk)
__global__ void k_scan(const int* __restrict__ cnt, int* __restrict__ off,
                       int* __restrict__ cursor, int N) {
    __shared__ int wpre[16];
    __shared__ int runsh;
    int t = threadIdx.x, lane = t & 63, wv = t >> 6;
    if (t == 0) { off[0] = 0; runsh = 0; }
    __syncthreads();
    for (int base = 0; base < N; base += 1024) {
        int x = (base + t < N) ? cnt[base + t] : 0;
        int s = x;
#pragma unroll
        for (int o = 1; o < 64; o <<= 1) {
            int v = __shfl_up(s, o, 64);
            if (lane >= o) s += v;
        }
        if (lane == 63) wpre[wv] = s;
        __syncthreads();
        if (t == 0) {
            int acc = runsh;
#pragma unroll
            for (int i = 0; i < 16; ++i) { int tmp = wpre[i]; wpre[i] = acc; acc += tmp; }
            runsh = acc;
        }
        __syncthreads();
        int inc = s + wpre[wv];
        if (base + t < N) {
            off[base + t + 1] = inc;
            cursor[base + t] = inc - x;
        }
        __syncthreads();
    }
}

__global__ void k_scatter(const int* __restrict__ eidx, int* __restrict__ cursor,
                          int* __restrict__ elist, int E) {
    int e = blockIdx.x * 256 + threadIdx.x;
    if (e < E) {
        int d = eidx[2 * e];
        int p = atomicAdd(&cursor[d], 1);
        elist[p] = e;
    }
}

// ---------------- z (bf16, (N,U,H)) = node @ W_att + b_att, all heads; fused s_src/s_dst ----------------
__global__ void __launch_bounds__(256) k_z8(
        const unsigned short* __restrict__ node_bf, const unsigned short* __restrict__ WtA,
        const float* __restrict__ batt, const float* __restrict__ aatt,
        unsigned short* __restrict__ zt, float* __restrict__ s_src, float* __restrict__ s_dst) {
    __shared__ unsigned short lds[16 * 1032];
    int n0 = blockIdx.x * 16;
    int t = threadIdx.x;
    {
        int r = t >> 4, c = t & 15;
        *reinterpret_cast<uint4*>(&lds[r * 136 + c * 8]) =
            *reinterpret_cast<const uint4*>(node_bf + (size_t)(n0 + r) * 128 + c * 8);
    }
    __syncthreads();

    int wid = t >> 6, lane = t & 63;
    int lr = lane & 15, lg = lane >> 4;

    f32x4 acc[2][8];
#pragma unroll
    for (int hh = 0; hh < 2; ++hh)
#pragma unroll
        for (int nt = 0; nt < 8; ++nt) acc[hh][nt] = (f32x4){0.f, 0.f, 0.f, 0.f};

#pragma unroll
    for (int ks = 0; ks < 4; ++ks) {
        int kb = ks * 32 + lg * 8;
        bf16x8 a = *reinterpret_cast<const bf16x8*>(&lds[lr * 136 + kb]);
#pragma unroll
        for (int hh = 0; hh < 2; ++hh) {
            const unsigned short* Wh = WtA + (size_t)(wid * 2 + hh) * 16384;
#pragma unroll
            for (int nt = 0; nt < 8; ++nt) {
                bf16x8 b = *reinterpret_cast<const bf16x8*>(Wh + (size_t)(nt * 16 + lr) * 128 + kb);
                acc[hh][nt] = __builtin_amdgcn_mfma_f32_16x16x32_bf16(a, b, acc[hh][nt], 0, 0, 0);
            }
        }
    }

    __syncthreads();                     // A reads done; reuse lds as (U,H)-interleaved C
    float ps[2][4], pd[2][4];
#pragma unroll
    for (int hh = 0; hh < 2; ++hh)
#pragma unroll
        for (int r = 0; r < 4; ++r) { ps[hh][r] = 0.f; pd[hh][r] = 0.f; }

#pragma unroll
    for (int hh = 0; hh < 2; ++hh) {
        int head = wid * 2 + hh;
#pragma unroll
        for (int nt = 0; nt < 8; ++nt) {
            int col = nt * 16 + lr;
            float bias = batt[head * 128 + col];
            float as = aatt[head * 384 + col];
            float ad = aatt[head * 384 + 128 + col];
#pragma unroll
            for (int r = 0; r < 4; ++r) {
                int row = lg * 4 + r;
                float zval = acc[hh][nt][r] + bias;
                lds[row * 1032 + ((col * 8) ^ ((row & 3) << 4)) + head] = f2bf(zval);
                ps[hh][r] = fmaf(zval, as, ps[hh][r]);
                pd[hh][r] = fmaf(zval, ad, pd[hh][r]);
            }
        }
    }
    // reduce over lr (16 lanes within same lg)
#pragma unroll
    for (int o = 1; o < 16; o <<= 1) {
#pragma unroll
        for (int hh = 0; hh < 2; ++hh)
#pragma unroll
            for (int r = 0; r < 4; ++r) {
                ps[hh][r] += __shfl_xor(ps[hh][r], o, 64);
                pd[hh][r] += __shfl_xor(pd[hh][r], o, 64);
            }
    }
    if (lr == 0) {
#pragma unroll
        for (int hh = 0; hh < 2; ++hh) {
            int head = wid * 2 + hh;
#pragma unroll
            for (int r = 0; r < 4; ++r) {
                int n = n0 + lg * 4 + r;
                s_src[n * 8 + head] = ps[hh][r];
                s_dst[n * 8 + head] = pd[hh][r];
            }
        }
    }
    __syncthreads();
    for (int q = t; q < 16 * 128; q += 256) {
        int row = q >> 7, c = q & 127;
        *reinterpret_cast<uint4*>(&zt[(size_t)(n0 + row) * 1024 + c * 8]) =
            *reinterpret_cast<const uint4*>(&lds[row * 1032 + ((c * 8) ^ ((row & 3) << 4))]);
    }
}

// ---------------- P12 (bf16) = node @ [W1|W2], MFMA, out N x 256 ----------------
__global__ void __launch_bounds__(256) k_p12_mfma(
        const unsigned short* __restrict__ node_bf, const unsigned short* __restrict__ WtE,
        unsigned short* __restrict__ p12, int N) {
    __shared__ unsigned short ash[64][136];
    int n0 = blockIdx.x * 64;
    int s = blockIdx.y;
    int t = threadIdx.x;
    for (int q = t; q < 64 * 16; q += 256) {
        int r = q >> 4, c = q & 15;
        int n = n0 + r; if (n >= N) n = N - 1;
        *reinterpret_cast<uint4*>(&ash[r][c * 8]) =
            *reinterpret_cast<const uint4*>(node_bf + (size_t)n * 128 + c * 8);
    }
    __syncthreads();

    int wid = t >> 6, lane = t & 63;
    int wm = wid >> 1, wn = wid & 1;
    int lr = lane & 15, lg = lane >> 4;

    f32x4 acc[2][4];
#pragma unroll
    for (int m = 0; m < 2; ++m)
#pragma unroll
        for (int n = 0; n < 4; ++n) acc[m][n] = (f32x4){0.f, 0.f, 0.f, 0.f};

    const unsigned short* Wh = WtE + (size_t)s * 16384;
#pragma unroll
    for (int ks = 0; ks < 4; ++ks) {
        int kb = ks * 32 + lg * 8;
        bf16x8 a0 = *reinterpret_cast<const bf16x8*>(&ash[wm * 32 + lr][kb]);
        bf16x8 a1 = *reinterpret_cast<const bf16x8*>(&ash[wm * 32 + 16 + lr][kb]);
        bf16x8 b[4];
#pragma unroll
        for (int n = 0; n < 4; ++n)
            b[n] = *reinterpret_cast<const bf16x8*>(Wh + (size_t)(wn * 64 + n * 16 + lr) * 128 + kb);
#pragma unroll
        for (int n = 0; n < 4; ++n) {
            acc[0][n] = __builtin_amdgcn_mfma_f32_16x16x32_bf16(a0, b[n], acc[0][n], 0, 0, 0);
            acc[1][n] = __builtin_amdgcn_mfma_f32_16x16x32_bf16(a1, b[n], acc[1][n], 0, 0, 0);
        }
    }

    __syncthreads();
    unsigned short* ot = &ash[0][0];
#pragma unroll
    for (int n = 0; n < 4; ++n) {
        int col = wn * 64 + n * 16 + lr;
#pragma unroll
        for (int m = 0; m < 2; ++m) {
            int rowb = wm * 32 + m * 16 + lg * 4;
#pragma unroll
            for (int r = 0; r < 4; ++r)
                ot[(rowb + r) * 136 + col] = f2bf(acc[m][n][r]);
        }
    }
    __syncthreads();
    for (int q = t; q < 64 * 16; q += 256) {
        int r = q >> 4, c = q & 15;
        int row = n0 + r;
        if (row < N)
            *reinterpret_cast<uint4*>(&p12[(size_t)row * 256 + s * 128 + c * 8]) =
                *reinterpret_cast<const uint4*>(&ot[r * 136 + c * 8]);
    }
}

// ---------------- PE+combine fused, single LDS buffer (A -> pcomb -> out) ----------------
__global__ void __launch_bounds__(256) k_pe_comb(
        const float* __restrict__ eattr, const unsigned short* __restrict__ WtE,
        const float* __restrict__ be, const unsigned short* __restrict__ p12,
        const int* __restrict__ eidx, unsigned short* __restrict__ ebuf,
        float* __restrict__ part) {
    __shared__ unsigned short ash[64][136];     // phase 1: A; phase 2: pcomb; phase 3: out
    __shared__ int sd[128];
    __shared__ float sbuf[4][64], qbuf[4][64];
    int e0 = blockIdx.x * 64;
    int t = threadIdx.x;
    if (t < 128) sd[t] = eidx[e0 * 2 + t];      // [e][0]=dst, [e][1]=src
    // stage A: f32 -> bf16
    for (int q = t; q < 64 * 32; q += 256) {
        int r = q >> 5, c = q & 31;
        float4 v = *reinterpret_cast<const float4*>(eattr + (size_t)(e0 + r) * 128 + c * 4);
        ushort4 o;
        o.x = f2bf(v.x); o.y = f2bf(v.y); o.z = f2bf(v.z); o.w = f2bf(v.w);
        *reinterpret_cast<ushort4*>(&ash[r][c * 4]) = o;
    }
    __syncthreads();

    int wid = t >> 6, lane = t & 63;
    int wm = wid >> 1, wn = wid & 1;
    int lr = lane & 15, lg = lane >> 4;

    f32x4 acc[2][4];
#pragma unroll
    for (int m = 0; m < 2; ++m)
#pragma unroll
        for (int n = 0; n < 4; ++n) acc[m][n] = (f32x4){0.f, 0.f, 0.f, 0.f};

    const unsigned short* Wh = WtE + (size_t)2 * 16384;
#pragma unroll
    for (int ks = 0; ks < 4; ++ks) {
        int kb = ks * 32 + lg * 8;
        bf16x8 a0 = *reinterpret_cast<const bf16x8*>(&ash[wm * 32 + lr][kb]);
        bf16x8 a1 = *reinterpret_cast<const bf16x8*>(&ash[wm * 32 + 16 + lr][kb]);
        bf16x8 b[4];
#pragma unroll
        for (int n = 0; n < 4; ++n)
            b[n] = *reinterpret_cast<const bf16x8*>(Wh + (size_t)(wn * 64 + n * 16 + lr) * 128 + kb);
#pragma unroll
        for (int n = 0; n < 4; ++n) {
            acc[0][n] = __builtin_amdgcn_mfma_f32_16x16x32_bf16(a0, b[n], acc[0][n], 0, 0, 0);
            acc[1][n] = __builtin_amdgcn_mfma_f32_16x16x32_bf16(a1, b[n], acc[1][n], 0, 0, 0);
        }
    }

    __syncthreads();                      // A dead; stage pcomb into same buffer
    for (int q = t; q < 64 * 16; q += 256) {
        int r = q >> 4, c = q & 15;
        int dst = sd[r * 2], src = sd[r * 2 + 1];
        u16x8 a = *reinterpret_cast<const u16x8*>(p12 + (size_t)src * 256 + c * 8);
        u16x8 b = *reinterpret_cast<const u16x8*>(p12 + (size_t)dst * 256 + 128 + c * 8);
        u16x8 o;
#pragma unroll
        for (int j = 0; j < 8; ++j) o[j] = f2bf(bf2f(a[j]) + bf2f(b[j]));
        *reinterpret_cast<u16x8*>(&ash[r][c * 8]) = o;
    }
    __syncthreads();

    // epilogue: each (row,col) owned by exactly one thread -> read pcomb, overwrite with out
    unsigned short* ot = &ash[0][0];
    float s[4] = {0.f, 0.f, 0.f, 0.f}, q[4] = {0.f, 0.f, 0.f, 0.f};
#pragma unroll
    for (int n = 0; n < 4; ++n) {
        int col = wn * 64 + n * 16 + lr;
        float bias = be[col];
#pragma unroll
        for (int m = 0; m < 2; ++m) {
            int rowb = wm * 32 + m * 16 + lg * 4;
#pragma unroll
            for (int r = 0; r < 4; ++r) {
                int row = rowb + r;
                float v = acc[m][n][r] + bias + bf2f(ot[row * 136 + col]);
                v = v > 0.f ? v : 0.f;
                ot[row * 136 + col] = f2bf(v);
                s[n] += v;
                q[n] += v * v;
            }
        }
    }
#pragma unroll
    for (int n = 0; n < 4; ++n) {
        s[n] += __shfl_xor(s[n], 16, 64);
        s[n] += __shfl_xor(s[n], 32, 64);
        q[n] += __shfl_xor(q[n], 16, 64);
        q[n] += __shfl_xor(q[n], 32, 64);
    }
    if (lane < 16) {
#pragma unroll
        for (int n = 0; n < 4; ++n) {
            sbuf[wid][n * 16 + lane] = s[n];
            qbuf[wid][n * 16 + lane] = q[n];
        }
    }
    __syncthreads();
    for (int q2 = t; q2 < 64 * 16; q2 += 256) {
        int r = q2 >> 4, c = q2 & 15;
        *reinterpret_cast<uint4*>(&ebuf[(size_t)(e0 + r) * 128 + c * 8]) =
            *reinterpret_cast<const uint4*>(&ot[r * 136 + c * 8]);
    }
    if (t < 128) {
        int half = t >> 6, c = t & 63;
        part[(size_t)blockIdx.x * 256 + t] = sbuf[half][c] + sbuf[2 + half][c];
        part[(size_t)blockIdx.x * 256 + 128 + t] = qbuf[half][c] + qbuf[2 + half][c];
    }
}

// ---------------- node MLP via MFMA: relu(node @ W_node + b) -> bf16, BN partials ----------------
__global__ void __launch_bounds__(256) k_node_mlp_mfma(
        const unsigned short* __restrict__ node_bf, const unsigned short* __restrict__ WnT,
        const float* __restrict__ bn, unsigned short* __restrict__ nupd_bf,
        float* __restrict__ part, int N) {
    __shared__ unsigned short ash[64][136];
    __shared__ float sbuf[4][64], qbuf[4][64];
    int n0 = blockIdx.x * 64;
    int t = threadIdx.x;
    for (int q = t; q < 64 * 16; q += 256) {
        int r = q >> 4, c = q & 15;
        int n = n0 + r; if (n >= N) n = N - 1;
        *reinterpret_cast<uint4*>(&ash[r][c * 8]) =
            *reinterpret_cast<const uint4*>(node_bf + (size_t)n * 128 + c * 8);
    }
    __syncthreads();

    int wid = t >> 6, lane = t & 63;
    int wm = wid >> 1, wn = wid & 1;
    int lr = lane & 15, lg = lane >> 4;

    f32x4 acc[2][4];
#pragma unroll
    for (int m = 0; m < 2; ++m)
#pragma unroll
        for (int n = 0; n < 4; ++n) acc[m][n] = (f32x4){0.f, 0.f, 0.f, 0.f};

#pragma unroll
    for (int ks = 0; ks < 4; ++ks) {
        int kb = ks * 32 + lg * 8;
        bf16x8 a0 = *reinterpret_cast<const bf16x8*>(&ash[wm * 32 + lr][kb]);
        bf16x8 a1 = *reinterpret_cast<const bf16x8*>(&ash[wm * 32 + 16 + lr][kb]);
        bf16x8 b[4];
#pragma unroll
        for (int n = 0; n < 4; ++n)
            b[n] = *reinterpret_cast<const bf16x8*>(WnT + (size_t)(wn * 64 + n * 16 + lr) * 128 + kb);
#pragma unroll
        for (int n = 0; n < 4; ++n) {
            acc[0][n] = __builtin_amdgcn_mfma_f32_16x16x32_bf16(a0, b[n], acc[0][n], 0, 0, 0);
            acc[1][n] = __builtin_amdgcn_mfma_f32_16x16x32_bf16(a1, b[n], acc[1][n], 0, 0, 0);
        }
    }

    __syncthreads();
    unsigned short* ot = &ash[0][0];
    float s[4] = {0.f, 0.f, 0.f, 0.f}, q[4] = {0.f, 0.f, 0.f, 0.f};
#pragma unroll
    for (int n = 0; n < 4; ++n) {
        int col = wn * 64 + n * 16 + lr;
        float bias = bn[col];
#pragma unroll
        for (int m = 0; m < 2; ++m) {
            int rowb = wm * 32 + m * 16 + lg * 4;
#pragma unroll
            for (int r = 0; r < 4; ++r) {
                int row = n0 + rowb + r;
                float v = acc[m][n][r] + bias;
                v = v > 0.f ? v : 0.f;
                ot[(rowb + r) * 136 + col] = f2bf(v);
                if (row < N) { s[n] += v; q[n] += v * v; }
            }
        }
    }
#pragma unroll
    for (int n = 0; n < 4; ++n) {
        s[n] += __shfl_xor(s[n], 16, 64);
        s[n] += __shfl_xor(s[n], 32, 64);
        q[n] += __shfl_xor(q[n], 16, 64);
        q[n] += __shfl_xor(q[n], 32, 64);
    }
    if (lane < 16) {
#pragma unroll
        for (int n = 0; n < 4; ++n) {
            sbuf[wid][n * 16 + lane] = s[n];
            qbuf[wid][n * 16 + lane] = q[n];
        }
    }
    __syncthreads();
    for (int q2 = t; q2 < 64 * 16; q2 += 256) {
        int r = q2 >> 4, c = q2 & 15;
        int row = n0 + r;
        if (row < N)
            *reinterpret_cast<uint4*>(&nupd_bf[(size_t)row * 128 + c * 8]) =
                *reinterpret_cast<const uint4*>(&ot[r * 136 + c * 8]);
    }
    if (t < 128) {
        int half = t >> 6, c = t & 63;
        part[(size_t)blockIdx.x * 256 + t] = sbuf[half][c] + sbuf[2 + half][c];
        part[(size_t)blockIdx.x * 256 + 128 + t] = qbuf[half][c] + qbuf[2 + half][c];
    }
}

// ---------------- BN finalize: scale/shift per column ----------------
__global__ void k_bn_fin(const float* __restrict__ part, int nblk, float invcnt,
                         const float* __restrict__ g, const float* __restrict__ b,
                         float* __restrict__ scale, float* __restrict__ shift) {
    int u = blockIdx.x;               // 128 blocks
    int t = threadIdx.x;              // 256
    float s = 0.f, q = 0.f;
    for (int i = t; i < nblk; i += 256) {
        s += part[(size_t)i * 256 + u];
        q += part[(size_t)i * 256 + 128 + u];
    }
    __shared__ float ls[4], lq[4];
    for (int o = 32; o > 0; o >>= 1) {
        s += __shfl_down(s, o, 64);
        q += __shfl_down(q, o, 64);
    }
    int lane = t & 63, w = t >> 6;
    if (lane == 0) { ls[w] = s; lq[w] = q; }
    __syncthreads();
    if (t == 0) {
        float S = ls[0] + ls[1] + ls[2] + ls[3];
        float Q = lq[0] + lq[1] + lq[2] + lq[3];
        float mean = S * invcnt;
        float var = Q * invcnt - mean * mean;
        float inv = rsqrtf(var + BN_EPS);
        float sc = g[u] * inv;
        scale[u] = sc;
        shift[u] = b[u] - mean * sc;
    }
}

// ---------------- edge finalize: wave=2 edges, lane=4 cols; BN apply + s_edge ----------------
__global__ void __launch_bounds__(256) k_edge_final(
        const unsigned short* __restrict__ ebuf, const float* __restrict__ scale,
        const float* __restrict__ shift, const float* __restrict__ aatt,
        float* __restrict__ eout, float* __restrict__ s_edge) {
    int t = threadIdx.x;
    int w = t >> 6, lane = t & 63;
    int q = lane & 31, half = lane >> 5;
    int e = blockIdx.x * 8 + w * 2 + half;

    float4 sc = *reinterpret_cast<const float4*>(scale + q * 4);
    float4 sh = *reinterpret_cast<const float4*>(shift + q * 4);
    float4 a4[8];
#pragma unroll
    for (int h = 0; h < 8; ++h)
        a4[h] = *reinterpret_cast<const float4*>(aatt + h * 384 + 256 + q * 4);

    ushort4 xb = *reinterpret_cast<const ushort4*>(ebuf + (size_t)e * 128 + q * 4);
    float4 x;
    x.x = bf2f(xb.x) * sc.x + sh.x;
    x.y = bf2f(xb.y) * sc.y + sh.y;
    x.z = bf2f(xb.z) * sc.z + sh.z;
    x.w = bf2f(xb.w) * sc.w + sh.w;
    *reinterpret_cast<float4*>(eout + (size_t)e * 128 + q * 4) = x;

    float v[8];
#pragma unroll
    for (int h = 0; h < 8; ++h)
        v[h] = x.x * a4[h].x + x.y * a4[h].y + x.z * a4[h].z + x.w * a4[h].w;
#pragma unroll
    for (int o = 1; o < 32; o <<= 1) {
#pragma unroll
        for (int h = 0; h < 8; ++h) v[h] += __shfl_xor(v[h], o, 64);
    }
    if (q == 0) {
#pragma unroll
        for (int h = 0; h < 8; ++h) s_edge[e * 8 + h] = v[h];
    }
}

// ---------------- attention softmax + aggregation; zt layout (N,U,H); bf16 out into cat ----------------
__global__ void k_agg(const unsigned short* __restrict__ zt, const float* __restrict__ s_src,
                      const float* __restrict__ s_dst, const float* __restrict__ s_edge,
                      const int* __restrict__ off, const int* __restrict__ elist,
                      const int* __restrict__ eidx, unsigned short* __restrict__ cat) {
    int n = blockIdx.x;
    int t = threadIdx.x;              // 128
    int beg = off[n], end = off[n + 1];
    int deg = end - beg;
    if (deg == 0) { cat[(size_t)n * 256 + t] = 0; return; }

    float sdh[8];
#pragma unroll
    for (int h = 0; h < 8; ++h) sdh[h] = s_dst[n * 8 + h];

    __shared__ float lred[16];
    __shared__ float wbuf[128][8];
    __shared__ int snbuf[128];

    float mx[8], den[8];
#pragma unroll
    for (int h = 0; h < 8; ++h) { mx[h] = -1e30f; den[h] = 0.f; }

    int lane = t & 63, w = t >> 6;

    // pass 1: running max / denominator
    for (int c0 = 0; c0 < deg; c0 += 128) {
        int cn = min(128, deg - c0);
        bool act = t < cn;
        int e = 0, sn = 0;
        if (act) { e = elist[beg + c0 + t]; sn = eidx[2 * e + 1]; }
        float lg[8];
#pragma unroll
        for (int h = 0; h < 8; ++h) {
            float x = act ? (s_src[sn * 8 + h] + sdh[h] + s_edge[e * 8 + h]) : -1e30f;
            lg[h] = x >= 0.f ? x : 0.2f * x;
        }
        float cm[8];
#pragma unroll
        for (int h = 0; h < 8; ++h) cm[h] = lg[h];
        for (int o = 32; o > 0; o >>= 1) {
#pragma unroll
            for (int h = 0; h < 8; ++h) cm[h] = fmaxf(cm[h], __shfl_down(cm[h], o, 64));
        }
        if (lane == 0) {
#pragma unroll
            for (int h = 0; h < 8; ++h) lred[w * 8 + h] = cm[h];
        }
        __syncthreads();
#pragma unroll
        for (int h = 0; h < 8; ++h) cm[h] = fmaxf(lred[h], lred[8 + h]);
        __syncthreads();
        float cs[8];
#pragma unroll
        for (int h = 0; h < 8; ++h) cs[h] = act ? __expf(lg[h] - cm[h]) : 0.f;
        for (int o = 32; o > 0; o >>= 1) {
#pragma unroll
            for (int h = 0; h < 8; ++h) cs[h] += __shfl_down(cs[h], o, 64);
        }
        if (lane == 0) {
#pragma unroll
            for (int h = 0; h < 8; ++h) lred[w * 8 + h] = cs[h];
        }
        __syncthreads();
#pragma unroll
        for (int h = 0; h < 8; ++h) {
            float csum = lred[h] + lred[8 + h];
            float nm = fmaxf(mx[h], cm[h]);
            den[h] = den[h] * __expf(mx[h] - nm) + csum * __expf(cm[h] - nm);
            mx[h] = nm;
        }
        __syncthreads();
    }
    float inv[8];
#pragma unroll
    for (int h = 0; h < 8; ++h) inv[h] = 1.f / den[h];

    // pass 2: weights into LDS, then accumulate Σ_h alpha_h * z[src, u=t, h]
    float acc = 0.f;
    for (int c0 = 0; c0 < deg; c0 += 128) {
        int cn = min(128, deg - c0);
        if (t < cn) {
            int e = elist[beg + c0 + t];
            int sn = eidx[2 * e + 1];
            snbuf[t] = sn;
#pragma unroll
            for (int h = 0; h < 8; ++h) {
                float x = s_src[sn * 8 + h] + sdh[h] + s_edge[e * 8 + h];
                x = x >= 0.f ? x : 0.2f * x;
                wbuf[t][h] = __expf(x - mx[h]) * inv[h];
            }
        }
        __syncthreads();
        for (int i = 0; i < cn; ++i) {
            int sn = snbuf[i];
            u16x8 zv = *reinterpret_cast<const u16x8*>(zt + (size_t)sn * 1024 + t * 8);
            float4 w0 = *reinterpret_cast<const float4*>(&wbuf[i][0]);
            float4 w1 = *reinterpret_cast<const float4*>(&wbuf[i][4]);
            acc = fmaf(w0.x, bf2f(zv[0]), acc);
            acc = fmaf(w0.y, bf2f(zv[1]), acc);
            acc = fmaf(w0.z, bf2f(zv[2]), acc);
            acc = fmaf(w0.w, bf2f(zv[3]), acc);
            acc = fmaf(w1.x, bf2f(zv[4]), acc);
            acc = fmaf(w1.y, bf2f(zv[5]), acc);
            acc = fmaf(w1.z, bf2f(zv[6]), acc);
            acc = fmaf(w1.w, bf2f(zv[7]), acc);
        }
        __syncthreads();
    }
    cat[(size_t)n * 256 + t] = f2bf(fmaxf(acc * 0.125f, 0.f));
}

// ---------------- GRU pre: ush = BN(nupd_bf); cat[:,128:256] = bf16(ush) ----------------
__global__ void k_gru_pre(const unsigned short* __restrict__ nupd_bf, const float* __restrict__ scale,
                          const float* __restrict__ shift, unsigned short* __restrict__ cat,
                          float* __restrict__ ush) {
    int i = blockIdx.x * 256 + threadIdx.x;   // over NN*32
    if (i >= NN * 32) return;
    int n = i >> 5, j4 = (i & 31) * 4;
    ushort4 ub_in = *reinterpret_cast<const ushort4*>(nupd_bf + (size_t)n * 128 + j4);
    float4 sc = *reinterpret_cast<const float4*>(scale + j4);
    float4 sh = *reinterpret_cast<const float4*>(shift + j4);
    float4 uv;
    uv.x = bf2f(ub_in.x) * sc.x + sh.x;
    uv.y = bf2f(ub_in.y) * sc.y + sh.y;
    uv.z = bf2f(ub_in.z) * sc.z + sh.z;
    uv.w = bf2f(ub_in.w) * sc.w + sh.w;
    ushort4 ub;
    ub.x = f2bf(uv.x); ub.y = f2bf(uv.y); ub.z = f2bf(uv.z); ub.w = f2bf(uv.w);
    *reinterpret_cast<ushort4*>(cat + (size_t)n * 256 + 128 + j4) = ub;
    *reinterpret_cast<float4*>(ush + (size_t)n * 128 + j4) = uv;
}

// ---------------- GRU GEMM: S = cat @ Wc  (M x 256 x 512), MFMA, LDS-coalesced store ----------------
__global__ void __launch_bounds__(256) k_gru_mm(
        const unsigned short* __restrict__ cat, const unsigned short* __restrict__ WcT,
        float* __restrict__ S, int N) {
    __shared__ unsigned short ash[64][264];
    int n0 = blockIdx.x * 64;
    int g = blockIdx.y;
    int t = threadIdx.x;
    for (int q = t; q < 64 * 32; q += 256) {
        int r = q >> 5, c = q & 31;
        int n = n0 + r; if (n >= N) n = N - 1;
        *reinterpret_cast<uint4*>(&ash[r][c * 8]) =
            *reinterpret_cast<const uint4*>(cat + (size_t)n * 256 + c * 8);
    }
    __syncthreads();

    int wid = t >> 6, lane = t & 63;
    int wm = wid >> 1, wn = wid & 1;
    int lr = lane & 15, lg = lane >> 4;

    f32x4 acc[2][4];
#pragma unroll
    for (int m = 0; m < 2; ++m)
#pragma unroll
        for (int n = 0; n < 4; ++n) acc[m][n] = (f32x4){0.f, 0.f, 0.f, 0.f};

    const unsigned short* Wg = WcT + (size_t)g * 128 * 256;
#pragma unroll
    for (int ks = 0; ks < 8; ++ks) {
        int kb = ks * 32 + lg * 8;
        bf16x8 a0 = *reinterpret_cast<const bf16x8*>(&ash[wm * 32 + lr][kb]);
        bf16x8 a1 = *reinterpret_cast<const bf16x8*>(&ash[wm * 32 + 16 + lr][kb]);
        bf16x8 b[4];
#pragma unroll
        for (int n = 0; n < 4; ++n)
            b[n] = *reinterpret_cast<const bf16x8*>(Wg + (size_t)(wn * 64 + n * 16 + lr) * 256 + kb);
#pragma unroll
        for (int n = 0; n < 4; ++n) {
            acc[0][n] = __builtin_amdgcn_mfma_f32_16x16x32_bf16(a0, b[n], acc[0][n], 0, 0, 0);
            acc[1][n] = __builtin_amdgcn_mfma_f32_16x16x32_bf16(a1, b[n], acc[1][n], 0, 0, 0);
        }
    }

    __syncthreads();
    float* otf = reinterpret_cast<float*>(&ash[0][0]);   // [64][132] f32
#pragma unroll
    for (int n = 0; n < 4; ++n) {
        int col = wn * 64 + n * 16 + lr;
#pragma unroll
        for (int m = 0; m < 2; ++m) {
            int rowb = wm * 32 + m * 16 + lg * 4;
#pragma unroll
            for (int r = 0; r < 4; ++r)
                otf[(rowb + r) * 132 + col] = acc[m][n][r];
        }
    }
    __syncthreads();
    for (int q = t; q < 64 * 32; q += 256) {
        int r = q >> 5, c = q & 31;
        int row = n0 + r;
        if (row < N)
            *reinterpret_cast<float4*>(&S[(size_t)row * 512 + g * 128 + c * 4]) =
                *reinterpret_cast<const float4*>(&otf[r * 132 + c * 4]);
    }
}

// ---------------- GRU gates: sigmoid/tanh + combine ----------------
__global__ void __launch_bounds__(256) k_gru_gates(
        const float* __restrict__ S, const float* __restrict__ ush,
        const float* __restrict__ gbias, float* __restrict__ outp) {
    int t = threadIdx.x;
    int n = blockIdx.x * 2 + (t >> 7);
    int u = t & 127;
    const float* b0 = gbias;
    const float* b1 = gbias + 384;
    float s0 = S[(size_t)n * 512 + u];
    float s1 = S[(size_t)n * 512 + 128 + u];
    float xh = S[(size_t)n * 512 + 256 + u];
    float rh = S[(size_t)n * 512 + 384 + u];
    float zg = 1.f / (1.f + __expf(-(s0 + b0[u] + b1[u])));
    float rg = 1.f / (1.f + __expf(-(s1 + b0[128 + u] + b1[128 + u])));
    float hh = tanhf(xh + b0[256 + u] + rg * (rh + b1[256 + u]));
    float uv = ush[(size_t)n * 128 + u];
    outp[(size_t)n * 128 + u] = zg * uv + (1.f - zg) * hh;
}

// ---------------- launch ----------------
extern "C" void kernel_launch(void* const* d_in, const int* in_sizes, int n_in,
                              void* d_out, int out_size, void* d_ws, size_t ws_size,
                              hipStream_t stream) {
    const float* node    = (const float*)d_in[0];
    const float* eattr   = (const float*)d_in[1];
    const int*   eidx    = (const int*)d_in[2];
    const float* We      = (const float*)d_in[3];
    const float* be      = (const float*)d_in[4];
    const float* gamma_e = (const float*)d_in[5];
    const float* beta_e  = (const float*)d_in[6];
    const float* Wn      = (const float*)d_in[7];
    const float* bnb     = (const float*)d_in[8];
    const float* gamma_n = (const float*)d_in[9];
    const float* beta_n  = (const float*)d_in[10];
    const float* Watt    = (const float*)d_in[11];
    const float* batt    = (const float*)d_in[12];
    const float* aatt    = (const float*)d_in[13];
    const float* Wk      = (const float*)d_in[14];
    const float* Wr      = (const float*)d_in[15];
    const float* gbias   = (const float*)d_in[16];

    float* out_node = (float*)d_out;
    float* out_edge = out_node + (size_t)NN * UU;

    char* wp = (char*)d_ws;
    auto alloc = [&](size_t bytes) {
        void* p = (void*)wp;
        wp += (bytes + 255) / 256 * 256;
        return p;
    };
    unsigned short* zt   = (unsigned short*)alloc((size_t)NN * 1024 * 2);   // z in (N,U,H)
    unsigned short* ebuf = (unsigned short*)alloc((size_t)EE * 128 * 2);
    float* s_src   = (float*)alloc((size_t)NN * 8 * 4);
    float* s_dst   = (float*)alloc((size_t)NN * 8 * 4);
    float* s_edge  = (float*)alloc((size_t)EE * 8 * 4);
    float* part_e  = (float*)alloc((size_t)2500 * 256 * 4);
    float* part_n  = (float*)alloc((size_t)157 * 256 * 4);
    float* scale_e = (float*)alloc(512);
    float* shift_e = (float*)alloc(512);
    float* scale_n = (float*)alloc(512);
    float* shift_n = (float*)alloc(512);
    unsigned short* nupd_bf = (unsigned short*)alloc((size_t)NN * 128 * 2);
    float* ush     = (float*)alloc((size_t)NN * 128 * 4);
    float* Sbuf    = (float*)alloc((size_t)NN * 512 * 4);
    int*   cnt     = (int*)alloc((size_t)NN * 4);
    int*   offs    = (int*)alloc((size_t)(NN + 1) * 4);
    int*   cursor  = (int*)alloc((size_t)NN * 4);
    int*   elist   = (int*)alloc((size_t)EE * 4);
    unsigned short* node_bf = (unsigned short*)alloc((size_t)NN * 128 * 2);
    unsigned short* WtE     = (unsigned short*)alloc((size_t)3 * 128 * 128 * 2);
    unsigned short* WtA     = (unsigned short*)alloc((size_t)8 * 128 * 128 * 2);
    unsigned short* WnT     = (unsigned short*)alloc((size_t)128 * 128 * 2);
    unsigned short* WcT     = (unsigned short*)alloc((size_t)512 * 256 * 2);
    unsigned short* cat     = (unsigned short*)alloc((size_t)NN * 256 * 2);
    unsigned short* p12     = (unsigned short*)alloc((size_t)NN * 256 * 2);

    hipMemsetAsync(cnt, 0, (size_t)NN * 4, stream);
    k_hist<<<(EE + 255) / 256, 256, 0, stream>>>(eidx, cnt, EE);
    k_scan<<<1, 1024, 0, stream>>>(cnt, offs, cursor, NN);
    k_scatter<<<(EE + 255) / 256, 256, 0, stream>>>(eidx, cursor, elist, EE);

    // fused conversions / weight preps (one launch)
    k_prep<<<2530, 256, 0, stream>>>(node, node_bf, We, WtE, Wn, WnT, Watt, WtA, Wk, Wr, WcT);

    // edge pipeline
    k_p12_mfma<<<dim3((NN + 63) / 64, 2), 256, 0, stream>>>(node_bf, WtE, p12, NN);
    k_pe_comb<<<EE / 64, 256, 0, stream>>>(eattr, WtE, be, p12, eidx, ebuf, part_e);
    k_bn_fin<<<128, 256, 0, stream>>>(part_e, EE / 64, 1.f / (float)EE,
                                      gamma_e, beta_e, scale_e, shift_e);
    k_edge_final<<<EE / 8, 256, 0, stream>>>(ebuf, scale_e, shift_e, aatt, out_edge, s_edge);

    // node/attention pipeline (z GEMM fused with s_src/s_dst)
    k_z8<<<NN / 16, 256, 0, stream>>>(node_bf, WtA, batt, aatt, zt, s_src, s_dst);
    k_agg<<<NN, 128, 0, stream>>>(zt, s_src, s_dst, s_edge, offs, elist, eidx, cat);

    // node MLP + BN
    k_node_mlp_mfma<<<(NN + 63) / 64, 256, 0, stream>>>(node_bf, WnT, bnb, nupd_bf, part_n, NN);
    k_bn_fin<<<128, 256, 0, stream>>>(part_n, (NN + 63) / 64, 1.f / (float)NN,
                                      gamma_n, beta_n, scale_n, shift_n);

    // GRU
    k_gru_pre<<<(NN * 32 + 255) / 256, 256, 0, stream>>>(nupd_bf, scale_n, shift_n, cat, ush);
    k_gru_mm<<<dim3((NN + 63) / 64, 4), 256, 0, stream>>>(cat, WcT, Sbuf, NN);
    k_gru_gates<<<NN / 2, 256, 0, stream>>>(Sbuf, ush, gbias, out_node);
}